// Round 16
// baseline (321.186 us; speedup 1.0000x reference)
//
#include <hip/hip_runtime.h>
#include <hip/hip_bf16.h>

#define TT 2048
#define DD 1024
#define FF 2048
#define NEXPI 10     // 2 shared + 8 routed expert instances
#define NRMAX 9216   // max compact rows: 4096 shared + 4096 routed + <=1024 pad
#define NTILEMAX 72  // NRMAX/128
#define CHTILES 36   // row-tiles per gemm1 chunk
#define CHROWS (CHTILES * 128)

typedef __attribute__((ext_vector_type(4))) int v4i;
typedef __attribute__((ext_vector_type(4))) float f32x4;

__device__ __forceinline__ double wave_sum_d(double v) {
#pragma unroll
  for (int o = 32; o > 0; o >>= 1) v += __shfl_down(v, o);
  return v;
}
__device__ __forceinline__ double wave_max_d(double v) {
#pragma unroll
  for (int o = 32; o > 0; o >>= 1) v = fmax(v, __shfl_down(v, o));
  return v;
}

// async global->LDS, 16B per lane; lds dest is wave-uniform base, lane l lands at +l*16
__device__ __forceinline__ void gll16(const void* g, void* l) {
  __builtin_amdgcn_global_load_lds(
      (const __attribute__((address_space(1))) void*)g,
      (__attribute__((address_space(3))) void*)l, 16, 0, 0);
}

// stage ROWS x 64B tile (i8, row stride K bytes in global) into linear LDS
template<int ROWS>
__device__ __forceinline__ void stage_rows(const signed char* src, int K,
                                           signed char* lds, int tid) {
  int w = tid >> 6, l = tid & 63;
  int sub = l >> 2, seg = (l & 3) * 16;
#pragma unroll
  for (int i = 0; i < ROWS / 64; ++i) {
    int rbase = w * (ROWS / 4) + i * 16;
    gll16(src + (size_t)(rbase + sub) * K + seg, lds + rbase * 64);
  }
}

// ---------------- zero init (compact rowmax) ----------------
__global__ void k_zero(unsigned* __restrict__ rm) {
  int i = blockIdx.x * 256 + threadIdx.x;
  if (i < NRMAX) rm[i] = 0u;
}

// ------------- rmsnorm + per-token absmax + int8 quant + bf16 h (f64 math) -------------
__global__ __launch_bounds__(256) void k_rms_quant(
    const float* __restrict__ x, const float* __restrict__ rw,
    signed char* __restrict__ qh, __hip_bfloat16* __restrict__ hb,
    double* __restrict__ amax_clip) {
  __shared__ double red[12];
  int t = blockIdx.x, tid = threadIdx.x;
  int lane = tid & 63, wid = tid >> 6;
  float4 xv = ((const float4*)(x + (size_t)t * DD))[tid];
  double x0 = xv.x, x1 = xv.y, x2 = xv.z, x3 = xv.w;
  double ss = x0 * x0 + x1 * x1 + x2 * x2 + x3 * x3;
  ss = wave_sum_d(ss);
  if (lane == 0) red[wid] = ss;
  __syncthreads();
  if (tid == 0) {
    double s = red[0] + red[1] + red[2] + red[3];
    red[8] = 1.0 / sqrt(s * (1.0 / DD) + 1e-6);
  }
  __syncthreads();
  double r = red[8];
  float4 wv = ((const float4*)rw)[tid];
  double h0 = x0 * r * (double)wv.x, h1 = x1 * r * (double)wv.y;
  double h2 = x2 * r * (double)wv.z, h3 = x3 * r * (double)wv.w;
  __hip_bfloat16* hp = hb + (size_t)t * DD + tid * 4;
  hp[0] = __float2bfloat16((float)h0); hp[1] = __float2bfloat16((float)h1);
  hp[2] = __float2bfloat16((float)h2); hp[3] = __float2bfloat16((float)h3);
  double am = fmax(fmax(fabs(h0), fabs(h1)), fmax(fabs(h2), fabs(h3)));
  am = wave_max_d(am);
  if (lane == 0) red[4 + wid] = am;
  __syncthreads();
  if (tid == 0) {
    double a = fmax(fmax(red[4], red[5]), fmax(red[6], red[7]));
    red[9] = fmax(a, 1e-5);
  }
  __syncthreads();
  double clipv = red[9];
  if (tid == 0) amax_clip[t] = clipv;
  double s = 127.0 / clipv;
  int q0 = (int)fmin(127.0, fmax(-128.0, rint(h0 * s)));
  int q1 = (int)fmin(127.0, fmax(-128.0, rint(h1 * s)));
  int q2 = (int)fmin(127.0, fmax(-128.0, rint(h2 * s)));
  int q3 = (int)fmin(127.0, fmax(-128.0, rint(h3 * s)));
  unsigned pw = (unsigned)(q0 & 255) | ((unsigned)(q1 & 255) << 8) |
                ((unsigned)(q2 & 255) << 16) | ((unsigned)(q3 & 255) << 24);
  *(unsigned*)(qh + (size_t)t * DD + tid * 4) = pw;
}

// ------------- weight absmean: f64 partial sums, 20 matrices x 128 blocks -------------
__global__ __launch_bounds__(256) void k_wabs_part(
    const float* __restrict__ w1s, const float* __restrict__ w2s,
    const float* __restrict__ w1r, const float* __restrict__ w2r,
    double* __restrict__ part) {
  __shared__ double red[4];
  int m = blockIdx.x >> 7, blk = blockIdx.x & 127;
  const float* base;
  if (m < 2)       base = w1s + (size_t)m * (DD * FF);
  else if (m < 4)  base = w2s + (size_t)(m - 2) * (DD * FF);
  else if (m < 12) base = w1r + (size_t)(m - 4) * (DD * FF);
  else             base = w2r + (size_t)(m - 12) * (DD * FF);
  const f32x4* p = (const f32x4*)base + (size_t)blk * 4096;
  int tid = threadIdx.x;
  double s0 = 0.0, s1 = 0.0, s2 = 0.0, s3 = 0.0;
#pragma unroll
  for (int b = 0; b < 2; ++b) {
    f32x4 v[8];
#pragma unroll
    for (int i = 0; i < 8; ++i)
      v[i] = __builtin_nontemporal_load(p + tid + (b * 8 + i) * 256);
#pragma unroll
    for (int i = 0; i < 8; i += 4) {
      s0 += (double)fabsf(v[i+0].x) + (double)fabsf(v[i+0].y) +
            (double)fabsf(v[i+0].z) + (double)fabsf(v[i+0].w);
      s1 += (double)fabsf(v[i+1].x) + (double)fabsf(v[i+1].y) +
            (double)fabsf(v[i+1].z) + (double)fabsf(v[i+1].w);
      s2 += (double)fabsf(v[i+2].x) + (double)fabsf(v[i+2].y) +
            (double)fabsf(v[i+2].z) + (double)fabsf(v[i+2].w);
      s3 += (double)fabsf(v[i+3].x) + (double)fabsf(v[i+3].y) +
            (double)fabsf(v[i+3].z) + (double)fabsf(v[i+3].w);
    }
  }
  double s = (s0 + s1) + (s2 + s3);
  s = wave_sum_d(s);
  int lane = tid & 63, wid = tid >> 6;
  if (lane == 0) red[wid] = s;
  __syncthreads();
  if (tid == 0) part[m * 128 + blk] = red[0] + red[1] + red[2] + red[3];
}

__global__ __launch_bounds__(64) void k_wscale_final(
    const double* __restrict__ part, double* __restrict__ wscale) {
  int m = blockIdx.x;
  double v = part[m * 128 + threadIdx.x] + part[m * 128 + 64 + threadIdx.x];
  v = wave_sum_d(v);
  if (threadIdx.x == 0) wscale[m] = v * (1.0 / 2097152.0) + 1e-8;
}

// ------------- router: bf16 products, f64 accum, bf16-rounded logits,
//               top-2 (lower-index tie-break), renorm -> dense gates + (i0,i1) ---------
__global__ __launch_bounds__(64) void k_router(
    const __hip_bfloat16* __restrict__ hb, const float* __restrict__ rw,
    float* __restrict__ gates, int2* __restrict__ i01) {
  int t = blockIdx.x, lane = threadIdx.x;
  double acc[8];
#pragma unroll
  for (int e = 0; e < 8; ++e) acc[e] = 0.0;
  const __hip_bfloat16* hp = hb + (size_t)t * DD;
  for (int d = lane; d < DD; d += 64) {
    double hv = (double)__bfloat162float(hp[d]);
#pragma unroll
    for (int e = 0; e < 8; ++e) {
      double wv = (double)__bfloat162float(__float2bfloat16(rw[e * DD + d]));
      acc[e] += hv * wv;
    }
  }
#pragma unroll
  for (int e = 0; e < 8; ++e) acc[e] = wave_sum_d(acc[e]);
  if (lane == 0) {
    double lb[8];
#pragma unroll
    for (int e = 0; e < 8; ++e)
      lb[e] = (double)__bfloat162float(__float2bfloat16((float)acc[e]));
    double mx = lb[0];
#pragma unroll
    for (int e = 1; e < 8; ++e) mx = fmax(mx, lb[e]);
    double p[8];
#pragma unroll
    for (int e = 0; e < 8; ++e) p[e] = exp(lb[e] - mx);
    int i0 = 0;
    for (int e = 1; e < 8; ++e) if (p[e] > p[i0]) i0 = e;
    int i1 = (i0 == 0) ? 1 : 0;
    for (int e = 0; e < 8; ++e) if (e != i0 && p[e] > p[i1]) i1 = e;
    double den = p[i0] + p[i1];
    float o[8] = {0.f, 0.f, 0.f, 0.f, 0.f, 0.f, 0.f, 0.f};
    o[i0] = (float)(p[i0] / den);
    o[i1] = (float)(p[i1] / den);
#pragma unroll
    for (int e = 0; e < 8; ++e) gates[(size_t)t * 8 + e] = o[e];
    i01[t] = make_int2(i0, i1);
  }
}

// ------------- per-expert ordered token lists (ballot prefix compaction) ---------------
__global__ __launch_bounds__(64) void k_lists(
    const int2* __restrict__ i01, int* __restrict__ lists,
    unsigned char* __restrict__ slots, int* __restrict__ cnt) {
  int e = blockIdx.x, lane = threadIdx.x;
  int* le = lists + e * TT;
  unsigned char* se = slots + e * TT;
  int base = 0;
  for (int it = 0; it < TT / 64; ++it) {
    int t = it * 64 + lane;
    int2 r = i01[t];
    bool hit0 = (r.x == e), hit1 = (r.y == e);
    bool hit = hit0 || hit1;
    unsigned long long m = __ballot(hit);
    int pos = base + __popcll(m & ((1ull << lane) - 1ull));
    if (hit) { le[pos] = t; se[pos] = hit0 ? 0 : 1; }
    base += __popcll(m);
  }
  if (lane == 0) cnt[e] = base;
}

// ------------- meta: segment offsets, tile->expert map, per-row gather tables ----------
__global__ __launch_bounds__(256) void k_meta(
    const int* __restrict__ cnt, const int* __restrict__ lists,
    const unsigned char* __restrict__ slots, const double* __restrict__ amax_clip,
    const double* __restrict__ wscale, int* __restrict__ meta,
    int* __restrict__ rowexp, int* __restrict__ tokidx,
    int* __restrict__ wrow, float* __restrict__ srow1c) {
  __shared__ int segs[9];
  __shared__ int scnt[8];
  int tid = threadIdx.x;
  if (tid == 0) {
    int acc = 0;
    for (int e = 0; e < 8; ++e) {
      scnt[e] = cnt[e];
      segs[e] = acc;
      acc += (cnt[e] + 127) & ~127;
    }
    segs[8] = acc;
    meta[0] = 32 + acc / 128;   // total row-tiles
    meta[1] = 4096 + acc;       // total compact rows
  }
  __syncthreads();
  int ntile = 32 + segs[8] / 128;
  for (int j = tid; j < NTILEMAX; j += 256) {
    int ei = -1;
    if (j < 16) ei = 0;
    else if (j < 32) ei = 1;
    else if (j < ntile) {
      int rr = (j - 32) * 128;
      for (int e = 0; e < 8; ++e)
        if (rr >= segs[e] && rr < segs[e + 1]) { ei = 2 + e; break; }
    }
    rowexp[j] = ei;
  }
  for (int r = tid; r < NRMAX; r += 256) {
    int t = 0; float s1 = 0.f; int w = -1;
    if (r < 4096) {
      int e = r >> 11; t = r & (TT - 1);
      double csc = wscale[e] * (1.0 / 127.0);
      s1 = (float)(amax_clip[t] * csc);
      w = e * TT + t;
    } else {
      int rr = r - 4096;
      if (rr < segs[8]) {
        int e = 0;
        for (int q = 0; q < 8; ++q)
          if (rr >= segs[q] && rr < segs[q + 1]) { e = q; break; }
        int k = rr - segs[e];
        if (k < scnt[e]) {
          t = lists[e * TT + k];
          int sl = slots[e * TT + k];
          double csc = wscale[4 + e] * (1.0 / 127.0);
          s1 = (float)(amax_clip[t] * csc);
          w = (2 + sl) * TT + t;
        }
      }
    }
    tokidx[r] = t; srow1c[r] = s1; wrow[r] = w;
  }
}

// ------------- ternary quant helper (f64 bins) -------------
__device__ __forceinline__ int qtern(float v, double winv) {
  double q = rint((double)v * winv);
  return (int)fmin(1.0, fmax(-1.0, q));
}
__device__ __forceinline__ unsigned pack4(int a, int b, int c, int d) {
  return (unsigned)(a & 255) | ((unsigned)(b & 255) << 8) |
         ((unsigned)(c & 255) << 16) | ((unsigned)(d & 255) << 24);
}

// ------------- weight quant + transpose: f32 [R][C] -> i8 W^T [C][R] -------------
__global__ __launch_bounds__(256) void k_wquant(
    const float* __restrict__ w1s, const float* __restrict__ w2s,
    const float* __restrict__ w1r, const float* __restrict__ w2r,
    const double* __restrict__ wscale,
    signed char* __restrict__ q1T, signed char* __restrict__ q2T) {
  __shared__ signed char tile[64 * 68];
  int bid = blockIdx.x;
  int m = bid >> 9, t = bid & 511;
  const float* src;
  signed char* dst;
  int ld, ldo, rt, ct;
  if (m < 2) {
    src = w1s + (size_t)m * DD * FF;
    dst = q1T + (size_t)m * FF * DD;
    ld = FF; ldo = DD; rt = t >> 5; ct = t & 31;
  } else if (m < 4) {
    src = w2s + (size_t)(m - 2) * FF * DD;
    dst = q2T + (size_t)(m - 2) * DD * FF;
    ld = DD; ldo = FF; rt = t >> 4; ct = t & 15;
  } else if (m < 12) {
    src = w1r + (size_t)(m - 4) * DD * FF;
    dst = q1T + (size_t)(m - 2) * FF * DD;
    ld = FF; ldo = DD; rt = t >> 5; ct = t & 31;
  } else {
    src = w2r + (size_t)(m - 12) * FF * DD;
    dst = q2T + (size_t)(m - 10) * DD * FF;
    ld = DD; ldo = FF; rt = t >> 4; ct = t & 15;
  }
  double winv = 1.0 / wscale[m];
  int row0 = rt * 64, col0 = ct * 64;
  int r = threadIdx.x >> 2, sc_ = (threadIdx.x & 3) * 16;
  const float* sp = src + (size_t)(row0 + r) * ld + col0 + sc_;
#pragma unroll
  for (int g = 0; g < 4; ++g) {
    float4 v = *(const float4*)(sp + g * 4);
    unsigned pk = pack4(qtern(v.x, winv), qtern(v.y, winv),
                        qtern(v.z, winv), qtern(v.w, winv));
    *(unsigned*)(tile + r * 68 + sc_ + g * 4) = pk;
  }
  __syncthreads();
  int c = threadIdx.x >> 2, sr = (threadIdx.x & 3) * 16;
  unsigned o[4];
#pragma unroll
  for (int g = 0; g < 4; ++g) {
    int j = sr + g * 4;
    o[g] = pack4(tile[(j + 0) * 68 + c], tile[(j + 1) * 68 + c],
                 tile[(j + 2) * 68 + c], tile[(j + 3) * 68 + c]);
  }
  int4 ov = make_int4((int)o[0], (int)o[1], (int)o[2], (int)o[3]);
  *(int4*)(dst + (size_t)(col0 + c) * ldo + row0 + sr) = ov;
}

// ------------- GEMM1 (compact rows, gathered A): 128x64 tiles, BK=256 ----------------
// fixed grid (32, CHTILES) = 1152 blocks; bijective XCD swizzle (chunks of 144)
__global__ __launch_bounds__(256) void k_g1(
    const signed char* __restrict__ qh, const signed char* __restrict__ q1T,
    const int* __restrict__ rowexp, const int* __restrict__ tokidx,
    const float* __restrict__ srow1c, const int* __restrict__ meta, int tile0,
    float* __restrict__ abuf_c, unsigned* __restrict__ rowmaxc) {
  __shared__ __align__(16) signed char As[128 * 256];  // 32KB
  __shared__ __align__(16) signed char Bs[64 * 256];   // 16KB
  int lid = blockIdx.x + 32 * blockIdx.y;          // 0..1151
  int nid = (lid & 7) * 144 + (lid >> 3);          // bijective XCD chunks
  int j = tile0 + (nid >> 5);
  if (j >= meta[0]) return;
  int col0 = (nid & 31) * 64;
  int ei = rowexp[j];
  int tid = threadIdx.x, lane = tid & 63, wid = tid >> 6;
  int wr = wid >> 1, wc = wid & 1;
  int rowt0 = j * 128;
  // staging lane mapping: 16 lanes per row, 4 rows per gll16 instr
  int subr = lane >> 4, seg = (lane & 15) * 16;
  // gathered A pointers (k-invariant), rows wid*32 + i*4 + subr
  const signed char* aptr[8];
#pragma unroll
  for (int i = 0; i < 8; ++i)
    aptr[i] = qh + (size_t)tokidx[rowt0 + wid * 32 + i * 4 + subr] * DD + seg;
  const signed char* b_src = q1T + (size_t)ei * FF * DD + (size_t)col0 * DD;
  int kg = (lane >> 4) * 16, rsel = lane & 15;
  v4i zero = {0, 0, 0, 0};
  v4i acc[4][2];
#pragma unroll
  for (int i = 0; i < 4; ++i)
#pragma unroll
    for (int jj = 0; jj < 2; ++jj) acc[i][jj] = zero;
  for (int k0 = 0; k0 < DD; k0 += 256) {
    __syncthreads();
#pragma unroll
    for (int i = 0; i < 8; ++i)
      gll16(aptr[i] + k0, As + (wid * 32 + i * 4) * 256);
#pragma unroll
    for (int i = 0; i < 4; ++i)
      gll16(b_src + (size_t)(wid * 16 + i * 4 + subr) * DD + seg + k0,
            Bs + (wid * 16 + i * 4) * 256);
    __syncthreads();
#pragma unroll
    for (int kk = 0; kk < 4; ++kk) {
      v4i af[4], bf[2];
#pragma unroll
      for (int mi = 0; mi < 4; ++mi)
        af[mi] = *(const v4i*)(As + (wr * 64 + mi * 16 + rsel) * 256 + kk * 64 + kg);
#pragma unroll
      for (int ni = 0; ni < 2; ++ni)
        bf[ni] = *(const v4i*)(Bs + (wc * 32 + ni * 16 + rsel) * 256 + kk * 64 + kg);
#pragma unroll
      for (int mi = 0; mi < 4; ++mi)
#pragma unroll
        for (int ni = 0; ni < 2; ++ni)
          acc[mi][ni] = __builtin_amdgcn_mfma_i32_16x16x64_i8(af[mi], bf[ni], acc[mi][ni], 0, 0, 0);
    }
  }
  int rlocal0 = (j - tile0) * 128;
#pragma unroll
  for (int mi = 0; mi < 4; ++mi) {
#pragma unroll
    for (int rg = 0; rg < 4; ++rg) {
      int rof = wr * 64 + mi * 16 + ((lane >> 4) << 2) + rg;
      int tr = rowt0 + rof;
      float sA = srow1c[tr];
      float mloc = 0.f;
      int rl = rlocal0 + rof;
#pragma unroll
      for (int ni = 0; ni < 2; ++ni) {
        int fc = col0 + wc * 32 + ni * 16 + (lane & 15);
        float a = (float)acc[mi][ni][rg] * sA;
        float v = a / (1.f + expf(-a));
        abuf_c[(size_t)rl * FF + fc] = v;
        mloc = fmaxf(mloc, fabsf(v));
      }
#pragma unroll
      for (int o = 1; o < 16; o <<= 1) mloc = fmaxf(mloc, __shfl_xor(mloc, o));
      if ((lane & 15) == 0) atomicMax(rowmaxc + tr, __float_as_uint(mloc));
    }
  }
}

// ------------- aquant (chunk of compact rows) -------------
__global__ __launch_bounds__(256) void k_aq(
    const float* __restrict__ abuf_c, const unsigned* __restrict__ rowmaxc,
    const int* __restrict__ meta, int row0, signed char* __restrict__ qa) {
  int nrows = meta[1] - row0;
  if (nrows > CHROWS) nrows = CHROWS;
  if (nrows < 0) nrows = 0;
  int total4 = nrows * (FF / 4);
  int stride = gridDim.x * 256;
  for (int i = blockIdx.x * 256 + threadIdx.x; i < total4; i += stride) {
    int rl = i >> 9;
    int r = row0 + rl;
    float clip = fmaxf(__uint_as_float(rowmaxc[r]), 1e-5f);
    float s = 127.f / clip;
    float4 v = ((const float4*)abuf_c)[i];
    int q0 = (int)fminf(127.f, fmaxf(-128.f, rintf(v.x * s)));
    int q1 = (int)fminf(127.f, fmaxf(-128.f, rintf(v.y * s)));
    int q2 = (int)fminf(127.f, fmaxf(-128.f, rintf(v.z * s)));
    int q3 = (int)fminf(127.f, fmaxf(-128.f, rintf(v.w * s)));
    ((unsigned*)qa)[(size_t)r * (FF / 4) + (i & 511)] = pack4(q0, q1, q2, q3);
  }
}

// ------------- final gemm2 scale per compact row -------------
__global__ __launch_bounds__(256) void k_scg(
    const unsigned* __restrict__ rowmaxc, const double* __restrict__ wscale,
    const float* __restrict__ gates, const int* __restrict__ tokidx,
    const int* __restrict__ wrow, const int* __restrict__ rowexp,
    float* __restrict__ sgc) {
  int r = blockIdx.x * 256 + threadIdx.x;
  if (r >= NRMAX) return;
  int ei = rowexp[r >> 7];
  int w = wrow[r];
  if (ei < 0 || w < 0) { sgc[r] = 0.f; return; }
  float clip = fmaxf(__uint_as_float(rowmaxc[r]), 1e-5f);
  int t = tokidx[r];
  double csc = wscale[ei < 2 ? ei + 2 : ei + 10] * (1.0 / 127.0);
  float g = (ei < 2) ? 1.f : gates[(size_t)t * 8 + (ei - 2)];
  sgc[r] = (float)((double)clip * csc) * g;
}

// ------------- GEMM2 (compact rows): 128x64 tiles, BK=256 ---------------------------
// fixed grid (16, NTILEMAX) = 1152 blocks; bijective XCD swizzle (chunks of 144)
__global__ __launch_bounds__(256) void k_g2(
    const signed char* __restrict__ qa, const signed char* __restrict__ q2T,
    const int* __restrict__ rowexp, const float* __restrict__ sgc,
    const int* __restrict__ wrow, const int* __restrict__ meta,
    float* __restrict__ pbuf) {
  __shared__ __align__(16) signed char As[128 * 256];  // 32KB
  __shared__ __align__(16) signed char Bs[64 * 256];   // 16KB
  int lid = blockIdx.x + 16 * blockIdx.y;          // 0..1151
  int nid = (lid & 7) * 144 + (lid >> 3);
  int j = nid >> 4;
  if (j >= meta[0]) return;
  int col0 = (nid & 15) * 64;
  int ei = rowexp[j];
  int tid = threadIdx.x, lane = tid & 63, wid = tid >> 6;
  int wr = wid >> 1, wc = wid & 1;
  const signed char* ap = qa + (size_t)j * 128 * FF;
  const signed char* bp = q2T + (size_t)ei * DD * FF + (size_t)col0 * FF;
  int subr = lane >> 4, seg = (lane & 15) * 16;
  int kg = (lane >> 4) * 16, rsel = lane & 15;
  v4i zero = {0, 0, 0, 0};
  v4i acc[4][2];
#pragma unroll
  for (int i = 0; i < 4; ++i)
#pragma unroll
    for (int jj = 0; jj < 2; ++jj) acc[i][jj] = zero;
  for (int k0 = 0; k0 < FF; k0 += 256) {
    __syncthreads();
#pragma unroll
    for (int i = 0; i < 8; ++i)
      gll16(ap + (size_t)(wid * 32 + i * 4 + subr) * FF + seg + k0,
            As + (wid * 32 + i * 4) * 256);
#pragma unroll
    for (int i = 0; i < 4; ++i)
      gll16(bp + (size_t)(wid * 16 + i * 4 + subr) * FF + seg + k0,
            Bs + (wid * 16 + i * 4) * 256);
    __syncthreads();
#pragma unroll
    for (int kk = 0; kk < 4; ++kk) {
      v4i af[4], bf[2];
#pragma unroll
      for (int mi = 0; mi < 4; ++mi)
        af[mi] = *(const v4i*)(As + (wr * 64 + mi * 16 + rsel) * 256 + kk * 64 + kg);
#pragma unroll
      for (int ni = 0; ni < 2; ++ni)
        bf[ni] = *(const v4i*)(Bs + (wc * 32 + ni * 16 + rsel) * 256 + kk * 64 + kg);
#pragma unroll
      for (int mi = 0; mi < 4; ++mi)
#pragma unroll
        for (int ni = 0; ni < 2; ++ni)
          acc[mi][ni] = __builtin_amdgcn_mfma_i32_16x16x64_i8(af[mi], bf[ni], acc[mi][ni], 0, 0, 0);
    }
  }
#pragma unroll
  for (int mi = 0; mi < 4; ++mi) {
#pragma unroll
    for (int rg = 0; rg < 4; ++rg) {
      int tr = j * 128 + wr * 64 + mi * 16 + ((lane >> 4) << 2) + rg;
      int w = wrow[tr];
      float sc = sgc[tr];
      if (w >= 0) {
#pragma unroll
        for (int ni = 0; ni < 2; ++ni) {
          int dc = col0 + wc * 32 + ni * 16 + (lane & 15);
          pbuf[(size_t)w * DD + dc] = (float)acc[mi][ni][rg] * sc;
        }
      }
    }
  }
}

// ------------- combine: out = sum of 4 planes -------------
__global__ __launch_bounds__(256) void k_combine(
    const float* __restrict__ pbuf, float* __restrict__ out) {
  int i = blockIdx.x * 256 + threadIdx.x;  // float4 index
  float4 s = ((const float4*)pbuf)[i];
#pragma unroll
  for (int z = 1; z < 4; ++z) {
    float4 v = ((const float4*)(pbuf + (size_t)z * TT * DD))[i];
    s.x += v.x; s.y += v.y; s.z += v.z; s.w += v.w;
  }
  ((float4*)out)[i] = s;
}

extern "C" void kernel_launch(void* const* d_in, const int* in_sizes, int n_in,
                              void* d_out, int out_size, void* d_ws, size_t ws_size,
                              hipStream_t stream) {
  const float* x    = (const float*)d_in[0];
  const float* rmsw = (const float*)d_in[1];
  const float* w1s  = (const float*)d_in[2];
  const float* w2s  = (const float*)d_in[3];
  const float* w1r  = (const float*)d_in[4];
  const float* w2r  = (const float*)d_in[5];
  const float* rw   = (const float*)d_in[6];
  float* out = (float*)d_out;

  char* ws = (char*)d_ws;
  // footprint ends at 0x7E80000 ~= 132.6MB (proven safe)
  double* amax_clip      = (double*)(ws + 0x0000000);   // 16KB
  double* part           = (double*)(ws + 0x0004000);   // 20KB (20*128 f64)
  double* wscale         = (double*)(ws + 0x0018000);   // 160B
  float* gates           = (float*)(ws + 0x0019000);    // 64KB
  int2* i01              = (int2*)(ws + 0x0029000);     // 16KB
  int* lists             = (int*)(ws + 0x002D000);      // 64KB
  unsigned char* slots   = (unsigned char*)(ws + 0x003D000); // 16KB
  int* cnt               = (int*)(ws + 0x0041000);      // 32B
  int* meta              = (int*)(ws + 0x0041100);      // 64B
  int* tokidx            = (int*)(ws + 0x0042000);      // 36KB
  int* wrow              = (int*)(ws + 0x004B000);      // 36KB
  float* srow1c          = (float*)(ws + 0x0054000);    // 36KB
  float* sgc             = (float*)(ws + 0x005D000);    // 36KB
  int* rowexp            = (int*)(ws + 0x0066000);      // 288B
  unsigned* rowmaxc      = (unsigned*)(ws + 0x0067000); // 36KB
  signed char* qh        = (signed char*)(ws + 0x0080000);    // 2MB
  __hip_bfloat16* hb     = (__hip_bfloat16*)(ws + 0x0280000); // 4MB
  signed char* q1T       = (signed char*)(ws + 0x0680000);    // 20MB
  signed char* q2T       = (signed char*)(ws + 0x1A80000);    // 20MB
  signed char* qa        = (signed char*)(ws + 0x2E80000);    // <=18.9MB (40MB region)
  float* pbuf            = (float*)(ws + 0x5680000);          // 4 planes = 32MB (40MB region)
  float* abuf_c          = pbuf;  // alias: chunk buffer (37.7MB) used before g2 writes pbuf

  k_zero<<<(NRMAX + 255) / 256, 256, 0, stream>>>(rowmaxc);
  k_rms_quant<<<TT, 256, 0, stream>>>(x, rmsw, qh, hb, amax_clip);
  k_wabs_part<<<20 * 128, 256, 0, stream>>>(w1s, w2s, w1r, w2r, part);
  k_wscale_final<<<20, 64, 0, stream>>>(part, wscale);
  k_router<<<TT, 64, 0, stream>>>(hb, rw, gates, i01);
  k_lists<<<8, 64, 0, stream>>>(i01, lists, slots, cnt);
  k_wquant<<<20 * 512, 256, 0, stream>>>(w1s, w2s, w1r, w2r, wscale, q1T, q2T);
  k_meta<<<1, 256, 0, stream>>>(cnt, lists, slots, amax_clip, wscale,
                                meta, rowexp, tokidx, wrow, srow1c);

  dim3 g1(32, CHTILES);
  k_g1<<<g1, 256, 0, stream>>>(qh, q1T, rowexp, tokidx, srow1c, meta, 0,
                               abuf_c, rowmaxc);
  k_aq<<<2048, 256, 0, stream>>>(abuf_c, rowmaxc, meta, 0, qa);
  k_g1<<<g1, 256, 0, stream>>>(qh, q1T, rowexp, tokidx, srow1c, meta, CHTILES,
                               abuf_c, rowmaxc);
  k_aq<<<2048, 256, 0, stream>>>(abuf_c, rowmaxc, meta, CHROWS, qa);

  k_scg<<<(NRMAX + 255) / 256, 256, 0, stream>>>(rowmaxc, wscale, gates,
                                                 tokidx, wrow, rowexp, sgc);
  dim3 g2(16, NTILEMAX);
  k_g2<<<g2, 256, 0, stream>>>(qa, q2T, rowexp, sgc, wrow, meta, pbuf);
  k_combine<<<TT * DD / 4 / 256, 256, 0, stream>>>(pbuf, out);
}

// Round 17
// 253.417 us; speedup vs baseline: 1.2674x; 1.2674x over previous
//
#include <hip/hip_runtime.h>
#include <hip/hip_bf16.h>

#define TT 2048
#define DD 1024
#define FF 2048
#define NEXPI 10     // 2 shared + 8 routed expert instances
#define NRMAX 9216   // max compact rows: 4096 shared + 4096 routed + <=1024 pad
#define NTILEMAX 72  // NRMAX/128
#define CHTILES 36   // row-tiles per gemm1 chunk
#define CHROWS (CHTILES * 128)

typedef __attribute__((ext_vector_type(4))) int v4i;
typedef __attribute__((ext_vector_type(4))) float f32x4;

__device__ __forceinline__ double wave_sum_d(double v) {
#pragma unroll
  for (int o = 32; o > 0; o >>= 1) v += __shfl_down(v, o);
  return v;
}
__device__ __forceinline__ double wave_max_d(double v) {
#pragma unroll
  for (int o = 32; o > 0; o >>= 1) v = fmax(v, __shfl_down(v, o));
  return v;
}

// async global->LDS, 16B per lane; lds dest is wave-uniform base, lane l lands at +l*16
__device__ __forceinline__ void gll16(const void* g, void* l) {
  __builtin_amdgcn_global_load_lds(
      (const __attribute__((address_space(1))) void*)g,
      (__attribute__((address_space(3))) void*)l, 16, 0, 0);
}

// stage ROWS x 64B tile (i8, row stride K bytes in global) into linear LDS
template<int ROWS>
__device__ __forceinline__ void stage_rows(const signed char* src, int K,
                                           signed char* lds, int tid) {
  int w = tid >> 6, l = tid & 63;
  int sub = l >> 2, seg = (l & 3) * 16;
#pragma unroll
  for (int i = 0; i < ROWS / 64; ++i) {
    int rbase = w * (ROWS / 4) + i * 16;
    gll16(src + (size_t)(rbase + sub) * K + seg, lds + rbase * 64);
  }
}

// ---------------- zero init (compact rowmax) ----------------
__global__ void k_zero(unsigned* __restrict__ rm) {
  int i = blockIdx.x * 256 + threadIdx.x;
  if (i < NRMAX) rm[i] = 0u;
}

// ------------- rmsnorm + per-token absmax + int8 quant + bf16 h (f64 math) -------------
__global__ __launch_bounds__(256) void k_rms_quant(
    const float* __restrict__ x, const float* __restrict__ rw,
    signed char* __restrict__ qh, __hip_bfloat16* __restrict__ hb,
    double* __restrict__ amax_clip) {
  __shared__ double red[12];
  int t = blockIdx.x, tid = threadIdx.x;
  int lane = tid & 63, wid = tid >> 6;
  float4 xv = ((const float4*)(x + (size_t)t * DD))[tid];
  double x0 = xv.x, x1 = xv.y, x2 = xv.z, x3 = xv.w;
  double ss = x0 * x0 + x1 * x1 + x2 * x2 + x3 * x3;
  ss = wave_sum_d(ss);
  if (lane == 0) red[wid] = ss;
  __syncthreads();
  if (tid == 0) {
    double s = red[0] + red[1] + red[2] + red[3];
    red[8] = 1.0 / sqrt(s * (1.0 / DD) + 1e-6);
  }
  __syncthreads();
  double r = red[8];
  float4 wv = ((const float4*)rw)[tid];
  double h0 = x0 * r * (double)wv.x, h1 = x1 * r * (double)wv.y;
  double h2 = x2 * r * (double)wv.z, h3 = x3 * r * (double)wv.w;
  __hip_bfloat16* hp = hb + (size_t)t * DD + tid * 4;
  hp[0] = __float2bfloat16((float)h0); hp[1] = __float2bfloat16((float)h1);
  hp[2] = __float2bfloat16((float)h2); hp[3] = __float2bfloat16((float)h3);
  double am = fmax(fmax(fabs(h0), fabs(h1)), fmax(fabs(h2), fabs(h3)));
  am = wave_max_d(am);
  if (lane == 0) red[4 + wid] = am;
  __syncthreads();
  if (tid == 0) {
    double a = fmax(fmax(red[4], red[5]), fmax(red[6], red[7]));
    red[9] = fmax(a, 1e-5);
  }
  __syncthreads();
  double clipv = red[9];
  if (tid == 0) amax_clip[t] = clipv;
  double s = 127.0 / clipv;
  int q0 = (int)fmin(127.0, fmax(-128.0, rint(h0 * s)));
  int q1 = (int)fmin(127.0, fmax(-128.0, rint(h1 * s)));
  int q2 = (int)fmin(127.0, fmax(-128.0, rint(h2 * s)));
  int q3 = (int)fmin(127.0, fmax(-128.0, rint(h3 * s)));
  unsigned pw = (unsigned)(q0 & 255) | ((unsigned)(q1 & 255) << 8) |
                ((unsigned)(q2 & 255) << 16) | ((unsigned)(q3 & 255) << 24);
  *(unsigned*)(qh + (size_t)t * DD + tid * 4) = pw;
}

// ------------- weight absmean: f64 partial sums, 20 matrices x 128 blocks -------------
__global__ __launch_bounds__(256) void k_wabs_part(
    const float* __restrict__ w1s, const float* __restrict__ w2s,
    const float* __restrict__ w1r, const float* __restrict__ w2r,
    double* __restrict__ part) {
  __shared__ double red[4];
  int m = blockIdx.x >> 7, blk = blockIdx.x & 127;
  const float* base;
  if (m < 2)       base = w1s + (size_t)m * (DD * FF);
  else if (m < 4)  base = w2s + (size_t)(m - 2) * (DD * FF);
  else if (m < 12) base = w1r + (size_t)(m - 4) * (DD * FF);
  else             base = w2r + (size_t)(m - 12) * (DD * FF);
  const f32x4* p = (const f32x4*)base + (size_t)blk * 4096;
  int tid = threadIdx.x;
  double s0 = 0.0, s1 = 0.0, s2 = 0.0, s3 = 0.0;
#pragma unroll
  for (int b = 0; b < 2; ++b) {
    f32x4 v[8];
#pragma unroll
    for (int i = 0; i < 8; ++i)
      v[i] = __builtin_nontemporal_load(p + tid + (b * 8 + i) * 256);
#pragma unroll
    for (int i = 0; i < 8; i += 4) {
      s0 += (double)fabsf(v[i+0].x) + (double)fabsf(v[i+0].y) +
            (double)fabsf(v[i+0].z) + (double)fabsf(v[i+0].w);
      s1 += (double)fabsf(v[i+1].x) + (double)fabsf(v[i+1].y) +
            (double)fabsf(v[i+1].z) + (double)fabsf(v[i+1].w);
      s2 += (double)fabsf(v[i+2].x) + (double)fabsf(v[i+2].y) +
            (double)fabsf(v[i+2].z) + (double)fabsf(v[i+2].w);
      s3 += (double)fabsf(v[i+3].x) + (double)fabsf(v[i+3].y) +
            (double)fabsf(v[i+3].z) + (double)fabsf(v[i+3].w);
    }
  }
  double s = (s0 + s1) + (s2 + s3);
  s = wave_sum_d(s);
  int lane = tid & 63, wid = tid >> 6;
  if (lane == 0) red[wid] = s;
  __syncthreads();
  if (tid == 0) part[m * 128 + blk] = red[0] + red[1] + red[2] + red[3];
}

__global__ __launch_bounds__(64) void k_wscale_final(
    const double* __restrict__ part, double* __restrict__ wscale) {
  int m = blockIdx.x;
  double v = part[m * 128 + threadIdx.x] + part[m * 128 + 64 + threadIdx.x];
  v = wave_sum_d(v);
  if (threadIdx.x == 0) wscale[m] = v * (1.0 / 2097152.0) + 1e-8;
}

// ------------- router: bf16 products, f64 accum, bf16-rounded logits,
//               top-2 (lower-index tie-break), renorm -> dense gates + (i0,i1) ---------
__global__ __launch_bounds__(64) void k_router(
    const __hip_bfloat16* __restrict__ hb, const float* __restrict__ rw,
    float* __restrict__ gates, int2* __restrict__ i01) {
  int t = blockIdx.x, lane = threadIdx.x;
  double acc[8];
#pragma unroll
  for (int e = 0; e < 8; ++e) acc[e] = 0.0;
  const __hip_bfloat16* hp = hb + (size_t)t * DD;
  for (int d = lane; d < DD; d += 64) {
    double hv = (double)__bfloat162float(hp[d]);
#pragma unroll
    for (int e = 0; e < 8; ++e) {
      double wv = (double)__bfloat162float(__float2bfloat16(rw[e * DD + d]));
      acc[e] += hv * wv;
    }
  }
#pragma unroll
  for (int e = 0; e < 8; ++e) acc[e] = wave_sum_d(acc[e]);
  if (lane == 0) {
    double lb[8];
#pragma unroll
    for (int e = 0; e < 8; ++e)
      lb[e] = (double)__bfloat162float(__float2bfloat16((float)acc[e]));
    double mx = lb[0];
#pragma unroll
    for (int e = 1; e < 8; ++e) mx = fmax(mx, lb[e]);
    double p[8];
#pragma unroll
    for (int e = 0; e < 8; ++e) p[e] = exp(lb[e] - mx);
    int i0 = 0;
    for (int e = 1; e < 8; ++e) if (p[e] > p[i0]) i0 = e;
    int i1 = (i0 == 0) ? 1 : 0;
    for (int e = 0; e < 8; ++e) if (e != i0 && p[e] > p[i1]) i1 = e;
    double den = p[i0] + p[i1];
    float o[8] = {0.f, 0.f, 0.f, 0.f, 0.f, 0.f, 0.f, 0.f};
    o[i0] = (float)(p[i0] / den);
    o[i1] = (float)(p[i1] / den);
#pragma unroll
    for (int e = 0; e < 8; ++e) gates[(size_t)t * 8 + e] = o[e];
    i01[t] = make_int2(i0, i1);
  }
}

// ------------- per-expert ordered token lists (ballot prefix compaction) ---------------
__global__ __launch_bounds__(64) void k_lists(
    const int2* __restrict__ i01, int* __restrict__ lists,
    unsigned char* __restrict__ slots, int* __restrict__ cnt) {
  int e = blockIdx.x, lane = threadIdx.x;
  int* le = lists + e * TT;
  unsigned char* se = slots + e * TT;
  int base = 0;
  for (int it = 0; it < TT / 64; ++it) {
    int t = it * 64 + lane;
    int2 r = i01[t];
    bool hit0 = (r.x == e), hit1 = (r.y == e);
    bool hit = hit0 || hit1;
    unsigned long long m = __ballot(hit);
    int pos = base + __popcll(m & ((1ull << lane) - 1ull));
    if (hit) { le[pos] = t; se[pos] = hit0 ? 0 : 1; }
    base += __popcll(m);
  }
  if (lane == 0) cnt[e] = base;
}

// ------------- meta: segment offsets, tile->expert map, per-row gather tables ----------
__global__ __launch_bounds__(256) void k_meta(
    const int* __restrict__ cnt, const int* __restrict__ lists,
    const unsigned char* __restrict__ slots, const double* __restrict__ amax_clip,
    const double* __restrict__ wscale, int* __restrict__ meta,
    int* __restrict__ rowexp, int* __restrict__ tokidx,
    int* __restrict__ wrow, float* __restrict__ srow1c) {
  __shared__ int segs[9];
  __shared__ int scnt[8];
  int tid = threadIdx.x;
  if (tid == 0) {
    int acc = 0;
    for (int e = 0; e < 8; ++e) {
      scnt[e] = cnt[e];
      segs[e] = acc;
      acc += (cnt[e] + 127) & ~127;
    }
    segs[8] = acc;
    meta[0] = 32 + acc / 128;   // total row-tiles
    meta[1] = 4096 + acc;       // total compact rows
  }
  __syncthreads();
  int ntile = 32 + segs[8] / 128;
  for (int j = tid; j < NTILEMAX; j += 256) {
    int ei = -1;
    if (j < 16) ei = 0;
    else if (j < 32) ei = 1;
    else if (j < ntile) {
      int rr = (j - 32) * 128;
      for (int e = 0; e < 8; ++e)
        if (rr >= segs[e] && rr < segs[e + 1]) { ei = 2 + e; break; }
    }
    rowexp[j] = ei;
  }
  for (int r = tid; r < NRMAX; r += 256) {
    int t = 0; float s1 = 0.f; int w = -1;
    if (r < 4096) {
      int e = r >> 11; t = r & (TT - 1);
      double csc = wscale[e] * (1.0 / 127.0);
      s1 = (float)(amax_clip[t] * csc);
      w = e * TT + t;
    } else {
      int rr = r - 4096;
      if (rr < segs[8]) {
        int e = 0;
        for (int q = 0; q < 8; ++q)
          if (rr >= segs[q] && rr < segs[q + 1]) { e = q; break; }
        int k = rr - segs[e];
        if (k < scnt[e]) {
          t = lists[e * TT + k];
          int sl = slots[e * TT + k];
          double csc = wscale[4 + e] * (1.0 / 127.0);
          s1 = (float)(amax_clip[t] * csc);
          w = (2 + sl) * TT + t;
        }
      }
    }
    tokidx[r] = t; srow1c[r] = s1; wrow[r] = w;
  }
}

// ------------- ternary quant helper (f64 bins) -------------
__device__ __forceinline__ int qtern(float v, double winv) {
  double q = rint((double)v * winv);
  return (int)fmin(1.0, fmax(-1.0, q));
}
__device__ __forceinline__ unsigned pack4(int a, int b, int c, int d) {
  return (unsigned)(a & 255) | ((unsigned)(b & 255) << 8) |
         ((unsigned)(c & 255) << 16) | ((unsigned)(d & 255) << 24);
}

// ------------- weight quant + transpose: f32 [R][C] -> i8 W^T [C][R] -------------
__global__ __launch_bounds__(256) void k_wquant(
    const float* __restrict__ w1s, const float* __restrict__ w2s,
    const float* __restrict__ w1r, const float* __restrict__ w2r,
    const double* __restrict__ wscale,
    signed char* __restrict__ q1T, signed char* __restrict__ q2T) {
  __shared__ signed char tile[64 * 68];
  int bid = blockIdx.x;
  int m = bid >> 9, t = bid & 511;
  const float* src;
  signed char* dst;
  int ld, ldo, rt, ct;
  if (m < 2) {
    src = w1s + (size_t)m * DD * FF;
    dst = q1T + (size_t)m * FF * DD;
    ld = FF; ldo = DD; rt = t >> 5; ct = t & 31;
  } else if (m < 4) {
    src = w2s + (size_t)(m - 2) * FF * DD;
    dst = q2T + (size_t)(m - 2) * DD * FF;
    ld = DD; ldo = FF; rt = t >> 4; ct = t & 15;
  } else if (m < 12) {
    src = w1r + (size_t)(m - 4) * DD * FF;
    dst = q1T + (size_t)(m - 2) * FF * DD;
    ld = FF; ldo = DD; rt = t >> 5; ct = t & 31;
  } else {
    src = w2r + (size_t)(m - 12) * FF * DD;
    dst = q2T + (size_t)(m - 10) * DD * FF;
    ld = DD; ldo = FF; rt = t >> 4; ct = t & 15;
  }
  double winv = 1.0 / wscale[m];
  int row0 = rt * 64, col0 = ct * 64;
  int r = threadIdx.x >> 2, sc_ = (threadIdx.x & 3) * 16;
  const float* sp = src + (size_t)(row0 + r) * ld + col0 + sc_;
#pragma unroll
  for (int g = 0; g < 4; ++g) {
    float4 v = *(const float4*)(sp + g * 4);
    unsigned pk = pack4(qtern(v.x, winv), qtern(v.y, winv),
                        qtern(v.z, winv), qtern(v.w, winv));
    *(unsigned*)(tile + r * 68 + sc_ + g * 4) = pk;
  }
  __syncthreads();
  int c = threadIdx.x >> 2, sr = (threadIdx.x & 3) * 16;
  unsigned o[4];
#pragma unroll
  for (int g = 0; g < 4; ++g) {
    int j = sr + g * 4;
    o[g] = pack4(tile[(j + 0) * 68 + c], tile[(j + 1) * 68 + c],
                 tile[(j + 2) * 68 + c], tile[(j + 3) * 68 + c]);
  }
  int4 ov = make_int4((int)o[0], (int)o[1], (int)o[2], (int)o[3]);
  *(int4*)(dst + (size_t)(col0 + c) * ldo + row0 + sr) = ov;
}

// ------------- GEMM1 (compact rows, gathered A): 128x64 tiles, BK=128 sub-tiled ------
// LDS layout: [slice][rows][64B] per operand -> conflict-free 64B-stride reads
// fixed grid (32, CHTILES) = 1152 blocks; bijective XCD swizzle (chunks of 144)
__global__ __launch_bounds__(256) void k_g1(
    const signed char* __restrict__ qh, const signed char* __restrict__ q1T,
    const int* __restrict__ rowexp, const int* __restrict__ tokidx,
    const float* __restrict__ srow1c, const int* __restrict__ meta, int tile0,
    float* __restrict__ abuf_c, unsigned* __restrict__ rowmaxc) {
  __shared__ __align__(16) signed char As[2 * 8192];   // 2 slices x 128 rows x 64B
  __shared__ __align__(16) signed char Bs[2 * 4096];   // 2 slices x 64 rows x 64B
  int lid = blockIdx.x + 32 * blockIdx.y;          // 0..1151
  int nid = (lid & 7) * 144 + (lid >> 3);          // bijective XCD chunks
  int j = tile0 + (nid >> 5);
  if (j >= meta[0]) return;
  int col0 = (nid & 31) * 64;
  int ei = rowexp[j];
  int tid = threadIdx.x, lane = tid & 63, wid = tid >> 6;
  int wr = wid >> 1, wc = wid & 1;
  int rowt0 = j * 128;
  // per-thread gathered A source pointers (k-invariant)
  int sub = lane >> 2, seg = (lane & 3) * 16;
  int sr0 = wid * 32 + sub, sr1 = sr0 + 16;
  const signed char* a0 = qh + (size_t)tokidx[rowt0 + sr0] * DD + seg;
  const signed char* a1 = qh + (size_t)tokidx[rowt0 + sr1] * DD + seg;
  const signed char* b_src = q1T + (size_t)ei * FF * DD + (size_t)col0 * DD;
  signed char* lda0 = As + (wid * 32) * 64;
  signed char* lda1 = As + (wid * 32 + 16) * 64;
  int kg = (lane >> 4) * 16, rsel = lane & 15;
  v4i zero = {0, 0, 0, 0};
  v4i acc[4][2];
#pragma unroll
  for (int i = 0; i < 4; ++i)
#pragma unroll
    for (int jj = 0; jj < 2; ++jj) acc[i][jj] = zero;
  for (int k0 = 0; k0 < DD; k0 += 128) {
    __syncthreads();
#pragma unroll
    for (int c = 0; c < 2; ++c) {
      gll16(a0 + k0 + c * 64, lda0 + c * 8192);
      gll16(a1 + k0 + c * 64, lda1 + c * 8192);
      stage_rows<64>(b_src + k0 + c * 64, DD, Bs + c * 4096, tid);
    }
    __syncthreads();
#pragma unroll
    for (int kk = 0; kk < 2; ++kk) {
      v4i af[4], bf[2];
#pragma unroll
      for (int mi = 0; mi < 4; ++mi)
        af[mi] = *(const v4i*)(As + kk * 8192 + (wr * 64 + mi * 16 + rsel) * 64 + kg);
#pragma unroll
      for (int ni = 0; ni < 2; ++ni)
        bf[ni] = *(const v4i*)(Bs + kk * 4096 + (wc * 32 + ni * 16 + rsel) * 64 + kg);
#pragma unroll
      for (int mi = 0; mi < 4; ++mi)
#pragma unroll
        for (int ni = 0; ni < 2; ++ni)
          acc[mi][ni] = __builtin_amdgcn_mfma_i32_16x16x64_i8(af[mi], bf[ni], acc[mi][ni], 0, 0, 0);
    }
  }
  int rlocal0 = (j - tile0) * 128;
#pragma unroll
  for (int mi = 0; mi < 4; ++mi) {
#pragma unroll
    for (int rg = 0; rg < 4; ++rg) {
      int rof = wr * 64 + mi * 16 + ((lane >> 4) << 2) + rg;
      int tr = rowt0 + rof;
      float sA = srow1c[tr];
      float mloc = 0.f;
      int rl = rlocal0 + rof;
#pragma unroll
      for (int ni = 0; ni < 2; ++ni) {
        int fc = col0 + wc * 32 + ni * 16 + (lane & 15);
        float a = (float)acc[mi][ni][rg] * sA;
        float v = a / (1.f + expf(-a));
        abuf_c[(size_t)rl * FF + fc] = v;
        mloc = fmaxf(mloc, fabsf(v));
      }
#pragma unroll
      for (int o = 1; o < 16; o <<= 1) mloc = fmaxf(mloc, __shfl_xor(mloc, o));
      if ((lane & 15) == 0) atomicMax(rowmaxc + tr, __float_as_uint(mloc));
    }
  }
}

// ------------- aquant (chunk of compact rows) -------------
__global__ __launch_bounds__(256) void k_aq(
    const float* __restrict__ abuf_c, const unsigned* __restrict__ rowmaxc,
    const int* __restrict__ meta, int row0, signed char* __restrict__ qa) {
  int nrows = meta[1] - row0;
  if (nrows > CHROWS) nrows = CHROWS;
  if (nrows < 0) nrows = 0;
  int total4 = nrows * (FF / 4);
  int stride = gridDim.x * 256;
  for (int i = blockIdx.x * 256 + threadIdx.x; i < total4; i += stride) {
    int rl = i >> 9;
    int r = row0 + rl;
    float clip = fmaxf(__uint_as_float(rowmaxc[r]), 1e-5f);
    float s = 127.f / clip;
    float4 v = ((const float4*)abuf_c)[i];
    int q0 = (int)fminf(127.f, fmaxf(-128.f, rintf(v.x * s)));
    int q1 = (int)fminf(127.f, fmaxf(-128.f, rintf(v.y * s)));
    int q2 = (int)fminf(127.f, fmaxf(-128.f, rintf(v.z * s)));
    int q3 = (int)fminf(127.f, fmaxf(-128.f, rintf(v.w * s)));
    ((unsigned*)qa)[(size_t)r * (FF / 4) + (i & 511)] = pack4(q0, q1, q2, q3);
  }
}

// ------------- final gemm2 scale per compact row -------------
__global__ __launch_bounds__(256) void k_scg(
    const unsigned* __restrict__ rowmaxc, const double* __restrict__ wscale,
    const float* __restrict__ gates, const int* __restrict__ tokidx,
    const int* __restrict__ wrow, const int* __restrict__ rowexp,
    float* __restrict__ sgc) {
  int r = blockIdx.x * 256 + threadIdx.x;
  if (r >= NRMAX) return;
  int ei = rowexp[r >> 7];
  int w = wrow[r];
  if (ei < 0 || w < 0) { sgc[r] = 0.f; return; }
  float clip = fmaxf(__uint_as_float(rowmaxc[r]), 1e-5f);
  int t = tokidx[r];
  double csc = wscale[ei < 2 ? ei + 2 : ei + 10] * (1.0 / 127.0);
  float g = (ei < 2) ? 1.f : gates[(size_t)t * 8 + (ei - 2)];
  sgc[r] = (float)((double)clip * csc) * g;
}

// ------------- GEMM2 (compact rows): 128x64 tiles, BK=128 sub-tiled -----------------
// fixed grid (16, NTILEMAX) = 1152 blocks; bijective XCD swizzle (chunks of 144)
__global__ __launch_bounds__(256) void k_g2(
    const signed char* __restrict__ qa, const signed char* __restrict__ q2T,
    const int* __restrict__ rowexp, const float* __restrict__ sgc,
    const int* __restrict__ wrow, const int* __restrict__ meta,
    float* __restrict__ pbuf) {
  __shared__ __align__(16) signed char As[2 * 8192];   // 2 slices x 128 rows x 64B
  __shared__ __align__(16) signed char Bs[2 * 4096];   // 2 slices x 64 rows x 64B
  int lid = blockIdx.x + 16 * blockIdx.y;          // 0..1151
  int nid = (lid & 7) * 144 + (lid >> 3);
  int j = nid >> 4;
  if (j >= meta[0]) return;
  int col0 = (nid & 15) * 64;
  int ei = rowexp[j];
  int tid = threadIdx.x, lane = tid & 63, wid = tid >> 6;
  int wr = wid >> 1, wc = wid & 1;
  const signed char* ap = qa + (size_t)j * 128 * FF;
  const signed char* bp = q2T + (size_t)ei * DD * FF + (size_t)col0 * FF;
  int kg = (lane >> 4) * 16, rsel = lane & 15;
  v4i zero = {0, 0, 0, 0};
  v4i acc[4][2];
#pragma unroll
  for (int i = 0; i < 4; ++i)
#pragma unroll
    for (int jj = 0; jj < 2; ++jj) acc[i][jj] = zero;
  for (int k0 = 0; k0 < FF; k0 += 128) {
    __syncthreads();
#pragma unroll
    for (int c = 0; c < 2; ++c) {
      stage_rows<128>(ap + k0 + c * 64, FF, As + c * 8192, tid);
      stage_rows<64>(bp + k0 + c * 64, FF, Bs + c * 4096, tid);
    }
    __syncthreads();
#pragma unroll
    for (int kk = 0; kk < 2; ++kk) {
      v4i af[4], bf[2];
#pragma unroll
      for (int mi = 0; mi < 4; ++mi)
        af[mi] = *(const v4i*)(As + kk * 8192 + (wr * 64 + mi * 16 + rsel) * 64 + kg);
#pragma unroll
      for (int ni = 0; ni < 2; ++ni)
        bf[ni] = *(const v4i*)(Bs + kk * 4096 + (wc * 32 + ni * 16 + rsel) * 64 + kg);
#pragma unroll
      for (int mi = 0; mi < 4; ++mi)
#pragma unroll
        for (int ni = 0; ni < 2; ++ni)
          acc[mi][ni] = __builtin_amdgcn_mfma_i32_16x16x64_i8(af[mi], bf[ni], acc[mi][ni], 0, 0, 0);
    }
  }
#pragma unroll
  for (int mi = 0; mi < 4; ++mi) {
#pragma unroll
    for (int rg = 0; rg < 4; ++rg) {
      int tr = j * 128 + wr * 64 + mi * 16 + ((lane >> 4) << 2) + rg;
      int w = wrow[tr];
      float sc = sgc[tr];
      if (w >= 0) {
#pragma unroll
        for (int ni = 0; ni < 2; ++ni) {
          int dc = col0 + wc * 32 + ni * 16 + (lane & 15);
          pbuf[(size_t)w * DD + dc] = (float)acc[mi][ni][rg] * sc;
        }
      }
    }
  }
}

// ------------- combine: out = sum of 4 planes -------------
__global__ __launch_bounds__(256) void k_combine(
    const float* __restrict__ pbuf, float* __restrict__ out) {
  int i = blockIdx.x * 256 + threadIdx.x;  // float4 index
  float4 s = ((const float4*)pbuf)[i];
#pragma unroll
  for (int z = 1; z < 4; ++z) {
    float4 v = ((const float4*)(pbuf + (size_t)z * TT * DD))[i];
    s.x += v.x; s.y += v.y; s.z += v.z; s.w += v.w;
  }
  ((float4*)out)[i] = s;
}

extern "C" void kernel_launch(void* const* d_in, const int* in_sizes, int n_in,
                              void* d_out, int out_size, void* d_ws, size_t ws_size,
                              hipStream_t stream) {
  const float* x    = (const float*)d_in[0];
  const float* rmsw = (const float*)d_in[1];
  const float* w1s  = (const float*)d_in[2];
  const float* w2s  = (const float*)d_in[3];
  const float* w1r  = (const float*)d_in[4];
  const float* w2r  = (const float*)d_in[5];
  const float* rw   = (const float*)d_in[6];
  float* out = (float*)d_out;

  char* ws = (char*)d_ws;
  // footprint ends at 0x7E80000 ~= 132.6MB (proven safe)
  double* amax_clip      = (double*)(ws + 0x0000000);   // 16KB
  double* part           = (double*)(ws + 0x0004000);   // 20KB (20*128 f64)
  double* wscale         = (double*)(ws + 0x0018000);   // 160B
  float* gates           = (float*)(ws + 0x0019000);    // 64KB
  int2* i01              = (int2*)(ws + 0x0029000);     // 16KB
  int* lists             = (int*)(ws + 0x002D000);      // 64KB
  unsigned char* slots   = (unsigned char*)(ws + 0x003D000); // 16KB
  int* cnt               = (int*)(ws + 0x0041000);      // 32B
  int* meta              = (int*)(ws + 0x0041100);      // 64B
  int* tokidx            = (int*)(ws + 0x0042000);      // 36KB
  int* wrow              = (int*)(ws + 0x004B000);      // 36KB
  float* srow1c          = (float*)(ws + 0x0054000);    // 36KB
  float* sgc             = (float*)(ws + 0x005D000);    // 36KB
  int* rowexp            = (int*)(ws + 0x0066000);      // 288B
  unsigned* rowmaxc      = (unsigned*)(ws + 0x0067000); // 36KB
  signed char* qh        = (signed char*)(ws + 0x0080000);    // 2MB
  __hip_bfloat16* hb     = (__hip_bfloat16*)(ws + 0x0280000); // 4MB
  signed char* q1T       = (signed char*)(ws + 0x0680000);    // 20MB
  signed char* q2T       = (signed char*)(ws + 0x1A80000);    // 20MB
  signed char* qa        = (signed char*)(ws + 0x2E80000);    // <=18.9MB (40MB region)
  float* pbuf            = (float*)(ws + 0x5680000);          // 4 planes = 32MB (40MB region)
  float* abuf_c          = pbuf;  // alias: chunk buffer (37.7MB) used before g2 writes pbuf

  k_zero<<<(NRMAX + 255) / 256, 256, 0, stream>>>(rowmaxc);
  k_rms_quant<<<TT, 256, 0, stream>>>(x, rmsw, qh, hb, amax_clip);
  k_wabs_part<<<20 * 128, 256, 0, stream>>>(w1s, w2s, w1r, w2r, part);
  k_wscale_final<<<20, 64, 0, stream>>>(part, wscale);
  k_router<<<TT, 64, 0, stream>>>(hb, rw, gates, i01);
  k_lists<<<8, 64, 0, stream>>>(i01, lists, slots, cnt);
  k_wquant<<<20 * 512, 256, 0, stream>>>(w1s, w2s, w1r, w2r, wscale, q1T, q2T);
  k_meta<<<1, 256, 0, stream>>>(cnt, lists, slots, amax_clip, wscale,
                                meta, rowexp, tokidx, wrow, srow1c);

  dim3 g1(32, CHTILES);
  k_g1<<<g1, 256, 0, stream>>>(qh, q1T, rowexp, tokidx, srow1c, meta, 0,
                               abuf_c, rowmaxc);
  k_aq<<<2048, 256, 0, stream>>>(abuf_c, rowmaxc, meta, 0, qa);
  k_g1<<<g1, 256, 0, stream>>>(qh, q1T, rowexp, tokidx, srow1c, meta, CHTILES,
                               abuf_c, rowmaxc);
  k_aq<<<2048, 256, 0, stream>>>(abuf_c, rowmaxc, meta, CHROWS, qa);

  k_scg<<<(NRMAX + 255) / 256, 256, 0, stream>>>(rowmaxc, wscale, gates,
                                                 tokidx, wrow, rowexp, sgc);
  dim3 g2(16, NTILEMAX);
  k_g2<<<g2, 256, 0, stream>>>(qa, q2T, rowexp, sgc, wrow, meta, pbuf);
  k_combine<<<TT * DD / 4 / 256, 256, 0, stream>>>(pbuf, out);
}

// Round 18
// 249.410 us; speedup vs baseline: 1.2878x; 1.0161x over previous
//
#include <hip/hip_runtime.h>
#include <hip/hip_bf16.h>

#define TT 2048
#define DD 1024
#define FF 2048
#define NEXPI 10     // 2 shared + 8 routed expert instances
#define NRMAX 9216   // max compact rows: 4096 shared + 4096 routed + <=1024 pad
#define NTILEMAX 72  // NRMAX/128
#define CHTILES 36   // row-tiles per gemm1 chunk
#define CHROWS (CHTILES * 128)

typedef __attribute__((ext_vector_type(4))) int v4i;
typedef __attribute__((ext_vector_type(4))) float f32x4;

__device__ __forceinline__ double wave_sum_d(double v) {
#pragma unroll
  for (int o = 32; o > 0; o >>= 1) v += __shfl_down(v, o);
  return v;
}
__device__ __forceinline__ double wave_max_d(double v) {
#pragma unroll
  for (int o = 32; o > 0; o >>= 1) v = fmax(v, __shfl_down(v, o));
  return v;
}

// async global->LDS, 16B per lane; lds dest is wave-uniform base, lane l lands at +l*16
__device__ __forceinline__ void gll16(const void* g, void* l) {
  __builtin_amdgcn_global_load_lds(
      (const __attribute__((address_space(1))) void*)g,
      (__attribute__((address_space(3))) void*)l, 16, 0, 0);
}

// stage ROWS x 64B tile (i8, row stride K bytes in global) into linear LDS
template<int ROWS>
__device__ __forceinline__ void stage_rows(const signed char* src, int K,
                                           signed char* lds, int tid) {
  int w = tid >> 6, l = tid & 63;
  int sub = l >> 2, seg = (l & 3) * 16;
#pragma unroll
  for (int i = 0; i < ROWS / 64; ++i) {
    int rbase = w * (ROWS / 4) + i * 16;
    gll16(src + (size_t)(rbase + sub) * K + seg, lds + rbase * 64);
  }
}

// ---------------- zero init (compact rowmax) ----------------
__global__ void k_zero(unsigned* __restrict__ rm) {
  int i = blockIdx.x * 256 + threadIdx.x;
  if (i < NRMAX) rm[i] = 0u;
}

// ------------- rmsnorm + per-token absmax + int8 quant + bf16 h (f64 math) -------------
__global__ __launch_bounds__(256) void k_rms_quant(
    const float* __restrict__ x, const float* __restrict__ rw,
    signed char* __restrict__ qh, __hip_bfloat16* __restrict__ hb,
    double* __restrict__ amax_clip) {
  __shared__ double red[12];
  int t = blockIdx.x, tid = threadIdx.x;
  int lane = tid & 63, wid = tid >> 6;
  float4 xv = ((const float4*)(x + (size_t)t * DD))[tid];
  double x0 = xv.x, x1 = xv.y, x2 = xv.z, x3 = xv.w;
  double ss = x0 * x0 + x1 * x1 + x2 * x2 + x3 * x3;
  ss = wave_sum_d(ss);
  if (lane == 0) red[wid] = ss;
  __syncthreads();
  if (tid == 0) {
    double s = red[0] + red[1] + red[2] + red[3];
    red[8] = 1.0 / sqrt(s * (1.0 / DD) + 1e-6);
  }
  __syncthreads();
  double r = red[8];
  float4 wv = ((const float4*)rw)[tid];
  double h0 = x0 * r * (double)wv.x, h1 = x1 * r * (double)wv.y;
  double h2 = x2 * r * (double)wv.z, h3 = x3 * r * (double)wv.w;
  __hip_bfloat16* hp = hb + (size_t)t * DD + tid * 4;
  hp[0] = __float2bfloat16((float)h0); hp[1] = __float2bfloat16((float)h1);
  hp[2] = __float2bfloat16((float)h2); hp[3] = __float2bfloat16((float)h3);
  double am = fmax(fmax(fabs(h0), fabs(h1)), fmax(fabs(h2), fabs(h3)));
  am = wave_max_d(am);
  if (lane == 0) red[4 + wid] = am;
  __syncthreads();
  if (tid == 0) {
    double a = fmax(fmax(red[4], red[5]), fmax(red[6], red[7]));
    red[9] = fmax(a, 1e-5);
  }
  __syncthreads();
  double clipv = red[9];
  if (tid == 0) amax_clip[t] = clipv;
  double s = 127.0 / clipv;
  int q0 = (int)fmin(127.0, fmax(-128.0, rint(h0 * s)));
  int q1 = (int)fmin(127.0, fmax(-128.0, rint(h1 * s)));
  int q2 = (int)fmin(127.0, fmax(-128.0, rint(h2 * s)));
  int q3 = (int)fmin(127.0, fmax(-128.0, rint(h3 * s)));
  unsigned pw = (unsigned)(q0 & 255) | ((unsigned)(q1 & 255) << 8) |
                ((unsigned)(q2 & 255) << 16) | ((unsigned)(q3 & 255) << 24);
  *(unsigned*)(qh + (size_t)t * DD + tid * 4) = pw;
}

// ------------- weight absmean: f64 partial sums, 20 matrices x 128 blocks -------------
__global__ __launch_bounds__(256) void k_wabs_part(
    const float* __restrict__ w1s, const float* __restrict__ w2s,
    const float* __restrict__ w1r, const float* __restrict__ w2r,
    double* __restrict__ part) {
  __shared__ double red[4];
  int m = blockIdx.x >> 7, blk = blockIdx.x & 127;
  const float* base;
  if (m < 2)       base = w1s + (size_t)m * (DD * FF);
  else if (m < 4)  base = w2s + (size_t)(m - 2) * (DD * FF);
  else if (m < 12) base = w1r + (size_t)(m - 4) * (DD * FF);
  else             base = w2r + (size_t)(m - 12) * (DD * FF);
  const f32x4* p = (const f32x4*)base + (size_t)blk * 4096;
  int tid = threadIdx.x;
  double s0 = 0.0, s1 = 0.0, s2 = 0.0, s3 = 0.0;
#pragma unroll
  for (int b = 0; b < 2; ++b) {
    f32x4 v[8];
#pragma unroll
    for (int i = 0; i < 8; ++i)
      v[i] = __builtin_nontemporal_load(p + tid + (b * 8 + i) * 256);
#pragma unroll
    for (int i = 0; i < 8; i += 4) {
      s0 += (double)fabsf(v[i+0].x) + (double)fabsf(v[i+0].y) +
            (double)fabsf(v[i+0].z) + (double)fabsf(v[i+0].w);
      s1 += (double)fabsf(v[i+1].x) + (double)fabsf(v[i+1].y) +
            (double)fabsf(v[i+1].z) + (double)fabsf(v[i+1].w);
      s2 += (double)fabsf(v[i+2].x) + (double)fabsf(v[i+2].y) +
            (double)fabsf(v[i+2].z) + (double)fabsf(v[i+2].w);
      s3 += (double)fabsf(v[i+3].x) + (double)fabsf(v[i+3].y) +
            (double)fabsf(v[i+3].z) + (double)fabsf(v[i+3].w);
    }
  }
  double s = (s0 + s1) + (s2 + s3);
  s = wave_sum_d(s);
  int lane = tid & 63, wid = tid >> 6;
  if (lane == 0) red[wid] = s;
  __syncthreads();
  if (tid == 0) part[m * 128 + blk] = red[0] + red[1] + red[2] + red[3];
}

__global__ __launch_bounds__(64) void k_wscale_final(
    const double* __restrict__ part, double* __restrict__ wscale) {
  int m = blockIdx.x;
  double v = part[m * 128 + threadIdx.x] + part[m * 128 + 64 + threadIdx.x];
  v = wave_sum_d(v);
  if (threadIdx.x == 0) wscale[m] = v * (1.0 / 2097152.0) + 1e-8;
}

// ------------- router: bf16 products, f64 accum, bf16-rounded logits,
//               top-2 (lower-index tie-break), renorm -> dense gates + (i0,i1) ---------
__global__ __launch_bounds__(64) void k_router(
    const __hip_bfloat16* __restrict__ hb, const float* __restrict__ rw,
    float* __restrict__ gates, int2* __restrict__ i01) {
  int t = blockIdx.x, lane = threadIdx.x;
  double acc[8];
#pragma unroll
  for (int e = 0; e < 8; ++e) acc[e] = 0.0;
  const __hip_bfloat16* hp = hb + (size_t)t * DD;
  for (int d = lane; d < DD; d += 64) {
    double hv = (double)__bfloat162float(hp[d]);
#pragma unroll
    for (int e = 0; e < 8; ++e) {
      double wv = (double)__bfloat162float(__float2bfloat16(rw[e * DD + d]));
      acc[e] += hv * wv;
    }
  }
#pragma unroll
  for (int e = 0; e < 8; ++e) acc[e] = wave_sum_d(acc[e]);
  if (lane == 0) {
    double lb[8];
#pragma unroll
    for (int e = 0; e < 8; ++e)
      lb[e] = (double)__bfloat162float(__float2bfloat16((float)acc[e]));
    double mx = lb[0];
#pragma unroll
    for (int e = 1; e < 8; ++e) mx = fmax(mx, lb[e]);
    double p[8];
#pragma unroll
    for (int e = 0; e < 8; ++e) p[e] = exp(lb[e] - mx);
    int i0 = 0;
    for (int e = 1; e < 8; ++e) if (p[e] > p[i0]) i0 = e;
    int i1 = (i0 == 0) ? 1 : 0;
    for (int e = 0; e < 8; ++e) if (e != i0 && p[e] > p[i1]) i1 = e;
    double den = p[i0] + p[i1];
    float o[8] = {0.f, 0.f, 0.f, 0.f, 0.f, 0.f, 0.f, 0.f};
    o[i0] = (float)(p[i0] / den);
    o[i1] = (float)(p[i1] / den);
#pragma unroll
    for (int e = 0; e < 8; ++e) gates[(size_t)t * 8 + e] = o[e];
    i01[t] = make_int2(i0, i1);
  }
}

// ------------- per-expert ordered token lists (ballot prefix compaction) ---------------
__global__ __launch_bounds__(64) void k_lists(
    const int2* __restrict__ i01, int* __restrict__ lists,
    unsigned char* __restrict__ slots, int* __restrict__ cnt) {
  int e = blockIdx.x, lane = threadIdx.x;
  int* le = lists + e * TT;
  unsigned char* se = slots + e * TT;
  int base = 0;
  for (int it = 0; it < TT / 64; ++it) {
    int t = it * 64 + lane;
    int2 r = i01[t];
    bool hit0 = (r.x == e), hit1 = (r.y == e);
    bool hit = hit0 || hit1;
    unsigned long long m = __ballot(hit);
    int pos = base + __popcll(m & ((1ull << lane) - 1ull));
    if (hit) { le[pos] = t; se[pos] = hit0 ? 0 : 1; }
    base += __popcll(m);
  }
  if (lane == 0) cnt[e] = base;
}

// ------------- meta: segment offsets, tile->expert map, per-row gather tables ----------
__global__ __launch_bounds__(256) void k_meta(
    const int* __restrict__ cnt, const int* __restrict__ lists,
    const unsigned char* __restrict__ slots, const double* __restrict__ amax_clip,
    const double* __restrict__ wscale, int* __restrict__ meta,
    int* __restrict__ rowexp, int* __restrict__ tokidx,
    int* __restrict__ wrow, float* __restrict__ srow1c) {
  __shared__ int segs[9];
  __shared__ int scnt[8];
  int tid = threadIdx.x;
  if (tid == 0) {
    int acc = 0;
    for (int e = 0; e < 8; ++e) {
      scnt[e] = cnt[e];
      segs[e] = acc;
      acc += (cnt[e] + 127) & ~127;
    }
    segs[8] = acc;
    meta[0] = 32 + acc / 128;   // total row-tiles
    meta[1] = 4096 + acc;       // total compact rows
  }
  __syncthreads();
  int ntile = 32 + segs[8] / 128;
  for (int j = tid; j < NTILEMAX; j += 256) {
    int ei = -1;
    if (j < 16) ei = 0;
    else if (j < 32) ei = 1;
    else if (j < ntile) {
      int rr = (j - 32) * 128;
      for (int e = 0; e < 8; ++e)
        if (rr >= segs[e] && rr < segs[e + 1]) { ei = 2 + e; break; }
    }
    rowexp[j] = ei;
  }
  for (int r = tid; r < NRMAX; r += 256) {
    int t = 0; float s1 = 0.f; int w = -1;
    if (r < 4096) {
      int e = r >> 11; t = r & (TT - 1);
      double csc = wscale[e] * (1.0 / 127.0);
      s1 = (float)(amax_clip[t] * csc);
      w = e * TT + t;
    } else {
      int rr = r - 4096;
      if (rr < segs[8]) {
        int e = 0;
        for (int q = 0; q < 8; ++q)
          if (rr >= segs[q] && rr < segs[q + 1]) { e = q; break; }
        int k = rr - segs[e];
        if (k < scnt[e]) {
          t = lists[e * TT + k];
          int sl = slots[e * TT + k];
          double csc = wscale[4 + e] * (1.0 / 127.0);
          s1 = (float)(amax_clip[t] * csc);
          w = (2 + sl) * TT + t;
        }
      }
    }
    tokidx[r] = t; srow1c[r] = s1; wrow[r] = w;
  }
}

// ------------- ternary quant helper (f64 bins) -------------
__device__ __forceinline__ int qtern(float v, double winv) {
  double q = rint((double)v * winv);
  return (int)fmin(1.0, fmax(-1.0, q));
}
__device__ __forceinline__ unsigned pack4(int a, int b, int c, int d) {
  return (unsigned)(a & 255) | ((unsigned)(b & 255) << 8) |
         ((unsigned)(c & 255) << 16) | ((unsigned)(d & 255) << 24);
}

// ------------- weight quant + transpose: f32 [R][C] -> i8 W^T [C][R] -------------
__global__ __launch_bounds__(256) void k_wquant(
    const float* __restrict__ w1s, const float* __restrict__ w2s,
    const float* __restrict__ w1r, const float* __restrict__ w2r,
    const double* __restrict__ wscale,
    signed char* __restrict__ q1T, signed char* __restrict__ q2T) {
  __shared__ signed char tile[64 * 68];
  int bid = blockIdx.x;
  int m = bid >> 9, t = bid & 511;
  const float* src;
  signed char* dst;
  int ld, ldo, rt, ct;
  if (m < 2) {
    src = w1s + (size_t)m * DD * FF;
    dst = q1T + (size_t)m * FF * DD;
    ld = FF; ldo = DD; rt = t >> 5; ct = t & 31;
  } else if (m < 4) {
    src = w2s + (size_t)(m - 2) * FF * DD;
    dst = q2T + (size_t)(m - 2) * DD * FF;
    ld = DD; ldo = FF; rt = t >> 4; ct = t & 15;
  } else if (m < 12) {
    src = w1r + (size_t)(m - 4) * DD * FF;
    dst = q1T + (size_t)(m - 2) * FF * DD;
    ld = FF; ldo = DD; rt = t >> 5; ct = t & 31;
  } else {
    src = w2r + (size_t)(m - 12) * FF * DD;
    dst = q2T + (size_t)(m - 10) * DD * FF;
    ld = DD; ldo = FF; rt = t >> 4; ct = t & 15;
  }
  double winv = 1.0 / wscale[m];
  int row0 = rt * 64, col0 = ct * 64;
  int r = threadIdx.x >> 2, sc_ = (threadIdx.x & 3) * 16;
  const float* sp = src + (size_t)(row0 + r) * ld + col0 + sc_;
#pragma unroll
  for (int g = 0; g < 4; ++g) {
    float4 v = *(const float4*)(sp + g * 4);
    unsigned pk = pack4(qtern(v.x, winv), qtern(v.y, winv),
                        qtern(v.z, winv), qtern(v.w, winv));
    *(unsigned*)(tile + r * 68 + sc_ + g * 4) = pk;
  }
  __syncthreads();
  int c = threadIdx.x >> 2, sr = (threadIdx.x & 3) * 16;
  unsigned o[4];
#pragma unroll
  for (int g = 0; g < 4; ++g) {
    int j = sr + g * 4;
    o[g] = pack4(tile[(j + 0) * 68 + c], tile[(j + 1) * 68 + c],
                 tile[(j + 2) * 68 + c], tile[(j + 3) * 68 + c]);
  }
  int4 ov = make_int4((int)o[0], (int)o[1], (int)o[2], (int)o[3]);
  *(int4*)(dst + (size_t)(col0 + c) * ldo + row0 + sr) = ov;
}

// ------------- GEMM1 (compact rows, gathered A): 128x64 tiles, BK=128 sub-tiled ------
// abuf output in bf16 (halves round-trip traffic); rowmax from bf16-rounded values
// fixed grid (32, CHTILES) = 1152 blocks; bijective XCD swizzle (chunks of 144)
__global__ __launch_bounds__(256) void k_g1(
    const signed char* __restrict__ qh, const signed char* __restrict__ q1T,
    const int* __restrict__ rowexp, const int* __restrict__ tokidx,
    const float* __restrict__ srow1c, const int* __restrict__ meta, int tile0,
    __hip_bfloat16* __restrict__ abuf_c, unsigned* __restrict__ rowmaxc) {
  __shared__ __align__(16) signed char As[2 * 8192];   // 2 slices x 128 rows x 64B
  __shared__ __align__(16) signed char Bs[2 * 4096];   // 2 slices x 64 rows x 64B
  int lid = blockIdx.x + 32 * blockIdx.y;          // 0..1151
  int nid = (lid & 7) * 144 + (lid >> 3);          // bijective XCD chunks
  int j = tile0 + (nid >> 5);
  if (j >= meta[0]) return;
  int col0 = (nid & 31) * 64;
  int ei = rowexp[j];
  int tid = threadIdx.x, lane = tid & 63, wid = tid >> 6;
  int wr = wid >> 1, wc = wid & 1;
  int rowt0 = j * 128;
  // per-thread gathered A source pointers (k-invariant)
  int sub = lane >> 2, seg = (lane & 3) * 16;
  int sr0 = wid * 32 + sub, sr1 = sr0 + 16;
  const signed char* a0 = qh + (size_t)tokidx[rowt0 + sr0] * DD + seg;
  const signed char* a1 = qh + (size_t)tokidx[rowt0 + sr1] * DD + seg;
  const signed char* b_src = q1T + (size_t)ei * FF * DD + (size_t)col0 * DD;
  signed char* lda0 = As + (wid * 32) * 64;
  signed char* lda1 = As + (wid * 32 + 16) * 64;
  int kg = (lane >> 4) * 16, rsel = lane & 15;
  v4i zero = {0, 0, 0, 0};
  v4i acc[4][2];
#pragma unroll
  for (int i = 0; i < 4; ++i)
#pragma unroll
    for (int jj = 0; jj < 2; ++jj) acc[i][jj] = zero;
  for (int k0 = 0; k0 < DD; k0 += 128) {
    __syncthreads();
#pragma unroll
    for (int c = 0; c < 2; ++c) {
      gll16(a0 + k0 + c * 64, lda0 + c * 8192);
      gll16(a1 + k0 + c * 64, lda1 + c * 8192);
      stage_rows<64>(b_src + k0 + c * 64, DD, Bs + c * 4096, tid);
    }
    __syncthreads();
#pragma unroll
    for (int kk = 0; kk < 2; ++kk) {
      v4i af[4], bf[2];
#pragma unroll
      for (int mi = 0; mi < 4; ++mi)
        af[mi] = *(const v4i*)(As + kk * 8192 + (wr * 64 + mi * 16 + rsel) * 64 + kg);
#pragma unroll
      for (int ni = 0; ni < 2; ++ni)
        bf[ni] = *(const v4i*)(Bs + kk * 4096 + (wc * 32 + ni * 16 + rsel) * 64 + kg);
#pragma unroll
      for (int mi = 0; mi < 4; ++mi)
#pragma unroll
        for (int ni = 0; ni < 2; ++ni)
          acc[mi][ni] = __builtin_amdgcn_mfma_i32_16x16x64_i8(af[mi], bf[ni], acc[mi][ni], 0, 0, 0);
    }
  }
  int rlocal0 = (j - tile0) * 128;
#pragma unroll
  for (int mi = 0; mi < 4; ++mi) {
#pragma unroll
    for (int rg = 0; rg < 4; ++rg) {
      int rof = wr * 64 + mi * 16 + ((lane >> 4) << 2) + rg;
      int tr = rowt0 + rof;
      float sA = srow1c[tr];
      float mloc = 0.f;
      int rl = rlocal0 + rof;
#pragma unroll
      for (int ni = 0; ni < 2; ++ni) {
        int fc = col0 + wc * 32 + ni * 16 + (lane & 15);
        float a = (float)acc[mi][ni][rg] * sA;
        float v = a / (1.f + expf(-a));
        __hip_bfloat16 vb = __float2bfloat16(v);
        float vq = __bfloat162float(vb);
        abuf_c[(size_t)rl * FF + fc] = vb;
        mloc = fmaxf(mloc, fabsf(vq));
      }
#pragma unroll
      for (int o = 1; o < 16; o <<= 1) mloc = fmaxf(mloc, __shfl_xor(mloc, o));
      if ((lane & 15) == 0) atomicMax(rowmaxc + tr, __float_as_uint(mloc));
    }
  }
}

// ------------- aquant (chunk of compact rows, bf16 input) -------------
__global__ __launch_bounds__(256) void k_aq(
    const __hip_bfloat16* __restrict__ abuf_c, const unsigned* __restrict__ rowmaxc,
    const int* __restrict__ meta, int row0, signed char* __restrict__ qa) {
  int nrows = meta[1] - row0;
  if (nrows > CHROWS) nrows = CHROWS;
  if (nrows < 0) nrows = 0;
  int total4 = nrows * (FF / 4);
  int stride = gridDim.x * 256;
  for (int i = blockIdx.x * 256 + threadIdx.x; i < total4; i += stride) {
    int rl = i >> 9;
    int r = row0 + rl;
    float clip = fmaxf(__uint_as_float(rowmaxc[r]), 1e-5f);
    float s = 127.f / clip;
    ushort4 raw = ((const ushort4*)abuf_c)[i];
    float vx = __bfloat162float(*(__hip_bfloat16*)&raw.x);
    float vy = __bfloat162float(*(__hip_bfloat16*)&raw.y);
    float vz = __bfloat162float(*(__hip_bfloat16*)&raw.z);
    float vw = __bfloat162float(*(__hip_bfloat16*)&raw.w);
    int q0 = (int)fminf(127.f, fmaxf(-128.f, rintf(vx * s)));
    int q1 = (int)fminf(127.f, fmaxf(-128.f, rintf(vy * s)));
    int q2 = (int)fminf(127.f, fmaxf(-128.f, rintf(vz * s)));
    int q3 = (int)fminf(127.f, fmaxf(-128.f, rintf(vw * s)));
    ((unsigned*)qa)[(size_t)r * (FF / 4) + (i & 511)] = pack4(q0, q1, q2, q3);
  }
}

// ------------- final gemm2 scale per compact row -------------
__global__ __launch_bounds__(256) void k_scg(
    const unsigned* __restrict__ rowmaxc, const double* __restrict__ wscale,
    const float* __restrict__ gates, const int* __restrict__ tokidx,
    const int* __restrict__ wrow, const int* __restrict__ rowexp,
    float* __restrict__ sgc) {
  int r = blockIdx.x * 256 + threadIdx.x;
  if (r >= NRMAX) return;
  int ei = rowexp[r >> 7];
  int w = wrow[r];
  if (ei < 0 || w < 0) { sgc[r] = 0.f; return; }
  float clip = fmaxf(__uint_as_float(rowmaxc[r]), 1e-5f);
  int t = tokidx[r];
  double csc = wscale[ei < 2 ? ei + 2 : ei + 10] * (1.0 / 127.0);
  float g = (ei < 2) ? 1.f : gates[(size_t)t * 8 + (ei - 2)];
  sgc[r] = (float)((double)clip * csc) * g;
}

// ------------- GEMM2 (compact rows): 128x64 tiles, BK=128 sub-tiled -----------------
// fixed grid (16, NTILEMAX) = 1152 blocks; bijective XCD swizzle (chunks of 144)
__global__ __launch_bounds__(256) void k_g2(
    const signed char* __restrict__ qa, const signed char* __restrict__ q2T,
    const int* __restrict__ rowexp, const float* __restrict__ sgc,
    const int* __restrict__ wrow, const int* __restrict__ meta,
    float* __restrict__ pbuf) {
  __shared__ __align__(16) signed char As[2 * 8192];   // 2 slices x 128 rows x 64B
  __shared__ __align__(16) signed char Bs[2 * 4096];   // 2 slices x 64 rows x 64B
  int lid = blockIdx.x + 16 * blockIdx.y;          // 0..1151
  int nid = (lid & 7) * 144 + (lid >> 3);
  int j = nid >> 4;
  if (j >= meta[0]) return;
  int col0 = (nid & 15) * 64;
  int ei = rowexp[j];
  int tid = threadIdx.x, lane = tid & 63, wid = tid >> 6;
  int wr = wid >> 1, wc = wid & 1;
  const signed char* ap = qa + (size_t)j * 128 * FF;
  const signed char* bp = q2T + (size_t)ei * DD * FF + (size_t)col0 * FF;
  int kg = (lane >> 4) * 16, rsel = lane & 15;
  v4i zero = {0, 0, 0, 0};
  v4i acc[4][2];
#pragma unroll
  for (int i = 0; i < 4; ++i)
#pragma unroll
    for (int jj = 0; jj < 2; ++jj) acc[i][jj] = zero;
  for (int k0 = 0; k0 < FF; k0 += 128) {
    __syncthreads();
#pragma unroll
    for (int c = 0; c < 2; ++c) {
      stage_rows<128>(ap + k0 + c * 64, FF, As + c * 8192, tid);
      stage_rows<64>(bp + k0 + c * 64, FF, Bs + c * 4096, tid);
    }
    __syncthreads();
#pragma unroll
    for (int kk = 0; kk < 2; ++kk) {
      v4i af[4], bf[2];
#pragma unroll
      for (int mi = 0; mi < 4; ++mi)
        af[mi] = *(const v4i*)(As + kk * 8192 + (wr * 64 + mi * 16 + rsel) * 64 + kg);
#pragma unroll
      for (int ni = 0; ni < 2; ++ni)
        bf[ni] = *(const v4i*)(Bs + kk * 4096 + (wc * 32 + ni * 16 + rsel) * 64 + kg);
#pragma unroll
      for (int mi = 0; mi < 4; ++mi)
#pragma unroll
        for (int ni = 0; ni < 2; ++ni)
          acc[mi][ni] = __builtin_amdgcn_mfma_i32_16x16x64_i8(af[mi], bf[ni], acc[mi][ni], 0, 0, 0);
    }
  }
#pragma unroll
  for (int mi = 0; mi < 4; ++mi) {
#pragma unroll
    for (int rg = 0; rg < 4; ++rg) {
      int tr = j * 128 + wr * 64 + mi * 16 + ((lane >> 4) << 2) + rg;
      int w = wrow[tr];
      float sc = sgc[tr];
      if (w >= 0) {
#pragma unroll
        for (int ni = 0; ni < 2; ++ni) {
          int dc = col0 + wc * 32 + ni * 16 + (lane & 15);
          pbuf[(size_t)w * DD + dc] = (float)acc[mi][ni][rg] * sc;
        }
      }
    }
  }
}

// ------------- combine: out = sum of 4 planes -------------
__global__ __launch_bounds__(256) void k_combine(
    const float* __restrict__ pbuf, float* __restrict__ out) {
  int i = blockIdx.x * 256 + threadIdx.x;  // float4 index
  float4 s = ((const float4*)pbuf)[i];
#pragma unroll
  for (int z = 1; z < 4; ++z) {
    float4 v = ((const float4*)(pbuf + (size_t)z * TT * DD))[i];
    s.x += v.x; s.y += v.y; s.z += v.z; s.w += v.w;
  }
  ((float4*)out)[i] = s;
}

extern "C" void kernel_launch(void* const* d_in, const int* in_sizes, int n_in,
                              void* d_out, int out_size, void* d_ws, size_t ws_size,
                              hipStream_t stream) {
  const float* x    = (const float*)d_in[0];
  const float* rmsw = (const float*)d_in[1];
  const float* w1s  = (const float*)d_in[2];
  const float* w2s  = (const float*)d_in[3];
  const float* w1r  = (const float*)d_in[4];
  const float* w2r  = (const float*)d_in[5];
  const float* rw   = (const float*)d_in[6];
  float* out = (float*)d_out;

  char* ws = (char*)d_ws;
  // footprint ends at 0x7E80000 ~= 132.6MB (proven safe)
  double* amax_clip      = (double*)(ws + 0x0000000);   // 16KB
  double* part           = (double*)(ws + 0x0004000);   // 20KB (20*128 f64)
  double* wscale         = (double*)(ws + 0x0018000);   // 160B
  float* gates           = (float*)(ws + 0x0019000);    // 64KB
  int2* i01              = (int2*)(ws + 0x0029000);     // 16KB
  int* lists             = (int*)(ws + 0x002D000);      // 64KB
  unsigned char* slots   = (unsigned char*)(ws + 0x003D000); // 16KB
  int* cnt               = (int*)(ws + 0x0041000);      // 32B
  int* meta              = (int*)(ws + 0x0041100);      // 64B
  int* tokidx            = (int*)(ws + 0x0042000);      // 36KB
  int* wrow              = (int*)(ws + 0x004B000);      // 36KB
  float* srow1c          = (float*)(ws + 0x0054000);    // 36KB
  float* sgc             = (float*)(ws + 0x005D000);    // 36KB
  int* rowexp            = (int*)(ws + 0x0066000);      // 288B
  unsigned* rowmaxc      = (unsigned*)(ws + 0x0067000); // 36KB
  signed char* qh        = (signed char*)(ws + 0x0080000);    // 2MB
  __hip_bfloat16* hb     = (__hip_bfloat16*)(ws + 0x0280000); // 4MB
  signed char* q1T       = (signed char*)(ws + 0x0680000);    // 20MB
  signed char* q2T       = (signed char*)(ws + 0x1A80000);    // 20MB
  signed char* qa        = (signed char*)(ws + 0x2E80000);    // <=18.9MB (40MB region)
  float* pbuf            = (float*)(ws + 0x5680000);          // 4 planes = 32MB (40MB region)
  __hip_bfloat16* abuf_c = (__hip_bfloat16*)pbuf;  // alias: bf16 chunk (18.9MB) used before g2 writes pbuf

  k_zero<<<(NRMAX + 255) / 256, 256, 0, stream>>>(rowmaxc);
  k_rms_quant<<<TT, 256, 0, stream>>>(x, rmsw, qh, hb, amax_clip);
  k_wabs_part<<<20 * 128, 256, 0, stream>>>(w1s, w2s, w1r, w2r, part);
  k_wscale_final<<<20, 64, 0, stream>>>(part, wscale);
  k_router<<<TT, 64, 0, stream>>>(hb, rw, gates, i01);
  k_lists<<<8, 64, 0, stream>>>(i01, lists, slots, cnt);
  k_wquant<<<20 * 512, 256, 0, stream>>>(w1s, w2s, w1r, w2r, wscale, q1T, q2T);
  k_meta<<<1, 256, 0, stream>>>(cnt, lists, slots, amax_clip, wscale,
                                meta, rowexp, tokidx, wrow, srow1c);

  dim3 g1(32, CHTILES);
  k_g1<<<g1, 256, 0, stream>>>(qh, q1T, rowexp, tokidx, srow1c, meta, 0,
                               abuf_c, rowmaxc);
  k_aq<<<2048, 256, 0, stream>>>(abuf_c, rowmaxc, meta, 0, qa);
  k_g1<<<g1, 256, 0, stream>>>(qh, q1T, rowexp, tokidx, srow1c, meta, CHTILES,
                               abuf_c, rowmaxc);
  k_aq<<<2048, 256, 0, stream>>>(abuf_c, rowmaxc, meta, CHROWS, qa);

  k_scg<<<(NRMAX + 255) / 256, 256, 0, stream>>>(rowmaxc, wscale, gates,
                                                 tokidx, wrow, rowexp, sgc);
  dim3 g2(16, NTILEMAX);
  k_g2<<<g2, 256, 0, stream>>>(qa, q2T, rowexp, sgc, wrow, meta, pbuf);
  k_combine<<<TT * DD / 4 / 256, 256, 0, stream>>>(pbuf, out);
}

// Round 19
// 244.200 us; speedup vs baseline: 1.3153x; 1.0213x over previous
//
#include <hip/hip_runtime.h>
#include <hip/hip_bf16.h>

#define TT 2048
#define DD 1024
#define FF 2048
#define NEXPI 10     // 2 shared + 8 routed expert instances
#define NRMAX 9216   // max compact rows: 4096 shared + 4096 routed + <=1024 pad
#define NTILEMAX 72  // NRMAX/128
#define CHTILES 36   // row-tiles per gemm1 chunk
#define CHROWS (CHTILES * 128)

typedef __attribute__((ext_vector_type(4))) int v4i;
typedef __attribute__((ext_vector_type(4))) float f32x4;

__device__ __forceinline__ double wave_sum_d(double v) {
#pragma unroll
  for (int o = 32; o > 0; o >>= 1) v += __shfl_down(v, o);
  return v;
}
__device__ __forceinline__ double wave_max_d(double v) {
#pragma unroll
  for (int o = 32; o > 0; o >>= 1) v = fmax(v, __shfl_down(v, o));
  return v;
}

// async global->LDS, 16B per lane; lds dest is wave-uniform base, lane l lands at +l*16
__device__ __forceinline__ void gll16(const void* g, void* l) {
  __builtin_amdgcn_global_load_lds(
      (const __attribute__((address_space(1))) void*)g,
      (__attribute__((address_space(3))) void*)l, 16, 0, 0);
}

// stage ROWS x 64B tile (i8, row stride K bytes in global) into linear LDS
template<int ROWS>
__device__ __forceinline__ void stage_rows(const signed char* src, int K,
                                           signed char* lds, int tid) {
  int w = tid >> 6, l = tid & 63;
  int sub = l >> 2, seg = (l & 3) * 16;
#pragma unroll
  for (int i = 0; i < ROWS / 64; ++i) {
    int rbase = w * (ROWS / 4) + i * 16;
    gll16(src + (size_t)(rbase + sub) * K + seg, lds + rbase * 64);
  }
}

// ---------------- zero init (compact rowmax) ----------------
__global__ void k_zero(unsigned* __restrict__ rm) {
  int i = blockIdx.x * 256 + threadIdx.x;
  if (i < NRMAX) rm[i] = 0u;
}

// ------------- rmsnorm + per-token absmax + int8 quant + bf16 h (f64 math) -------------
__global__ __launch_bounds__(256) void k_rms_quant(
    const float* __restrict__ x, const float* __restrict__ rw,
    signed char* __restrict__ qh, __hip_bfloat16* __restrict__ hb,
    double* __restrict__ amax_clip) {
  __shared__ double red[12];
  int t = blockIdx.x, tid = threadIdx.x;
  int lane = tid & 63, wid = tid >> 6;
  float4 xv = ((const float4*)(x + (size_t)t * DD))[tid];
  double x0 = xv.x, x1 = xv.y, x2 = xv.z, x3 = xv.w;
  double ss = x0 * x0 + x1 * x1 + x2 * x2 + x3 * x3;
  ss = wave_sum_d(ss);
  if (lane == 0) red[wid] = ss;
  __syncthreads();
  if (tid == 0) {
    double s = red[0] + red[1] + red[2] + red[3];
    red[8] = 1.0 / sqrt(s * (1.0 / DD) + 1e-6);
  }
  __syncthreads();
  double r = red[8];
  float4 wv = ((const float4*)rw)[tid];
  double h0 = x0 * r * (double)wv.x, h1 = x1 * r * (double)wv.y;
  double h2 = x2 * r * (double)wv.z, h3 = x3 * r * (double)wv.w;
  __hip_bfloat16* hp = hb + (size_t)t * DD + tid * 4;
  hp[0] = __float2bfloat16((float)h0); hp[1] = __float2bfloat16((float)h1);
  hp[2] = __float2bfloat16((float)h2); hp[3] = __float2bfloat16((float)h3);
  double am = fmax(fmax(fabs(h0), fabs(h1)), fmax(fabs(h2), fabs(h3)));
  am = wave_max_d(am);
  if (lane == 0) red[4 + wid] = am;
  __syncthreads();
  if (tid == 0) {
    double a = fmax(fmax(red[4], red[5]), fmax(red[6], red[7]));
    red[9] = fmax(a, 1e-5);
  }
  __syncthreads();
  double clipv = red[9];
  if (tid == 0) amax_clip[t] = clipv;
  double s = 127.0 / clipv;
  int q0 = (int)fmin(127.0, fmax(-128.0, rint(h0 * s)));
  int q1 = (int)fmin(127.0, fmax(-128.0, rint(h1 * s)));
  int q2 = (int)fmin(127.0, fmax(-128.0, rint(h2 * s)));
  int q3 = (int)fmin(127.0, fmax(-128.0, rint(h3 * s)));
  unsigned pw = (unsigned)(q0 & 255) | ((unsigned)(q1 & 255) << 8) |
                ((unsigned)(q2 & 255) << 16) | ((unsigned)(q3 & 255) << 24);
  *(unsigned*)(qh + (size_t)t * DD + tid * 4) = pw;
}

// ------------- weight absmean: f64 partial sums, 20 matrices x 128 blocks -------------
// plain (cached) loads so weights populate L3 for k_wquant's re-read
__global__ __launch_bounds__(256) void k_wabs_part(
    const float* __restrict__ w1s, const float* __restrict__ w2s,
    const float* __restrict__ w1r, const float* __restrict__ w2r,
    double* __restrict__ part) {
  __shared__ double red[4];
  int m = blockIdx.x >> 7, blk = blockIdx.x & 127;
  const float* base;
  if (m < 2)       base = w1s + (size_t)m * (DD * FF);
  else if (m < 4)  base = w2s + (size_t)(m - 2) * (DD * FF);
  else if (m < 12) base = w1r + (size_t)(m - 4) * (DD * FF);
  else             base = w2r + (size_t)(m - 12) * (DD * FF);
  const f32x4* p = (const f32x4*)base + (size_t)blk * 4096;
  int tid = threadIdx.x;
  double s0 = 0.0, s1 = 0.0, s2 = 0.0, s3 = 0.0;
#pragma unroll
  for (int b = 0; b < 2; ++b) {
    f32x4 v[8];
#pragma unroll
    for (int i = 0; i < 8; ++i)
      v[i] = p[tid + (b * 8 + i) * 256];
#pragma unroll
    for (int i = 0; i < 8; i += 4) {
      s0 += (double)fabsf(v[i+0].x) + (double)fabsf(v[i+0].y) +
            (double)fabsf(v[i+0].z) + (double)fabsf(v[i+0].w);
      s1 += (double)fabsf(v[i+1].x) + (double)fabsf(v[i+1].y) +
            (double)fabsf(v[i+1].z) + (double)fabsf(v[i+1].w);
      s2 += (double)fabsf(v[i+2].x) + (double)fabsf(v[i+2].y) +
            (double)fabsf(v[i+2].z) + (double)fabsf(v[i+2].w);
      s3 += (double)fabsf(v[i+3].x) + (double)fabsf(v[i+3].y) +
            (double)fabsf(v[i+3].z) + (double)fabsf(v[i+3].w);
    }
  }
  double s = (s0 + s1) + (s2 + s3);
  s = wave_sum_d(s);
  int lane = tid & 63, wid = tid >> 6;
  if (lane == 0) red[wid] = s;
  __syncthreads();
  if (tid == 0) part[m * 128 + blk] = red[0] + red[1] + red[2] + red[3];
}

__global__ __launch_bounds__(64) void k_wscale_final(
    const double* __restrict__ part, double* __restrict__ wscale) {
  int m = blockIdx.x;
  double v = part[m * 128 + threadIdx.x] + part[m * 128 + 64 + threadIdx.x];
  v = wave_sum_d(v);
  if (threadIdx.x == 0) wscale[m] = v * (1.0 / 2097152.0) + 1e-8;
}

// ------------- router: bf16 products, f64 accum, bf16-rounded logits,
//               top-2 (lower-index tie-break), renorm -> dense gates + (i0,i1) ---------
__global__ __launch_bounds__(64) void k_router(
    const __hip_bfloat16* __restrict__ hb, const float* __restrict__ rw,
    float* __restrict__ gates, int2* __restrict__ i01) {
  int t = blockIdx.x, lane = threadIdx.x;
  double acc[8];
#pragma unroll
  for (int e = 0; e < 8; ++e) acc[e] = 0.0;
  const __hip_bfloat16* hp = hb + (size_t)t * DD;
  for (int d = lane; d < DD; d += 64) {
    double hv = (double)__bfloat162float(hp[d]);
#pragma unroll
    for (int e = 0; e < 8; ++e) {
      double wv = (double)__bfloat162float(__float2bfloat16(rw[e * DD + d]));
      acc[e] += hv * wv;
    }
  }
#pragma unroll
  for (int e = 0; e < 8; ++e) acc[e] = wave_sum_d(acc[e]);
  if (lane == 0) {
    double lb[8];
#pragma unroll
    for (int e = 0; e < 8; ++e)
      lb[e] = (double)__bfloat162float(__float2bfloat16((float)acc[e]));
    double mx = lb[0];
#pragma unroll
    for (int e = 1; e < 8; ++e) mx = fmax(mx, lb[e]);
    double p[8];
#pragma unroll
    for (int e = 0; e < 8; ++e) p[e] = exp(lb[e] - mx);
    int i0 = 0;
    for (int e = 1; e < 8; ++e) if (p[e] > p[i0]) i0 = e;
    int i1 = (i0 == 0) ? 1 : 0;
    for (int e = 0; e < 8; ++e) if (e != i0 && p[e] > p[i1]) i1 = e;
    double den = p[i0] + p[i1];
    float o[8] = {0.f, 0.f, 0.f, 0.f, 0.f, 0.f, 0.f, 0.f};
    o[i0] = (float)(p[i0] / den);
    o[i1] = (float)(p[i1] / den);
#pragma unroll
    for (int e = 0; e < 8; ++e) gates[(size_t)t * 8 + e] = o[e];
    i01[t] = make_int2(i0, i1);
  }
}

// ------------- per-expert ordered token lists (ballot prefix compaction) ---------------
__global__ __launch_bounds__(64) void k_lists(
    const int2* __restrict__ i01, int* __restrict__ lists,
    unsigned char* __restrict__ slots, int* __restrict__ cnt) {
  int e = blockIdx.x, lane = threadIdx.x;
  int* le = lists + e * TT;
  unsigned char* se = slots + e * TT;
  int base = 0;
  for (int it = 0; it < TT / 64; ++it) {
    int t = it * 64 + lane;
    int2 r = i01[t];
    bool hit0 = (r.x == e), hit1 = (r.y == e);
    bool hit = hit0 || hit1;
    unsigned long long m = __ballot(hit);
    int pos = base + __popcll(m & ((1ull << lane) - 1ull));
    if (hit) { le[pos] = t; se[pos] = hit0 ? 0 : 1; }
    base += __popcll(m);
  }
  if (lane == 0) cnt[e] = base;
}

// ------------- meta: segment offsets, tile->expert map, per-row gather tables ----------
__global__ __launch_bounds__(256) void k_meta(
    const int* __restrict__ cnt, const int* __restrict__ lists,
    const unsigned char* __restrict__ slots, const double* __restrict__ amax_clip,
    const double* __restrict__ wscale, int* __restrict__ meta,
    int* __restrict__ rowexp, int* __restrict__ tokidx,
    int* __restrict__ wrow, float* __restrict__ srow1c) {
  __shared__ int segs[9];
  __shared__ int scnt[8];
  int tid = threadIdx.x;
  if (tid == 0) {
    int acc = 0;
    for (int e = 0; e < 8; ++e) {
      scnt[e] = cnt[e];
      segs[e] = acc;
      acc += (cnt[e] + 127) & ~127;
    }
    segs[8] = acc;
    meta[0] = 32 + acc / 128;   // total row-tiles
    meta[1] = 4096 + acc;       // total compact rows
  }
  __syncthreads();
  int ntile = 32 + segs[8] / 128;
  for (int j = tid; j < NTILEMAX; j += 256) {
    int ei = -1;
    if (j < 16) ei = 0;
    else if (j < 32) ei = 1;
    else if (j < ntile) {
      int rr = (j - 32) * 128;
      for (int e = 0; e < 8; ++e)
        if (rr >= segs[e] && rr < segs[e + 1]) { ei = 2 + e; break; }
    }
    rowexp[j] = ei;
  }
  for (int r = tid; r < NRMAX; r += 256) {
    int t = 0; float s1 = 0.f; int w = -1;
    if (r < 4096) {
      int e = r >> 11; t = r & (TT - 1);
      double csc = wscale[e] * (1.0 / 127.0);
      s1 = (float)(amax_clip[t] * csc);
      w = e * TT + t;
    } else {
      int rr = r - 4096;
      if (rr < segs[8]) {
        int e = 0;
        for (int q = 0; q < 8; ++q)
          if (rr >= segs[q] && rr < segs[q + 1]) { e = q; break; }
        int k = rr - segs[e];
        if (k < scnt[e]) {
          t = lists[e * TT + k];
          int sl = slots[e * TT + k];
          double csc = wscale[4 + e] * (1.0 / 127.0);
          s1 = (float)(amax_clip[t] * csc);
          w = (2 + sl) * TT + t;
        }
      }
    }
    tokidx[r] = t; srow1c[r] = s1; wrow[r] = w;
  }
}

// ------------- ternary quant helper (f64 bins) -------------
__device__ __forceinline__ int qtern(float v, double winv) {
  double q = rint((double)v * winv);
  return (int)fmin(1.0, fmax(-1.0, q));
}
__device__ __forceinline__ unsigned pack4(int a, int b, int c, int d) {
  return (unsigned)(a & 255) | ((unsigned)(b & 255) << 8) |
         ((unsigned)(c & 255) << 16) | ((unsigned)(d & 255) << 24);
}

// ------------- weight quant + transpose: f32 [R][C] -> i8 W^T [C][R] -------------
__global__ __launch_bounds__(256) void k_wquant(
    const float* __restrict__ w1s, const float* __restrict__ w2s,
    const float* __restrict__ w1r, const float* __restrict__ w2r,
    const double* __restrict__ wscale,
    signed char* __restrict__ q1T, signed char* __restrict__ q2T) {
  __shared__ signed char tile[64 * 68];
  int bid = blockIdx.x;
  int m = bid >> 9, t = bid & 511;
  const float* src;
  signed char* dst;
  int ld, ldo, rt, ct;
  if (m < 2) {
    src = w1s + (size_t)m * DD * FF;
    dst = q1T + (size_t)m * FF * DD;
    ld = FF; ldo = DD; rt = t >> 5; ct = t & 31;
  } else if (m < 4) {
    src = w2s + (size_t)(m - 2) * FF * DD;
    dst = q2T + (size_t)(m - 2) * DD * FF;
    ld = DD; ldo = FF; rt = t >> 4; ct = t & 15;
  } else if (m < 12) {
    src = w1r + (size_t)(m - 4) * DD * FF;
    dst = q1T + (size_t)(m - 2) * FF * DD;
    ld = FF; ldo = DD; rt = t >> 5; ct = t & 31;
  } else {
    src = w2r + (size_t)(m - 12) * FF * DD;
    dst = q2T + (size_t)(m - 10) * DD * FF;
    ld = DD; ldo = FF; rt = t >> 4; ct = t & 15;
  }
  double winv = 1.0 / wscale[m];
  int row0 = rt * 64, col0 = ct * 64;
  int r = threadIdx.x >> 2, sc_ = (threadIdx.x & 3) * 16;
  const float* sp = src + (size_t)(row0 + r) * ld + col0 + sc_;
#pragma unroll
  for (int g = 0; g < 4; ++g) {
    float4 v = *(const float4*)(sp + g * 4);
    unsigned pk = pack4(qtern(v.x, winv), qtern(v.y, winv),
                        qtern(v.z, winv), qtern(v.w, winv));
    *(unsigned*)(tile + r * 68 + sc_ + g * 4) = pk;
  }
  __syncthreads();
  int c = threadIdx.x >> 2, sr = (threadIdx.x & 3) * 16;
  unsigned o[4];
#pragma unroll
  for (int g = 0; g < 4; ++g) {
    int j = sr + g * 4;
    o[g] = pack4(tile[(j + 0) * 68 + c], tile[(j + 1) * 68 + c],
                 tile[(j + 2) * 68 + c], tile[(j + 3) * 68 + c]);
  }
  int4 ov = make_int4((int)o[0], (int)o[1], (int)o[2], (int)o[3]);
  *(int4*)(dst + (size_t)(col0 + c) * ldo + row0 + sr) = ov;
}

// ------------- GEMM1 (compact rows, gathered A): 128x64 tiles, BK=128 sub-tiled ------
// abuf output in bf16 (halves round-trip traffic); rowmax from bf16-rounded values
// fixed grid (32, CHTILES) = 1152 blocks; bijective XCD swizzle (chunks of 144)
__global__ __launch_bounds__(256) void k_g1(
    const signed char* __restrict__ qh, const signed char* __restrict__ q1T,
    const int* __restrict__ rowexp, const int* __restrict__ tokidx,
    const float* __restrict__ srow1c, const int* __restrict__ meta, int tile0,
    __hip_bfloat16* __restrict__ abuf_c, unsigned* __restrict__ rowmaxc) {
  __shared__ __align__(16) signed char As[2 * 8192];   // 2 slices x 128 rows x 64B
  __shared__ __align__(16) signed char Bs[2 * 4096];   // 2 slices x 64 rows x 64B
  int lid = blockIdx.x + 32 * blockIdx.y;          // 0..1151
  int nid = (lid & 7) * 144 + (lid >> 3);          // bijective XCD chunks
  int j = tile0 + (nid >> 5);
  if (j >= meta[0]) return;
  int col0 = (nid & 31) * 64;
  int ei = rowexp[j];
  int tid = threadIdx.x, lane = tid & 63, wid = tid >> 6;
  int wr = wid >> 1, wc = wid & 1;
  int rowt0 = j * 128;
  // per-thread gathered A source pointers (k-invariant)
  int sub = lane >> 2, seg = (lane & 3) * 16;
  int sr0 = wid * 32 + sub, sr1 = sr0 + 16;
  const signed char* a0 = qh + (size_t)tokidx[rowt0 + sr0] * DD + seg;
  const signed char* a1 = qh + (size_t)tokidx[rowt0 + sr1] * DD + seg;
  const signed char* b_src = q1T + (size_t)ei * FF * DD + (size_t)col0 * DD;
  signed char* lda0 = As + (wid * 32) * 64;
  signed char* lda1 = As + (wid * 32 + 16) * 64;
  int kg = (lane >> 4) * 16, rsel = lane & 15;
  v4i zero = {0, 0, 0, 0};
  v4i acc[4][2];
#pragma unroll
  for (int i = 0; i < 4; ++i)
#pragma unroll
    for (int jj = 0; jj < 2; ++jj) acc[i][jj] = zero;
  for (int k0 = 0; k0 < DD; k0 += 128) {
    __syncthreads();
#pragma unroll
    for (int c = 0; c < 2; ++c) {
      gll16(a0 + k0 + c * 64, lda0 + c * 8192);
      gll16(a1 + k0 + c * 64, lda1 + c * 8192);
      stage_rows<64>(b_src + k0 + c * 64, DD, Bs + c * 4096, tid);
    }
    __syncthreads();
#pragma unroll
    for (int kk = 0; kk < 2; ++kk) {
      v4i af[4], bf[2];
#pragma unroll
      for (int mi = 0; mi < 4; ++mi)
        af[mi] = *(const v4i*)(As + kk * 8192 + (wr * 64 + mi * 16 + rsel) * 64 + kg);
#pragma unroll
      for (int ni = 0; ni < 2; ++ni)
        bf[ni] = *(const v4i*)(Bs + kk * 4096 + (wc * 32 + ni * 16 + rsel) * 64 + kg);
#pragma unroll
      for (int mi = 0; mi < 4; ++mi)
#pragma unroll
        for (int ni = 0; ni < 2; ++ni)
          acc[mi][ni] = __builtin_amdgcn_mfma_i32_16x16x64_i8(af[mi], bf[ni], acc[mi][ni], 0, 0, 0);
    }
  }
  int rlocal0 = (j - tile0) * 128;
#pragma unroll
  for (int mi = 0; mi < 4; ++mi) {
#pragma unroll
    for (int rg = 0; rg < 4; ++rg) {
      int rof = wr * 64 + mi * 16 + ((lane >> 4) << 2) + rg;
      int tr = rowt0 + rof;
      float sA = srow1c[tr];
      float mloc = 0.f;
      int rl = rlocal0 + rof;
#pragma unroll
      for (int ni = 0; ni < 2; ++ni) {
        int fc = col0 + wc * 32 + ni * 16 + (lane & 15);
        float a = (float)acc[mi][ni][rg] * sA;
        float v = a / (1.f + expf(-a));
        __hip_bfloat16 vb = __float2bfloat16(v);
        float vq = __bfloat162float(vb);
        abuf_c[(size_t)rl * FF + fc] = vb;
        mloc = fmaxf(mloc, fabsf(vq));
      }
#pragma unroll
      for (int o = 1; o < 16; o <<= 1) mloc = fmaxf(mloc, __shfl_xor(mloc, o));
      if ((lane & 15) == 0) atomicMax(rowmaxc + tr, __float_as_uint(mloc));
    }
  }
}

// ------------- aquant (chunk of compact rows, bf16 input) -------------
__global__ __launch_bounds__(256) void k_aq(
    const __hip_bfloat16* __restrict__ abuf_c, const unsigned* __restrict__ rowmaxc,
    const int* __restrict__ meta, int row0, signed char* __restrict__ qa) {
  int nrows = meta[1] - row0;
  if (nrows > CHROWS) nrows = CHROWS;
  if (nrows < 0) nrows = 0;
  int total4 = nrows * (FF / 4);
  int stride = gridDim.x * 256;
  for (int i = blockIdx.x * 256 + threadIdx.x; i < total4; i += stride) {
    int rl = i >> 9;
    int r = row0 + rl;
    float clip = fmaxf(__uint_as_float(rowmaxc[r]), 1e-5f);
    float s = 127.f / clip;
    ushort4 raw = ((const ushort4*)abuf_c)[i];
    float vx = __bfloat162float(*(__hip_bfloat16*)&raw.x);
    float vy = __bfloat162float(*(__hip_bfloat16*)&raw.y);
    float vz = __bfloat162float(*(__hip_bfloat16*)&raw.z);
    float vw = __bfloat162float(*(__hip_bfloat16*)&raw.w);
    int q0 = (int)fminf(127.f, fmaxf(-128.f, rintf(vx * s)));
    int q1 = (int)fminf(127.f, fmaxf(-128.f, rintf(vy * s)));
    int q2 = (int)fminf(127.f, fmaxf(-128.f, rintf(vz * s)));
    int q3 = (int)fminf(127.f, fmaxf(-128.f, rintf(vw * s)));
    ((unsigned*)qa)[(size_t)r * (FF / 4) + (i & 511)] = pack4(q0, q1, q2, q3);
  }
}

// ------------- final gemm2 scale per compact row -------------
__global__ __launch_bounds__(256) void k_scg(
    const unsigned* __restrict__ rowmaxc, const double* __restrict__ wscale,
    const float* __restrict__ gates, const int* __restrict__ tokidx,
    const int* __restrict__ wrow, const int* __restrict__ rowexp,
    float* __restrict__ sgc) {
  int r = blockIdx.x * 256 + threadIdx.x;
  if (r >= NRMAX) return;
  int ei = rowexp[r >> 7];
  int w = wrow[r];
  if (ei < 0 || w < 0) { sgc[r] = 0.f; return; }
  float clip = fmaxf(__uint_as_float(rowmaxc[r]), 1e-5f);
  int t = tokidx[r];
  double csc = wscale[ei < 2 ? ei + 2 : ei + 10] * (1.0 / 127.0);
  float g = (ei < 2) ? 1.f : gates[(size_t)t * 8 + (ei - 2)];
  sgc[r] = (float)((double)clip * csc) * g;
}

// ------------- GEMM2 (compact rows): 128x64 tiles, BK=128 sub-tiled -----------------
// fixed grid (16, NTILEMAX) = 1152 blocks; bijective XCD swizzle (chunks of 144)
__global__ __launch_bounds__(256) void k_g2(
    const signed char* __restrict__ qa, const signed char* __restrict__ q2T,
    const int* __restrict__ rowexp, const float* __restrict__ sgc,
    const int* __restrict__ wrow, const int* __restrict__ meta,
    float* __restrict__ pbuf) {
  __shared__ __align__(16) signed char As[2 * 8192];   // 2 slices x 128 rows x 64B
  __shared__ __align__(16) signed char Bs[2 * 4096];   // 2 slices x 64 rows x 64B
  int lid = blockIdx.x + 16 * blockIdx.y;          // 0..1151
  int nid = (lid & 7) * 144 + (lid >> 3);
  int j = nid >> 4;
  if (j >= meta[0]) return;
  int col0 = (nid & 15) * 64;
  int ei = rowexp[j];
  int tid = threadIdx.x, lane = tid & 63, wid = tid >> 6;
  int wr = wid >> 1, wc = wid & 1;
  const signed char* ap = qa + (size_t)j * 128 * FF;
  const signed char* bp = q2T + (size_t)ei * DD * FF + (size_t)col0 * FF;
  int kg = (lane >> 4) * 16, rsel = lane & 15;
  v4i zero = {0, 0, 0, 0};
  v4i acc[4][2];
#pragma unroll
  for (int i = 0; i < 4; ++i)
#pragma unroll
    for (int jj = 0; jj < 2; ++jj) acc[i][jj] = zero;
  for (int k0 = 0; k0 < FF; k0 += 128) {
    __syncthreads();
#pragma unroll
    for (int c = 0; c < 2; ++c) {
      stage_rows<128>(ap + k0 + c * 64, FF, As + c * 8192, tid);
      stage_rows<64>(bp + k0 + c * 64, FF, Bs + c * 4096, tid);
    }
    __syncthreads();
#pragma unroll
    for (int kk = 0; kk < 2; ++kk) {
      v4i af[4], bf[2];
#pragma unroll
      for (int mi = 0; mi < 4; ++mi)
        af[mi] = *(const v4i*)(As + kk * 8192 + (wr * 64 + mi * 16 + rsel) * 64 + kg);
#pragma unroll
      for (int ni = 0; ni < 2; ++ni)
        bf[ni] = *(const v4i*)(Bs + kk * 4096 + (wc * 32 + ni * 16 + rsel) * 64 + kg);
#pragma unroll
      for (int mi = 0; mi < 4; ++mi)
#pragma unroll
        for (int ni = 0; ni < 2; ++ni)
          acc[mi][ni] = __builtin_amdgcn_mfma_i32_16x16x64_i8(af[mi], bf[ni], acc[mi][ni], 0, 0, 0);
    }
  }
#pragma unroll
  for (int mi = 0; mi < 4; ++mi) {
#pragma unroll
    for (int rg = 0; rg < 4; ++rg) {
      int tr = j * 128 + wr * 64 + mi * 16 + ((lane >> 4) << 2) + rg;
      int w = wrow[tr];
      float sc = sgc[tr];
      if (w >= 0) {
#pragma unroll
        for (int ni = 0; ni < 2; ++ni) {
          int dc = col0 + wc * 32 + ni * 16 + (lane & 15);
          pbuf[(size_t)w * DD + dc] = (float)acc[mi][ni][rg] * sc;
        }
      }
    }
  }
}

// ------------- combine: out = sum of 4 planes -------------
__global__ __launch_bounds__(256) void k_combine(
    const float* __restrict__ pbuf, float* __restrict__ out) {
  int i = blockIdx.x * 256 + threadIdx.x;  // float4 index
  float4 s = ((const float4*)pbuf)[i];
#pragma unroll
  for (int z = 1; z < 4; ++z) {
    float4 v = ((const float4*)(pbuf + (size_t)z * TT * DD))[i];
    s.x += v.x; s.y += v.y; s.z += v.z; s.w += v.w;
  }
  ((float4*)out)[i] = s;
}

extern "C" void kernel_launch(void* const* d_in, const int* in_sizes, int n_in,
                              void* d_out, int out_size, void* d_ws, size_t ws_size,
                              hipStream_t stream) {
  const float* x    = (const float*)d_in[0];
  const float* rmsw = (const float*)d_in[1];
  const float* w1s  = (const float*)d_in[2];
  const float* w2s  = (const float*)d_in[3];
  const float* w1r  = (const float*)d_in[4];
  const float* w2r  = (const float*)d_in[5];
  const float* rw   = (const float*)d_in[6];
  float* out = (float*)d_out;

  char* ws = (char*)d_ws;
  // footprint ends at 0x7E80000 ~= 132.6MB (proven safe)
  double* amax_clip      = (double*)(ws + 0x0000000);   // 16KB
  double* part           = (double*)(ws + 0x0004000);   // 20KB (20*128 f64)
  double* wscale         = (double*)(ws + 0x0018000);   // 160B
  float* gates           = (float*)(ws + 0x0019000);    // 64KB
  int2* i01              = (int2*)(ws + 0x0029000);     // 16KB
  int* lists             = (int*)(ws + 0x002D000);      // 64KB
  unsigned char* slots   = (unsigned char*)(ws + 0x003D000); // 16KB
  int* cnt               = (int*)(ws + 0x0041000);      // 32B
  int* meta              = (int*)(ws + 0x0041100);      // 64B
  int* tokidx            = (int*)(ws + 0x0042000);      // 36KB
  int* wrow              = (int*)(ws + 0x004B000);      // 36KB
  float* srow1c          = (float*)(ws + 0x0054000);    // 36KB
  float* sgc             = (float*)(ws + 0x005D000);    // 36KB
  int* rowexp            = (int*)(ws + 0x0066000);      // 288B
  unsigned* rowmaxc      = (unsigned*)(ws + 0x0067000); // 36KB
  signed char* qh        = (signed char*)(ws + 0x0080000);    // 2MB
  __hip_bfloat16* hb     = (__hip_bfloat16*)(ws + 0x0280000); // 4MB
  signed char* q1T       = (signed char*)(ws + 0x0680000);    // 20MB
  signed char* q2T       = (signed char*)(ws + 0x1A80000);    // 20MB
  signed char* qa        = (signed char*)(ws + 0x2E80000);    // <=18.9MB (40MB region)
  float* pbuf            = (float*)(ws + 0x5680000);          // 4 planes = 32MB (40MB region)
  __hip_bfloat16* abuf_c = (__hip_bfloat16*)pbuf;  // alias: bf16 chunk (18.9MB) used before g2 writes pbuf

  k_zero<<<(NRMAX + 255) / 256, 256, 0, stream>>>(rowmaxc);
  k_rms_quant<<<TT, 256, 0, stream>>>(x, rmsw, qh, hb, amax_clip);
  k_wabs_part<<<20 * 128, 256, 0, stream>>>(w1s, w2s, w1r, w2r, part);
  k_wscale_final<<<20, 64, 0, stream>>>(part, wscale);
  k_router<<<TT, 64, 0, stream>>>(hb, rw, gates, i01);
  k_lists<<<8, 64, 0, stream>>>(i01, lists, slots, cnt);
  k_wquant<<<20 * 512, 256, 0, stream>>>(w1s, w2s, w1r, w2r, wscale, q1T, q2T);
  k_meta<<<1, 256, 0, stream>>>(cnt, lists, slots, amax_clip, wscale,
                                meta, rowexp, tokidx, wrow, srow1c);

  dim3 g1(32, CHTILES);
  k_g1<<<g1, 256, 0, stream>>>(qh, q1T, rowexp, tokidx, srow1c, meta, 0,
                               abuf_c, rowmaxc);
  k_aq<<<2048, 256, 0, stream>>>(abuf_c, rowmaxc, meta, 0, qa);
  k_g1<<<g1, 256, 0, stream>>>(qh, q1T, rowexp, tokidx, srow1c, meta, CHTILES,
                               abuf_c, rowmaxc);
  k_aq<<<2048, 256, 0, stream>>>(abuf_c, rowmaxc, meta, CHROWS, qa);

  k_scg<<<(NRMAX + 255) / 256, 256, 0, stream>>>(rowmaxc, wscale, gates,
                                                 tokidx, wrow, rowexp, sgc);
  dim3 g2(16, NTILEMAX);
  k_g2<<<g2, 256, 0, stream>>>(qa, q2T, rowexp, sgc, wrow, meta, pbuf);
  k_combine<<<TT * DD / 4 / 256, 256, 0, stream>>>(pbuf, out);
}

// Round 20
// 235.368 us; speedup vs baseline: 1.3646x; 1.0375x over previous
//
#include <hip/hip_runtime.h>
#include <hip/hip_bf16.h>

#define TT 2048
#define DD 1024
#define FF 2048
#define NEXPI 10     // 2 shared + 8 routed expert instances
#define NRMAX 9216   // max compact rows: 4096 shared + 4096 routed + <=1024 pad
#define NTILEMAX 72  // NRMAX/128
#define CHTILES 36   // row-tiles per gemm1 chunk
#define CHROWS (CHTILES * 128)

typedef __attribute__((ext_vector_type(4))) int v4i;
typedef __attribute__((ext_vector_type(4))) float f32x4;

__device__ __forceinline__ double wave_sum_d(double v) {
#pragma unroll
  for (int o = 32; o > 0; o >>= 1) v += __shfl_down(v, o);
  return v;
}
__device__ __forceinline__ double wave_max_d(double v) {
#pragma unroll
  for (int o = 32; o > 0; o >>= 1) v = fmax(v, __shfl_down(v, o));
  return v;
}

// async global->LDS, 16B per lane; lds dest is wave-uniform base, lane l lands at +l*16
__device__ __forceinline__ void gll16(const void* g, void* l) {
  __builtin_amdgcn_global_load_lds(
      (const __attribute__((address_space(1))) void*)g,
      (__attribute__((address_space(3))) void*)l, 16, 0, 0);
}

// stage ROWS x 64B tile (i8, row stride K bytes in global) into linear LDS
template<int ROWS>
__device__ __forceinline__ void stage_rows(const signed char* src, int K,
                                           signed char* lds, int tid) {
  int w = tid >> 6, l = tid & 63;
  int sub = l >> 2, seg = (l & 3) * 16;
#pragma unroll
  for (int i = 0; i < ROWS / 64; ++i) {
    int rbase = w * (ROWS / 4) + i * 16;
    gll16(src + (size_t)(rbase + sub) * K + seg, lds + rbase * 64);
  }
}

// ------------- fused prologue: wabs (blocks 0..2559) | rmsnorm+quant (2560..4607)
//               | rowmax zero (4608..4643). All three independent. -------------
__global__ __launch_bounds__(256) void k_pro(
    const float* __restrict__ w1s, const float* __restrict__ w2s,
    const float* __restrict__ w1r, const float* __restrict__ w2r,
    double* __restrict__ part,
    const float* __restrict__ x, const float* __restrict__ rw,
    signed char* __restrict__ qh, __hip_bfloat16* __restrict__ hb,
    double* __restrict__ amax_clip, unsigned* __restrict__ rm) {
  __shared__ double red[12];
  int bid = blockIdx.x, tid = threadIdx.x;
  if (bid < 2560) {
    // ---- weight absmean partials: 20 matrices x 128 blocks, 8-deep bursts ----
    int m = bid >> 7, blk = bid & 127;
    const float* base;
    if (m < 2)       base = w1s + (size_t)m * (DD * FF);
    else if (m < 4)  base = w2s + (size_t)(m - 2) * (DD * FF);
    else if (m < 12) base = w1r + (size_t)(m - 4) * (DD * FF);
    else             base = w2r + (size_t)(m - 12) * (DD * FF);
    const f32x4* p = (const f32x4*)base + (size_t)blk * 4096;
    double s0 = 0.0, s1 = 0.0, s2 = 0.0, s3 = 0.0;
#pragma unroll
    for (int b = 0; b < 2; ++b) {
      f32x4 v[8];
#pragma unroll
      for (int i = 0; i < 8; ++i)
        v[i] = p[tid + (b * 8 + i) * 256];
#pragma unroll
      for (int i = 0; i < 8; i += 4) {
        s0 += (double)fabsf(v[i+0].x) + (double)fabsf(v[i+0].y) +
              (double)fabsf(v[i+0].z) + (double)fabsf(v[i+0].w);
        s1 += (double)fabsf(v[i+1].x) + (double)fabsf(v[i+1].y) +
              (double)fabsf(v[i+1].z) + (double)fabsf(v[i+1].w);
        s2 += (double)fabsf(v[i+2].x) + (double)fabsf(v[i+2].y) +
              (double)fabsf(v[i+2].z) + (double)fabsf(v[i+2].w);
        s3 += (double)fabsf(v[i+3].x) + (double)fabsf(v[i+3].y) +
              (double)fabsf(v[i+3].z) + (double)fabsf(v[i+3].w);
      }
    }
    double s = (s0 + s1) + (s2 + s3);
    s = wave_sum_d(s);
    int lane = tid & 63, wid = tid >> 6;
    if (lane == 0) red[wid] = s;
    __syncthreads();
    if (tid == 0) part[m * 128 + blk] = red[0] + red[1] + red[2] + red[3];
  } else if (bid < 4608) {
    // ---- rmsnorm + per-token absmax + int8 quant + bf16 h (f64 math) ----
    int t = bid - 2560;
    int lane = tid & 63, wid = tid >> 6;
    float4 xv = ((const float4*)(x + (size_t)t * DD))[tid];
    double x0 = xv.x, x1 = xv.y, x2 = xv.z, x3 = xv.w;
    double ss = x0 * x0 + x1 * x1 + x2 * x2 + x3 * x3;
    ss = wave_sum_d(ss);
    if (lane == 0) red[wid] = ss;
    __syncthreads();
    if (tid == 0) {
      double s = red[0] + red[1] + red[2] + red[3];
      red[8] = 1.0 / sqrt(s * (1.0 / DD) + 1e-6);
    }
    __syncthreads();
    double r = red[8];
    float4 wv = ((const float4*)rw)[tid];
    double h0 = x0 * r * (double)wv.x, h1 = x1 * r * (double)wv.y;
    double h2 = x2 * r * (double)wv.z, h3 = x3 * r * (double)wv.w;
    __hip_bfloat16* hp = hb + (size_t)t * DD + tid * 4;
    hp[0] = __float2bfloat16((float)h0); hp[1] = __float2bfloat16((float)h1);
    hp[2] = __float2bfloat16((float)h2); hp[3] = __float2bfloat16((float)h3);
    double am = fmax(fmax(fabs(h0), fabs(h1)), fmax(fabs(h2), fabs(h3)));
    am = wave_max_d(am);
    if (lane == 0) red[4 + wid] = am;
    __syncthreads();
    if (tid == 0) {
      double a = fmax(fmax(red[4], red[5]), fmax(red[6], red[7]));
      red[9] = fmax(a, 1e-5);
    }
    __syncthreads();
    double clipv = red[9];
    if (tid == 0) amax_clip[t] = clipv;
    double s = 127.0 / clipv;
    int q0 = (int)fmin(127.0, fmax(-128.0, rint(h0 * s)));
    int q1 = (int)fmin(127.0, fmax(-128.0, rint(h1 * s)));
    int q2 = (int)fmin(127.0, fmax(-128.0, rint(h2 * s)));
    int q3 = (int)fmin(127.0, fmax(-128.0, rint(h3 * s)));
    unsigned pw = (unsigned)(q0 & 255) | ((unsigned)(q1 & 255) << 8) |
                  ((unsigned)(q2 & 255) << 16) | ((unsigned)(q3 & 255) << 24);
    *(unsigned*)(qh + (size_t)t * DD + tid * 4) = pw;
  } else {
    // ---- zero compact rowmax ----
    int i = (bid - 4608) * 256 + tid;
    if (i < NRMAX) rm[i] = 0u;
  }
}

__global__ __launch_bounds__(64) void k_wscale_final(
    const double* __restrict__ part, double* __restrict__ wscale) {
  int m = blockIdx.x;
  double v = part[m * 128 + threadIdx.x] + part[m * 128 + 64 + threadIdx.x];
  v = wave_sum_d(v);
  if (threadIdx.x == 0) wscale[m] = v * (1.0 / 2097152.0) + 1e-8;
}

// ------------- router: bf16 products, f64 accum, bf16-rounded logits,
//               top-2 (lower-index tie-break), renorm -> dense gates + (i0,i1) ---------
__global__ __launch_bounds__(64) void k_router(
    const __hip_bfloat16* __restrict__ hb, const float* __restrict__ rw,
    float* __restrict__ gates, int2* __restrict__ i01) {
  int t = blockIdx.x, lane = threadIdx.x;
  double acc[8];
#pragma unroll
  for (int e = 0; e < 8; ++e) acc[e] = 0.0;
  const __hip_bfloat16* hp = hb + (size_t)t * DD;
  for (int d = lane; d < DD; d += 64) {
    double hv = (double)__bfloat162float(hp[d]);
#pragma unroll
    for (int e = 0; e < 8; ++e) {
      double wv = (double)__bfloat162float(__float2bfloat16(rw[e * DD + d]));
      acc[e] += hv * wv;
    }
  }
#pragma unroll
  for (int e = 0; e < 8; ++e) acc[e] = wave_sum_d(acc[e]);
  if (lane == 0) {
    double lb[8];
#pragma unroll
    for (int e = 0; e < 8; ++e)
      lb[e] = (double)__bfloat162float(__float2bfloat16((float)acc[e]));
    double mx = lb[0];
#pragma unroll
    for (int e = 1; e < 8; ++e) mx = fmax(mx, lb[e]);
    double p[8];
#pragma unroll
    for (int e = 0; e < 8; ++e) p[e] = exp(lb[e] - mx);
    int i0 = 0;
    for (int e = 1; e < 8; ++e) if (p[e] > p[i0]) i0 = e;
    int i1 = (i0 == 0) ? 1 : 0;
    for (int e = 0; e < 8; ++e) if (e != i0 && p[e] > p[i1]) i1 = e;
    double den = p[i0] + p[i1];
    float o[8] = {0.f, 0.f, 0.f, 0.f, 0.f, 0.f, 0.f, 0.f};
    o[i0] = (float)(p[i0] / den);
    o[i1] = (float)(p[i1] / den);
#pragma unroll
    for (int e = 0; e < 8; ++e) gates[(size_t)t * 8 + e] = o[e];
    i01[t] = make_int2(i0, i1);
  }
}

// ------------- per-expert ordered token lists (ballot prefix compaction) ---------------
__global__ __launch_bounds__(64) void k_lists(
    const int2* __restrict__ i01, int* __restrict__ lists,
    unsigned char* __restrict__ slots, int* __restrict__ cnt) {
  int e = blockIdx.x, lane = threadIdx.x;
  int* le = lists + e * TT;
  unsigned char* se = slots + e * TT;
  int base = 0;
  for (int it = 0; it < TT / 64; ++it) {
    int t = it * 64 + lane;
    int2 r = i01[t];
    bool hit0 = (r.x == e), hit1 = (r.y == e);
    bool hit = hit0 || hit1;
    unsigned long long m = __ballot(hit);
    int pos = base + __popcll(m & ((1ull << lane) - 1ull));
    if (hit) { le[pos] = t; se[pos] = hit0 ? 0 : 1; }
    base += __popcll(m);
  }
  if (lane == 0) cnt[e] = base;
}

// ------------- meta: segment offsets, tile->expert map, per-row gather tables ----------
__global__ __launch_bounds__(256) void k_meta(
    const int* __restrict__ cnt, const int* __restrict__ lists,
    const unsigned char* __restrict__ slots, const double* __restrict__ amax_clip,
    const double* __restrict__ wscale, int* __restrict__ meta,
    int* __restrict__ rowexp, int* __restrict__ tokidx,
    int* __restrict__ wrow, float* __restrict__ srow1c) {
  __shared__ int segs[9];
  __shared__ int scnt[8];
  int tid = threadIdx.x;
  if (tid == 0) {
    int acc = 0;
    for (int e = 0; e < 8; ++e) {
      scnt[e] = cnt[e];
      segs[e] = acc;
      acc += (cnt[e] + 127) & ~127;
    }
    segs[8] = acc;
    meta[0] = 32 + acc / 128;   // total row-tiles
    meta[1] = 4096 + acc;       // total compact rows
  }
  __syncthreads();
  int ntile = 32 + segs[8] / 128;
  for (int j = tid; j < NTILEMAX; j += 256) {
    int ei = -1;
    if (j < 16) ei = 0;
    else if (j < 32) ei = 1;
    else if (j < ntile) {
      int rr = (j - 32) * 128;
      for (int e = 0; e < 8; ++e)
        if (rr >= segs[e] && rr < segs[e + 1]) { ei = 2 + e; break; }
    }
    rowexp[j] = ei;
  }
  for (int r = tid; r < NRMAX; r += 256) {
    int t = 0; float s1 = 0.f; int w = -1;
    if (r < 4096) {
      int e = r >> 11; t = r & (TT - 1);
      double csc = wscale[e] * (1.0 / 127.0);
      s1 = (float)(amax_clip[t] * csc);
      w = e * TT + t;
    } else {
      int rr = r - 4096;
      if (rr < segs[8]) {
        int e = 0;
        for (int q = 0; q < 8; ++q)
          if (rr >= segs[q] && rr < segs[q + 1]) { e = q; break; }
        int k = rr - segs[e];
        if (k < scnt[e]) {
          t = lists[e * TT + k];
          int sl = slots[e * TT + k];
          double csc = wscale[4 + e] * (1.0 / 127.0);
          s1 = (float)(amax_clip[t] * csc);
          w = (2 + sl) * TT + t;
        }
      }
    }
    tokidx[r] = t; srow1c[r] = s1; wrow[r] = w;
  }
}

// ------------- ternary quant helper (f64 bins) -------------
__device__ __forceinline__ int qtern(float v, double winv) {
  double q = rint((double)v * winv);
  return (int)fmin(1.0, fmax(-1.0, q));
}
__device__ __forceinline__ unsigned pack4(int a, int b, int c, int d) {
  return (unsigned)(a & 255) | ((unsigned)(b & 255) << 8) |
         ((unsigned)(c & 255) << 16) | ((unsigned)(d & 255) << 24);
}

// ------------- weight quant + transpose: f32 [R][C] -> i8 W^T [C][R] -------------
__global__ __launch_bounds__(256) void k_wquant(
    const float* __restrict__ w1s, const float* __restrict__ w2s,
    const float* __restrict__ w1r, const float* __restrict__ w2r,
    const double* __restrict__ wscale,
    signed char* __restrict__ q1T, signed char* __restrict__ q2T) {
  __shared__ signed char tile[64 * 68];
  int bid = blockIdx.x;
  int m = bid >> 9, t = bid & 511;
  const float* src;
  signed char* dst;
  int ld, ldo, rt, ct;
  if (m < 2) {
    src = w1s + (size_t)m * DD * FF;
    dst = q1T + (size_t)m * FF * DD;
    ld = FF; ldo = DD; rt = t >> 5; ct = t & 31;
  } else if (m < 4) {
    src = w2s + (size_t)(m - 2) * FF * DD;
    dst = q2T + (size_t)(m - 2) * DD * FF;
    ld = DD; ldo = FF; rt = t >> 4; ct = t & 15;
  } else if (m < 12) {
    src = w1r + (size_t)(m - 4) * DD * FF;
    dst = q1T + (size_t)(m - 2) * FF * DD;
    ld = FF; ldo = DD; rt = t >> 5; ct = t & 31;
  } else {
    src = w2r + (size_t)(m - 12) * FF * DD;
    dst = q2T + (size_t)(m - 10) * DD * FF;
    ld = DD; ldo = FF; rt = t >> 4; ct = t & 15;
  }
  double winv = 1.0 / wscale[m];
  int row0 = rt * 64, col0 = ct * 64;
  int r = threadIdx.x >> 2, sc_ = (threadIdx.x & 3) * 16;
  const float* sp = src + (size_t)(row0 + r) * ld + col0 + sc_;
#pragma unroll
  for (int g = 0; g < 4; ++g) {
    float4 v = *(const float4*)(sp + g * 4);
    unsigned pk = pack4(qtern(v.x, winv), qtern(v.y, winv),
                        qtern(v.z, winv), qtern(v.w, winv));
    *(unsigned*)(tile + r * 68 + sc_ + g * 4) = pk;
  }
  __syncthreads();
  int c = threadIdx.x >> 2, sr = (threadIdx.x & 3) * 16;
  unsigned o[4];
#pragma unroll
  for (int g = 0; g < 4; ++g) {
    int j = sr + g * 4;
    o[g] = pack4(tile[(j + 0) * 68 + c], tile[(j + 1) * 68 + c],
                 tile[(j + 2) * 68 + c], tile[(j + 3) * 68 + c]);
  }
  int4 ov = make_int4((int)o[0], (int)o[1], (int)o[2], (int)o[3]);
  *(int4*)(dst + (size_t)(col0 + c) * ldo + row0 + sr) = ov;
}

// ------------- GEMM1 (compact rows, gathered A): 128x64 tiles, BK=128 sub-tiled ------
// abuf output in bf16 (halves round-trip traffic); rowmax from bf16-rounded values
// fixed grid (32, CHTILES) = 1152 blocks; bijective XCD swizzle (chunks of 144)
__global__ __launch_bounds__(256) void k_g1(
    const signed char* __restrict__ qh, const signed char* __restrict__ q1T,
    const int* __restrict__ rowexp, const int* __restrict__ tokidx,
    const float* __restrict__ srow1c, const int* __restrict__ meta, int tile0,
    __hip_bfloat16* __restrict__ abuf_c, unsigned* __restrict__ rowmaxc) {
  __shared__ __align__(16) signed char As[2 * 8192];   // 2 slices x 128 rows x 64B
  __shared__ __align__(16) signed char Bs[2 * 4096];   // 2 slices x 64 rows x 64B
  int lid = blockIdx.x + 32 * blockIdx.y;          // 0..1151
  int nid = (lid & 7) * 144 + (lid >> 3);          // bijective XCD chunks
  int j = tile0 + (nid >> 5);
  if (j >= meta[0]) return;
  int col0 = (nid & 31) * 64;
  int ei = rowexp[j];
  int tid = threadIdx.x, lane = tid & 63, wid = tid >> 6;
  int wr = wid >> 1, wc = wid & 1;
  int rowt0 = j * 128;
  // per-thread gathered A source pointers (k-invariant)
  int sub = lane >> 2, seg = (lane & 3) * 16;
  int sr0 = wid * 32 + sub, sr1 = sr0 + 16;
  const signed char* a0 = qh + (size_t)tokidx[rowt0 + sr0] * DD + seg;
  const signed char* a1 = qh + (size_t)tokidx[rowt0 + sr1] * DD + seg;
  const signed char* b_src = q1T + (size_t)ei * FF * DD + (size_t)col0 * DD;
  signed char* lda0 = As + (wid * 32) * 64;
  signed char* lda1 = As + (wid * 32 + 16) * 64;
  int kg = (lane >> 4) * 16, rsel = lane & 15;
  v4i zero = {0, 0, 0, 0};
  v4i acc[4][2];
#pragma unroll
  for (int i = 0; i < 4; ++i)
#pragma unroll
    for (int jj = 0; jj < 2; ++jj) acc[i][jj] = zero;
  for (int k0 = 0; k0 < DD; k0 += 128) {
    __syncthreads();
#pragma unroll
    for (int c = 0; c < 2; ++c) {
      gll16(a0 + k0 + c * 64, lda0 + c * 8192);
      gll16(a1 + k0 + c * 64, lda1 + c * 8192);
      stage_rows<64>(b_src + k0 + c * 64, DD, Bs + c * 4096, tid);
    }
    __syncthreads();
#pragma unroll
    for (int kk = 0; kk < 2; ++kk) {
      v4i af[4], bf[2];
#pragma unroll
      for (int mi = 0; mi < 4; ++mi)
        af[mi] = *(const v4i*)(As + kk * 8192 + (wr * 64 + mi * 16 + rsel) * 64 + kg);
#pragma unroll
      for (int ni = 0; ni < 2; ++ni)
        bf[ni] = *(const v4i*)(Bs + kk * 4096 + (wc * 32 + ni * 16 + rsel) * 64 + kg);
#pragma unroll
      for (int mi = 0; mi < 4; ++mi)
#pragma unroll
        for (int ni = 0; ni < 2; ++ni)
          acc[mi][ni] = __builtin_amdgcn_mfma_i32_16x16x64_i8(af[mi], bf[ni], acc[mi][ni], 0, 0, 0);
    }
  }
  int rlocal0 = (j - tile0) * 128;
#pragma unroll
  for (int mi = 0; mi < 4; ++mi) {
#pragma unroll
    for (int rg = 0; rg < 4; ++rg) {
      int rof = wr * 64 + mi * 16 + ((lane >> 4) << 2) + rg;
      int tr = rowt0 + rof;
      float sA = srow1c[tr];
      float mloc = 0.f;
      int rl = rlocal0 + rof;
#pragma unroll
      for (int ni = 0; ni < 2; ++ni) {
        int fc = col0 + wc * 32 + ni * 16 + (lane & 15);
        float a = (float)acc[mi][ni][rg] * sA;
        float v = a / (1.f + expf(-a));
        __hip_bfloat16 vb = __float2bfloat16(v);
        float vq = __bfloat162float(vb);
        abuf_c[(size_t)rl * FF + fc] = vb;
        mloc = fmaxf(mloc, fabsf(vq));
      }
#pragma unroll
      for (int o = 1; o < 16; o <<= 1) mloc = fmaxf(mloc, __shfl_xor(mloc, o));
      if ((lane & 15) == 0) atomicMax(rowmaxc + tr, __float_as_uint(mloc));
    }
  }
}

// ------------- aquant (chunk of compact rows, bf16 input) -------------
__global__ __launch_bounds__(256) void k_aq(
    const __hip_bfloat16* __restrict__ abuf_c, const unsigned* __restrict__ rowmaxc,
    const int* __restrict__ meta, int row0, signed char* __restrict__ qa) {
  int nrows = meta[1] - row0;
  if (nrows > CHROWS) nrows = CHROWS;
  if (nrows < 0) nrows = 0;
  int total4 = nrows * (FF / 4);
  int stride = gridDim.x * 256;
  for (int i = blockIdx.x * 256 + threadIdx.x; i < total4; i += stride) {
    int rl = i >> 9;
    int r = row0 + rl;
    float clip = fmaxf(__uint_as_float(rowmaxc[r]), 1e-5f);
    float s = 127.f / clip;
    ushort4 raw = ((const ushort4*)abuf_c)[i];
    float vx = __bfloat162float(*(__hip_bfloat16*)&raw.x);
    float vy = __bfloat162float(*(__hip_bfloat16*)&raw.y);
    float vz = __bfloat162float(*(__hip_bfloat16*)&raw.z);
    float vw = __bfloat162float(*(__hip_bfloat16*)&raw.w);
    int q0 = (int)fminf(127.f, fmaxf(-128.f, rintf(vx * s)));
    int q1 = (int)fminf(127.f, fmaxf(-128.f, rintf(vy * s)));
    int q2 = (int)fminf(127.f, fmaxf(-128.f, rintf(vz * s)));
    int q3 = (int)fminf(127.f, fmaxf(-128.f, rintf(vw * s)));
    ((unsigned*)qa)[(size_t)r * (FF / 4) + (i & 511)] = pack4(q0, q1, q2, q3);
  }
}

// ------------- final gemm2 scale per compact row -------------
__global__ __launch_bounds__(256) void k_scg(
    const unsigned* __restrict__ rowmaxc, const double* __restrict__ wscale,
    const float* __restrict__ gates, const int* __restrict__ tokidx,
    const int* __restrict__ wrow, const int* __restrict__ rowexp,
    float* __restrict__ sgc) {
  int r = blockIdx.x * 256 + threadIdx.x;
  if (r >= NRMAX) return;
  int ei = rowexp[r >> 7];
  int w = wrow[r];
  if (ei < 0 || w < 0) { sgc[r] = 0.f; return; }
  float clip = fmaxf(__uint_as_float(rowmaxc[r]), 1e-5f);
  int t = tokidx[r];
  double csc = wscale[ei < 2 ? ei + 2 : ei + 10] * (1.0 / 127.0);
  float g = (ei < 2) ? 1.f : gates[(size_t)t * 8 + (ei - 2)];
  sgc[r] = (float)((double)clip * csc) * g;
}

// ------------- GEMM2 (compact rows): 128x64 tiles, BK=128 sub-tiled -----------------
// fixed grid (16, NTILEMAX) = 1152 blocks; bijective XCD swizzle (chunks of 144)
__global__ __launch_bounds__(256) void k_g2(
    const signed char* __restrict__ qa, const signed char* __restrict__ q2T,
    const int* __restrict__ rowexp, const float* __restrict__ sgc,
    const int* __restrict__ wrow, const int* __restrict__ meta,
    float* __restrict__ pbuf) {
  __shared__ __align__(16) signed char As[2 * 8192];   // 2 slices x 128 rows x 64B
  __shared__ __align__(16) signed char Bs[2 * 4096];   // 2 slices x 64 rows x 64B
  int lid = blockIdx.x + 16 * blockIdx.y;          // 0..1151
  int nid = (lid & 7) * 144 + (lid >> 3);
  int j = nid >> 4;
  if (j >= meta[0]) return;
  int col0 = (nid & 15) * 64;
  int ei = rowexp[j];
  int tid = threadIdx.x, lane = tid & 63, wid = tid >> 6;
  int wr = wid >> 1, wc = wid & 1;
  const signed char* ap = qa + (size_t)j * 128 * FF;
  const signed char* bp = q2T + (size_t)ei * DD * FF + (size_t)col0 * FF;
  int kg = (lane >> 4) * 16, rsel = lane & 15;
  v4i zero = {0, 0, 0, 0};
  v4i acc[4][2];
#pragma unroll
  for (int i = 0; i < 4; ++i)
#pragma unroll
    for (int jj = 0; jj < 2; ++jj) acc[i][jj] = zero;
  for (int k0 = 0; k0 < FF; k0 += 128) {
    __syncthreads();
#pragma unroll
    for (int c = 0; c < 2; ++c) {
      stage_rows<128>(ap + k0 + c * 64, FF, As + c * 8192, tid);
      stage_rows<64>(bp + k0 + c * 64, FF, Bs + c * 4096, tid);
    }
    __syncthreads();
#pragma unroll
    for (int kk = 0; kk < 2; ++kk) {
      v4i af[4], bf[2];
#pragma unroll
      for (int mi = 0; mi < 4; ++mi)
        af[mi] = *(const v4i*)(As + kk * 8192 + (wr * 64 + mi * 16 + rsel) * 64 + kg);
#pragma unroll
      for (int ni = 0; ni < 2; ++ni)
        bf[ni] = *(const v4i*)(Bs + kk * 4096 + (wc * 32 + ni * 16 + rsel) * 64 + kg);
#pragma unroll
      for (int mi = 0; mi < 4; ++mi)
#pragma unroll
        for (int ni = 0; ni < 2; ++ni)
          acc[mi][ni] = __builtin_amdgcn_mfma_i32_16x16x64_i8(af[mi], bf[ni], acc[mi][ni], 0, 0, 0);
    }
  }
#pragma unroll
  for (int mi = 0; mi < 4; ++mi) {
#pragma unroll
    for (int rg = 0; rg < 4; ++rg) {
      int tr = j * 128 + wr * 64 + mi * 16 + ((lane >> 4) << 2) + rg;
      int w = wrow[tr];
      float sc = sgc[tr];
      if (w >= 0) {
#pragma unroll
        for (int ni = 0; ni < 2; ++ni) {
          int dc = col0 + wc * 32 + ni * 16 + (lane & 15);
          pbuf[(size_t)w * DD + dc] = (float)acc[mi][ni][rg] * sc;
        }
      }
    }
  }
}

// ------------- combine: out = sum of 4 planes -------------
__global__ __launch_bounds__(256) void k_combine(
    const float* __restrict__ pbuf, float* __restrict__ out) {
  int i = blockIdx.x * 256 + threadIdx.x;  // float4 index
  float4 s = ((const float4*)pbuf)[i];
#pragma unroll
  for (int z = 1; z < 4; ++z) {
    float4 v = ((const float4*)(pbuf + (size_t)z * TT * DD))[i];
    s.x += v.x; s.y += v.y; s.z += v.z; s.w += v.w;
  }
  ((float4*)out)[i] = s;
}

extern "C" void kernel_launch(void* const* d_in, const int* in_sizes, int n_in,
                              void* d_out, int out_size, void* d_ws, size_t ws_size,
                              hipStream_t stream) {
  const float* x    = (const float*)d_in[0];
  const float* rmsw = (const float*)d_in[1];
  const float* w1s  = (const float*)d_in[2];
  const float* w2s  = (const float*)d_in[3];
  const float* w1r  = (const float*)d_in[4];
  const float* w2r  = (const float*)d_in[5];
  const float* rw   = (const float*)d_in[6];
  float* out = (float*)d_out;

  char* ws = (char*)d_ws;
  // footprint ends at 0x7E80000 ~= 132.6MB (proven safe)
  double* amax_clip      = (double*)(ws + 0x0000000);   // 16KB
  double* part           = (double*)(ws + 0x0004000);   // 20KB (20*128 f64)
  double* wscale         = (double*)(ws + 0x0018000);   // 160B
  float* gates           = (float*)(ws + 0x0019000);    // 64KB
  int2* i01              = (int2*)(ws + 0x0029000);     // 16KB
  int* lists             = (int*)(ws + 0x002D000);      // 64KB
  unsigned char* slots   = (unsigned char*)(ws + 0x003D000); // 16KB
  int* cnt               = (int*)(ws + 0x0041000);      // 32B
  int* meta              = (int*)(ws + 0x0041100);      // 64B
  int* tokidx            = (int*)(ws + 0x0042000);      // 36KB
  int* wrow              = (int*)(ws + 0x004B000);      // 36KB
  float* srow1c          = (float*)(ws + 0x0054000);    // 36KB
  float* sgc             = (float*)(ws + 0x005D000);    // 36KB
  int* rowexp            = (int*)(ws + 0x0066000);      // 288B
  unsigned* rowmaxc      = (unsigned*)(ws + 0x0067000); // 36KB
  signed char* qh        = (signed char*)(ws + 0x0080000);    // 2MB
  __hip_bfloat16* hb     = (__hip_bfloat16*)(ws + 0x0280000); // 4MB
  signed char* q1T       = (signed char*)(ws + 0x0680000);    // 20MB
  signed char* q2T       = (signed char*)(ws + 0x1A80000);    // 20MB
  signed char* qa        = (signed char*)(ws + 0x2E80000);    // <=18.9MB (40MB region)
  float* pbuf            = (float*)(ws + 0x5680000);          // 4 planes = 32MB (40MB region)
  __hip_bfloat16* abuf_c = (__hip_bfloat16*)pbuf;  // alias: bf16 chunk (18.9MB) used before g2 writes pbuf

  // fused prologue: wabs (2560) | rms_quant (2048) | rowmax zero (36)
  k_pro<<<4644, 256, 0, stream>>>(w1s, w2s, w1r, w2r, part,
                                  x, rmsw, qh, hb, amax_clip, rowmaxc);
  k_wscale_final<<<20, 64, 0, stream>>>(part, wscale);
  k_router<<<TT, 64, 0, stream>>>(hb, rw, gates, i01);
  k_lists<<<8, 64, 0, stream>>>(i01, lists, slots, cnt);
  k_wquant<<<20 * 512, 256, 0, stream>>>(w1s, w2s, w1r, w2r, wscale, q1T, q2T);
  k_meta<<<1, 256, 0, stream>>>(cnt, lists, slots, amax_clip, wscale,
                                meta, rowexp, tokidx, wrow, srow1c);

  dim3 g1(32, CHTILES);
  k_g1<<<g1, 256, 0, stream>>>(qh, q1T, rowexp, tokidx, srow1c, meta, 0,
                               abuf_c, rowmaxc);
  k_aq<<<2048, 256, 0, stream>>>(abuf_c, rowmaxc, meta, 0, qa);
  k_g1<<<g1, 256, 0, stream>>>(qh, q1T, rowexp, tokidx, srow1c, meta, CHTILES,
                               abuf_c, rowmaxc);
  k_aq<<<2048, 256, 0, stream>>>(abuf_c, rowmaxc, meta, CHROWS, qa);

  k_scg<<<(NRMAX + 255) / 256, 256, 0, stream>>>(rowmaxc, wscale, gates,
                                                 tokidx, wrow, rowexp, sgc);
  dim3 g2(16, NTILEMAX);
  k_g2<<<g2, 256, 0, stream>>>(qa, q2T, rowexp, sgc, wrow, meta, pbuf);
  k_combine<<<TT * DD / 4 / 256, 256, 0, stream>>>(pbuf, out);
}

// Round 21
// 233.545 us; speedup vs baseline: 1.3753x; 1.0078x over previous
//
#include <hip/hip_runtime.h>
#include <hip/hip_bf16.h>

#define TT 2048
#define DD 1024
#define FF 2048
#define NEXPI 10     // 2 shared + 8 routed expert instances
#define NRMAX 9216   // max compact rows: 4096 shared + 4096 routed + <=1024 pad
#define NTILEMAX 72  // NRMAX/128
#define CHTILES 36   // row-tiles per gemm1 chunk
#define CHROWS (CHTILES * 128)

typedef __attribute__((ext_vector_type(4))) int v4i;
typedef __attribute__((ext_vector_type(4))) float f32x4;

__device__ __forceinline__ double wave_sum_d(double v) {
#pragma unroll
  for (int o = 32; o > 0; o >>= 1) v += __shfl_down(v, o);
  return v;
}
__device__ __forceinline__ double wave_max_d(double v) {
#pragma unroll
  for (int o = 32; o > 0; o >>= 1) v = fmax(v, __shfl_down(v, o));
  return v;
}

// async global->LDS, 16B per lane; lds dest is wave-uniform base, lane l lands at +l*16
__device__ __forceinline__ void gll16(const void* g, void* l) {
  __builtin_amdgcn_global_load_lds(
      (const __attribute__((address_space(1))) void*)g,
      (__attribute__((address_space(3))) void*)l, 16, 0, 0);
}

// stage ROWS x 64B tile (i8, row stride K bytes in global) into linear LDS
template<int ROWS>
__device__ __forceinline__ void stage_rows(const signed char* src, int K,
                                           signed char* lds, int tid) {
  int w = tid >> 6, l = tid & 63;
  int sub = l >> 2, seg = (l & 3) * 16;
#pragma unroll
  for (int i = 0; i < ROWS / 64; ++i) {
    int rbase = w * (ROWS / 4) + i * 16;
    gll16(src + (size_t)(rbase + sub) * K + seg, lds + rbase * 64);
  }
}

// ------------- fused prologue: wabs (blocks 0..2559) | rmsnorm+quant (2560..4607)
//               | rowmax zero (4608..4643). All three independent. -------------
__global__ __launch_bounds__(256) void k_pro(
    const float* __restrict__ w1s, const float* __restrict__ w2s,
    const float* __restrict__ w1r, const float* __restrict__ w2r,
    double* __restrict__ part,
    const float* __restrict__ x, const float* __restrict__ rw,
    signed char* __restrict__ qh, __hip_bfloat16* __restrict__ hb,
    double* __restrict__ amax_clip, unsigned* __restrict__ rm) {
  __shared__ double red[12];
  int bid = blockIdx.x, tid = threadIdx.x;
  if (bid < 2560) {
    int m = bid >> 7, blk = bid & 127;
    const float* base;
    if (m < 2)       base = w1s + (size_t)m * (DD * FF);
    else if (m < 4)  base = w2s + (size_t)(m - 2) * (DD * FF);
    else if (m < 12) base = w1r + (size_t)(m - 4) * (DD * FF);
    else             base = w2r + (size_t)(m - 12) * (DD * FF);
    const f32x4* p = (const f32x4*)base + (size_t)blk * 4096;
    double s0 = 0.0, s1 = 0.0, s2 = 0.0, s3 = 0.0;
#pragma unroll
    for (int b = 0; b < 2; ++b) {
      f32x4 v[8];
#pragma unroll
      for (int i = 0; i < 8; ++i)
        v[i] = p[tid + (b * 8 + i) * 256];
#pragma unroll
      for (int i = 0; i < 8; i += 4) {
        s0 += (double)fabsf(v[i+0].x) + (double)fabsf(v[i+0].y) +
              (double)fabsf(v[i+0].z) + (double)fabsf(v[i+0].w);
        s1 += (double)fabsf(v[i+1].x) + (double)fabsf(v[i+1].y) +
              (double)fabsf(v[i+1].z) + (double)fabsf(v[i+1].w);
        s2 += (double)fabsf(v[i+2].x) + (double)fabsf(v[i+2].y) +
              (double)fabsf(v[i+2].z) + (double)fabsf(v[i+2].w);
        s3 += (double)fabsf(v[i+3].x) + (double)fabsf(v[i+3].y) +
              (double)fabsf(v[i+3].z) + (double)fabsf(v[i+3].w);
      }
    }
    double s = (s0 + s1) + (s2 + s3);
    s = wave_sum_d(s);
    int lane = tid & 63, wid = tid >> 6;
    if (lane == 0) red[wid] = s;
    __syncthreads();
    if (tid == 0) part[m * 128 + blk] = red[0] + red[1] + red[2] + red[3];
  } else if (bid < 4608) {
    int t = bid - 2560;
    int lane = tid & 63, wid = tid >> 6;
    float4 xv = ((const float4*)(x + (size_t)t * DD))[tid];
    double x0 = xv.x, x1 = xv.y, x2 = xv.z, x3 = xv.w;
    double ss = x0 * x0 + x1 * x1 + x2 * x2 + x3 * x3;
    ss = wave_sum_d(ss);
    if (lane == 0) red[wid] = ss;
    __syncthreads();
    if (tid == 0) {
      double s = red[0] + red[1] + red[2] + red[3];
      red[8] = 1.0 / sqrt(s * (1.0 / DD) + 1e-6);
    }
    __syncthreads();
    double r = red[8];
    float4 wv = ((const float4*)rw)[tid];
    double h0 = x0 * r * (double)wv.x, h1 = x1 * r * (double)wv.y;
    double h2 = x2 * r * (double)wv.z, h3 = x3 * r * (double)wv.w;
    __hip_bfloat16* hp = hb + (size_t)t * DD + tid * 4;
    hp[0] = __float2bfloat16((float)h0); hp[1] = __float2bfloat16((float)h1);
    hp[2] = __float2bfloat16((float)h2); hp[3] = __float2bfloat16((float)h3);
    double am = fmax(fmax(fabs(h0), fabs(h1)), fmax(fabs(h2), fabs(h3)));
    am = wave_max_d(am);
    if (lane == 0) red[4 + wid] = am;
    __syncthreads();
    if (tid == 0) {
      double a = fmax(fmax(red[4], red[5]), fmax(red[6], red[7]));
      red[9] = fmax(a, 1e-5);
    }
    __syncthreads();
    double clipv = red[9];
    if (tid == 0) amax_clip[t] = clipv;
    double s = 127.0 / clipv;
    int q0 = (int)fmin(127.0, fmax(-128.0, rint(h0 * s)));
    int q1 = (int)fmin(127.0, fmax(-128.0, rint(h1 * s)));
    int q2 = (int)fmin(127.0, fmax(-128.0, rint(h2 * s)));
    int q3 = (int)fmin(127.0, fmax(-128.0, rint(h3 * s)));
    unsigned pw = (unsigned)(q0 & 255) | ((unsigned)(q1 & 255) << 8) |
                  ((unsigned)(q2 & 255) << 16) | ((unsigned)(q3 & 255) << 24);
    *(unsigned*)(qh + (size_t)t * DD + tid * 4) = pw;
  } else {
    int i = (bid - 4608) * 256 + tid;
    if (i < NRMAX) rm[i] = 0u;
  }
}

__global__ __launch_bounds__(64) void k_wscale_final(
    const double* __restrict__ part, double* __restrict__ wscale) {
  int m = blockIdx.x;
  double v = part[m * 128 + threadIdx.x] + part[m * 128 + 64 + threadIdx.x];
  v = wave_sum_d(v);
  if (threadIdx.x == 0) wscale[m] = v * (1.0 / 2097152.0) + 1e-8;
}

// ------------- ternary quant helper (f64 bins) -------------
__device__ __forceinline__ int qtern(float v, double winv) {
  double q = rint((double)v * winv);
  return (int)fmin(1.0, fmax(-1.0, q));
}
__device__ __forceinline__ unsigned pack4(int a, int b, int c, int d) {
  return (unsigned)(a & 255) | ((unsigned)(b & 255) << 8) |
         ((unsigned)(c & 255) << 16) | ((unsigned)(d & 255) << 24);
}

// ------------- fused mid: wquant (blocks 0..10239) | router (10240..10751, 4 tok/blk)
//               both independent: wquant needs wscale, router needs hb --------------
__global__ __launch_bounds__(256) void k_mid(
    const float* __restrict__ w1s, const float* __restrict__ w2s,
    const float* __restrict__ w1r, const float* __restrict__ w2r,
    const double* __restrict__ wscale,
    signed char* __restrict__ q1T, signed char* __restrict__ q2T,
    const __hip_bfloat16* __restrict__ hb, const float* __restrict__ rw,
    float* __restrict__ gates, int2* __restrict__ i01) {
  int bid = blockIdx.x, tidx = threadIdx.x;
  if (bid < 10240) {
    // ---- weight quant + transpose: f32 [R][C] -> i8 W^T [C][R] ----
    __shared__ signed char tile[64 * 68];
    int m = bid >> 9, t = bid & 511;
    const float* src;
    signed char* dst;
    int ld, ldo, rt, ct;
    if (m < 2) {
      src = w1s + (size_t)m * DD * FF;
      dst = q1T + (size_t)m * FF * DD;
      ld = FF; ldo = DD; rt = t >> 5; ct = t & 31;
    } else if (m < 4) {
      src = w2s + (size_t)(m - 2) * FF * DD;
      dst = q2T + (size_t)(m - 2) * DD * FF;
      ld = DD; ldo = FF; rt = t >> 4; ct = t & 15;
    } else if (m < 12) {
      src = w1r + (size_t)(m - 4) * DD * FF;
      dst = q1T + (size_t)(m - 2) * FF * DD;
      ld = FF; ldo = DD; rt = t >> 5; ct = t & 31;
    } else {
      src = w2r + (size_t)(m - 12) * FF * DD;
      dst = q2T + (size_t)(m - 10) * DD * FF;
      ld = DD; ldo = FF; rt = t >> 4; ct = t & 15;
    }
    double winv = 1.0 / wscale[m];
    int row0 = rt * 64, col0 = ct * 64;
    int r = tidx >> 2, sc_ = (tidx & 3) * 16;
    const float* sp = src + (size_t)(row0 + r) * ld + col0 + sc_;
#pragma unroll
    for (int g = 0; g < 4; ++g) {
      float4 v = *(const float4*)(sp + g * 4);
      unsigned pk = pack4(qtern(v.x, winv), qtern(v.y, winv),
                          qtern(v.z, winv), qtern(v.w, winv));
      *(unsigned*)(tile + r * 68 + sc_ + g * 4) = pk;
    }
    __syncthreads();
    int c = tidx >> 2, sr = (tidx & 3) * 16;
    unsigned o[4];
#pragma unroll
    for (int g = 0; g < 4; ++g) {
      int j = sr + g * 4;
      o[g] = pack4(tile[(j + 0) * 68 + c], tile[(j + 1) * 68 + c],
                   tile[(j + 2) * 68 + c], tile[(j + 3) * 68 + c]);
    }
    int4 ov = make_int4((int)o[0], (int)o[1], (int)o[2], (int)o[3]);
    *(int4*)(dst + (size_t)(col0 + c) * ldo + row0 + sr) = ov;
  } else {
    // ---- router: 4 tokens per block, one 64-lane wave each ----
    int t = (bid - 10240) * 4 + (tidx >> 6);
    int lane = tidx & 63;
    double acc[8];
#pragma unroll
    for (int e = 0; e < 8; ++e) acc[e] = 0.0;
    const __hip_bfloat16* hp = hb + (size_t)t * DD;
    for (int d = lane; d < DD; d += 64) {
      double hv = (double)__bfloat162float(hp[d]);
#pragma unroll
      for (int e = 0; e < 8; ++e) {
        double wv = (double)__bfloat162float(__float2bfloat16(rw[e * DD + d]));
        acc[e] += hv * wv;
      }
    }
#pragma unroll
    for (int e = 0; e < 8; ++e) acc[e] = wave_sum_d(acc[e]);
    if (lane == 0) {
      double lb[8];
#pragma unroll
      for (int e = 0; e < 8; ++e)
        lb[e] = (double)__bfloat162float(__float2bfloat16((float)acc[e]));
      double mx = lb[0];
#pragma unroll
      for (int e = 1; e < 8; ++e) mx = fmax(mx, lb[e]);
      double p[8];
#pragma unroll
      for (int e = 0; e < 8; ++e) p[e] = exp(lb[e] - mx);
      int i0 = 0;
      for (int e = 1; e < 8; ++e) if (p[e] > p[i0]) i0 = e;
      int i1 = (i0 == 0) ? 1 : 0;
      for (int e = 0; e < 8; ++e) if (e != i0 && p[e] > p[i1]) i1 = e;
      double den = p[i0] + p[i1];
      float o[8] = {0.f, 0.f, 0.f, 0.f, 0.f, 0.f, 0.f, 0.f};
      o[i0] = (float)(p[i0] / den);
      o[i1] = (float)(p[i1] / den);
#pragma unroll
      for (int e = 0; e < 8; ++e) gates[(size_t)t * 8 + e] = o[e];
      i01[t] = make_int2(i0, i1);
    }
  }
}

// ------------- per-expert ordered token lists (ballot prefix compaction) ---------------
__global__ __launch_bounds__(64) void k_lists(
    const int2* __restrict__ i01, int* __restrict__ lists,
    unsigned char* __restrict__ slots, int* __restrict__ cnt) {
  int e = blockIdx.x, lane = threadIdx.x;
  int* le = lists + e * TT;
  unsigned char* se = slots + e * TT;
  int base = 0;
  for (int it = 0; it < TT / 64; ++it) {
    int t = it * 64 + lane;
    int2 r = i01[t];
    bool hit0 = (r.x == e), hit1 = (r.y == e);
    bool hit = hit0 || hit1;
    unsigned long long m = __ballot(hit);
    int pos = base + __popcll(m & ((1ull << lane) - 1ull));
    if (hit) { le[pos] = t; se[pos] = hit0 ? 0 : 1; }
    base += __popcll(m);
  }
  if (lane == 0) cnt[e] = base;
}

// ------------- meta: segment offsets, tile->expert map, per-row gather tables ----------
__global__ __launch_bounds__(256) void k_meta(
    const int* __restrict__ cnt, const int* __restrict__ lists,
    const unsigned char* __restrict__ slots, const double* __restrict__ amax_clip,
    const double* __restrict__ wscale, int* __restrict__ meta,
    int* __restrict__ rowexp, int* __restrict__ tokidx,
    int* __restrict__ wrow, float* __restrict__ srow1c) {
  __shared__ int segs[9];
  __shared__ int scnt[8];
  int tid = threadIdx.x;
  if (tid == 0) {
    int acc = 0;
    for (int e = 0; e < 8; ++e) {
      scnt[e] = cnt[e];
      segs[e] = acc;
      acc += (cnt[e] + 127) & ~127;
    }
    segs[8] = acc;
    meta[0] = 32 + acc / 128;   // total row-tiles
    meta[1] = 4096 + acc;       // total compact rows
  }
  __syncthreads();
  int ntile = 32 + segs[8] / 128;
  for (int j = tid; j < NTILEMAX; j += 256) {
    int ei = -1;
    if (j < 16) ei = 0;
    else if (j < 32) ei = 1;
    else if (j < ntile) {
      int rr = (j - 32) * 128;
      for (int e = 0; e < 8; ++e)
        if (rr >= segs[e] && rr < segs[e + 1]) { ei = 2 + e; break; }
    }
    rowexp[j] = ei;
  }
  for (int r = tid; r < NRMAX; r += 256) {
    int t = 0; float s1 = 0.f; int w = -1;
    if (r < 4096) {
      int e = r >> 11; t = r & (TT - 1);
      double csc = wscale[e] * (1.0 / 127.0);
      s1 = (float)(amax_clip[t] * csc);
      w = e * TT + t;
    } else {
      int rr = r - 4096;
      if (rr < segs[8]) {
        int e = 0;
        for (int q = 0; q < 8; ++q)
          if (rr >= segs[q] && rr < segs[q + 1]) { e = q; break; }
        int k = rr - segs[e];
        if (k < scnt[e]) {
          t = lists[e * TT + k];
          int sl = slots[e * TT + k];
          double csc = wscale[4 + e] * (1.0 / 127.0);
          s1 = (float)(amax_clip[t] * csc);
          w = (2 + sl) * TT + t;
        }
      }
    }
    tokidx[r] = t; srow1c[r] = s1; wrow[r] = w;
  }
}

// ------------- GEMM1 (compact rows, gathered A): 128x64 tiles, BK=128 sub-tiled ------
__global__ __launch_bounds__(256) void k_g1(
    const signed char* __restrict__ qh, const signed char* __restrict__ q1T,
    const int* __restrict__ rowexp, const int* __restrict__ tokidx,
    const float* __restrict__ srow1c, const int* __restrict__ meta, int tile0,
    __hip_bfloat16* __restrict__ abuf_c, unsigned* __restrict__ rowmaxc) {
  __shared__ __align__(16) signed char As[2 * 8192];   // 2 slices x 128 rows x 64B
  __shared__ __align__(16) signed char Bs[2 * 4096];   // 2 slices x 64 rows x 64B
  int lid = blockIdx.x + 32 * blockIdx.y;          // 0..1151
  int nid = (lid & 7) * 144 + (lid >> 3);          // bijective XCD chunks
  int j = tile0 + (nid >> 5);
  if (j >= meta[0]) return;
  int col0 = (nid & 31) * 64;
  int ei = rowexp[j];
  int tid = threadIdx.x, lane = tid & 63, wid = tid >> 6;
  int wr = wid >> 1, wc = wid & 1;
  int rowt0 = j * 128;
  int sub = lane >> 2, seg = (lane & 3) * 16;
  int sr0 = wid * 32 + sub, sr1 = sr0 + 16;
  const signed char* a0 = qh + (size_t)tokidx[rowt0 + sr0] * DD + seg;
  const signed char* a1 = qh + (size_t)tokidx[rowt0 + sr1] * DD + seg;
  const signed char* b_src = q1T + (size_t)ei * FF * DD + (size_t)col0 * DD;
  signed char* lda0 = As + (wid * 32) * 64;
  signed char* lda1 = As + (wid * 32 + 16) * 64;
  int kg = (lane >> 4) * 16, rsel = lane & 15;
  v4i zero = {0, 0, 0, 0};
  v4i acc[4][2];
#pragma unroll
  for (int i = 0; i < 4; ++i)
#pragma unroll
    for (int jj = 0; jj < 2; ++jj) acc[i][jj] = zero;
  for (int k0 = 0; k0 < DD; k0 += 128) {
    __syncthreads();
#pragma unroll
    for (int c = 0; c < 2; ++c) {
      gll16(a0 + k0 + c * 64, lda0 + c * 8192);
      gll16(a1 + k0 + c * 64, lda1 + c * 8192);
      stage_rows<64>(b_src + k0 + c * 64, DD, Bs + c * 4096, tid);
    }
    __syncthreads();
#pragma unroll
    for (int kk = 0; kk < 2; ++kk) {
      v4i af[4], bf[2];
#pragma unroll
      for (int mi = 0; mi < 4; ++mi)
        af[mi] = *(const v4i*)(As + kk * 8192 + (wr * 64 + mi * 16 + rsel) * 64 + kg);
#pragma unroll
      for (int ni = 0; ni < 2; ++ni)
        bf[ni] = *(const v4i*)(Bs + kk * 4096 + (wc * 32 + ni * 16 + rsel) * 64 + kg);
#pragma unroll
      for (int mi = 0; mi < 4; ++mi)
#pragma unroll
        for (int ni = 0; ni < 2; ++ni)
          acc[mi][ni] = __builtin_amdgcn_mfma_i32_16x16x64_i8(af[mi], bf[ni], acc[mi][ni], 0, 0, 0);
    }
  }
  int rlocal0 = (j - tile0) * 128;
#pragma unroll
  for (int mi = 0; mi < 4; ++mi) {
#pragma unroll
    for (int rg = 0; rg < 4; ++rg) {
      int rof = wr * 64 + mi * 16 + ((lane >> 4) << 2) + rg;
      int tr = rowt0 + rof;
      float sA = srow1c[tr];
      float mloc = 0.f;
      int rl = rlocal0 + rof;
#pragma unroll
      for (int ni = 0; ni < 2; ++ni) {
        int fc = col0 + wc * 32 + ni * 16 + (lane & 15);
        float a = (float)acc[mi][ni][rg] * sA;
        float v = a / (1.f + expf(-a));
        __hip_bfloat16 vb = __float2bfloat16(v);
        float vq = __bfloat162float(vb);
        abuf_c[(size_t)rl * FF + fc] = vb;
        mloc = fmaxf(mloc, fabsf(vq));
      }
#pragma unroll
      for (int o = 1; o < 16; o <<= 1) mloc = fmaxf(mloc, __shfl_xor(mloc, o));
      if ((lane & 15) == 0) atomicMax(rowmaxc + tr, __float_as_uint(mloc));
    }
  }
}

// ------------- aquant (chunk of compact rows, bf16 input); explicit stride -----------
__device__ __forceinline__ void aq_body(
    const __hip_bfloat16* __restrict__ abuf_c, const unsigned* __restrict__ rowmaxc,
    const int* __restrict__ meta, int row0, signed char* __restrict__ qa,
    int bid, int nblocks, int tid) {
  int nrows = meta[1] - row0;
  if (nrows > CHROWS) nrows = CHROWS;
  if (nrows < 0) nrows = 0;
  int total4 = nrows * (FF / 4);
  int stride = nblocks * 256;
  for (int i = bid * 256 + tid; i < total4; i += stride) {
    int rl = i >> 9;
    int r = row0 + rl;
    float clip = fmaxf(__uint_as_float(rowmaxc[r]), 1e-5f);
    float s = 127.f / clip;
    ushort4 raw = ((const ushort4*)abuf_c)[i];
    float vx = __bfloat162float(*(__hip_bfloat16*)&raw.x);
    float vy = __bfloat162float(*(__hip_bfloat16*)&raw.y);
    float vz = __bfloat162float(*(__hip_bfloat16*)&raw.z);
    float vw = __bfloat162float(*(__hip_bfloat16*)&raw.w);
    int q0 = (int)fminf(127.f, fmaxf(-128.f, rintf(vx * s)));
    int q1 = (int)fminf(127.f, fmaxf(-128.f, rintf(vy * s)));
    int q2 = (int)fminf(127.f, fmaxf(-128.f, rintf(vz * s)));
    int q3 = (int)fminf(127.f, fmaxf(-128.f, rintf(vw * s)));
    ((unsigned*)qa)[(size_t)r * (FF / 4) + (i & 511)] = pack4(q0, q1, q2, q3);
  }
}

__global__ __launch_bounds__(256) void k_aq(
    const __hip_bfloat16* __restrict__ abuf_c, const unsigned* __restrict__ rowmaxc,
    const int* __restrict__ meta, int row0, signed char* __restrict__ qa) {
  aq_body(abuf_c, rowmaxc, meta, row0, qa, blockIdx.x, gridDim.x, threadIdx.x);
}

// fused: aq chunk2 (blocks 0..2047) | scg (2048..2083) — both ready after g1#2
__global__ __launch_bounds__(256) void k_aqs(
    const __hip_bfloat16* __restrict__ abuf_c, const unsigned* __restrict__ rowmaxc,
    const int* __restrict__ meta, signed char* __restrict__ qa,
    const double* __restrict__ wscale, const float* __restrict__ gates,
    const int* __restrict__ tokidx, const int* __restrict__ wrow,
    const int* __restrict__ rowexp, float* __restrict__ sgc) {
  int bid = blockIdx.x, tid = threadIdx.x;
  if (bid < 2048) {
    aq_body(abuf_c, rowmaxc, meta, CHROWS, qa, bid, 2048, tid);
  } else {
    int r = (bid - 2048) * 256 + tid;
    if (r >= NRMAX) return;
    int ei = rowexp[r >> 7];
    int w = wrow[r];
    if (ei < 0 || w < 0) { sgc[r] = 0.f; return; }
    float clip = fmaxf(__uint_as_float(rowmaxc[r]), 1e-5f);
    int t = tokidx[r];
    double csc = wscale[ei < 2 ? ei + 2 : ei + 10] * (1.0 / 127.0);
    float g = (ei < 2) ? 1.f : gates[(size_t)t * 8 + (ei - 2)];
    sgc[r] = (float)((double)clip * csc) * g;
  }
}

// ------------- GEMM2 (compact rows): 128x64 tiles, BK=128 sub-tiled -----------------
__global__ __launch_bounds__(256) void k_g2(
    const signed char* __restrict__ qa, const signed char* __restrict__ q2T,
    const int* __restrict__ rowexp, const float* __restrict__ sgc,
    const int* __restrict__ wrow, const int* __restrict__ meta,
    float* __restrict__ pbuf) {
  __shared__ __align__(16) signed char As[2 * 8192];   // 2 slices x 128 rows x 64B
  __shared__ __align__(16) signed char Bs[2 * 4096];   // 2 slices x 64 rows x 64B
  int lid = blockIdx.x + 16 * blockIdx.y;          // 0..1151
  int nid = (lid & 7) * 144 + (lid >> 3);
  int j = nid >> 4;
  if (j >= meta[0]) return;
  int col0 = (nid & 15) * 64;
  int ei = rowexp[j];
  int tid = threadIdx.x, lane = tid & 63, wid = tid >> 6;
  int wr = wid >> 1, wc = wid & 1;
  const signed char* ap = qa + (size_t)j * 128 * FF;
  const signed char* bp = q2T + (size_t)ei * DD * FF + (size_t)col0 * FF;
  int kg = (lane >> 4) * 16, rsel = lane & 15;
  v4i zero = {0, 0, 0, 0};
  v4i acc[4][2];
#pragma unroll
  for (int i = 0; i < 4; ++i)
#pragma unroll
    for (int jj = 0; jj < 2; ++jj) acc[i][jj] = zero;
  for (int k0 = 0; k0 < FF; k0 += 128) {
    __syncthreads();
#pragma unroll
    for (int c = 0; c < 2; ++c) {
      stage_rows<128>(ap + k0 + c * 64, FF, As + c * 8192, tid);
      stage_rows<64>(bp + k0 + c * 64, FF, Bs + c * 4096, tid);
    }
    __syncthreads();
#pragma unroll
    for (int kk = 0; kk < 2; ++kk) {
      v4i af[4], bf[2];
#pragma unroll
      for (int mi = 0; mi < 4; ++mi)
        af[mi] = *(const v4i*)(As + kk * 8192 + (wr * 64 + mi * 16 + rsel) * 64 + kg);
#pragma unroll
      for (int ni = 0; ni < 2; ++ni)
        bf[ni] = *(const v4i*)(Bs + kk * 4096 + (wc * 32 + ni * 16 + rsel) * 64 + kg);
#pragma unroll
      for (int mi = 0; mi < 4; ++mi)
#pragma unroll
        for (int ni = 0; ni < 2; ++ni)
          acc[mi][ni] = __builtin_amdgcn_mfma_i32_16x16x64_i8(af[mi], bf[ni], acc[mi][ni], 0, 0, 0);
    }
  }
#pragma unroll
  for (int mi = 0; mi < 4; ++mi) {
#pragma unroll
    for (int rg = 0; rg < 4; ++rg) {
      int tr = j * 128 + wr * 64 + mi * 16 + ((lane >> 4) << 2) + rg;
      int w = wrow[tr];
      float sc = sgc[tr];
      if (w >= 0) {
#pragma unroll
        for (int ni = 0; ni < 2; ++ni) {
          int dc = col0 + wc * 32 + ni * 16 + (lane & 15);
          pbuf[(size_t)w * DD + dc] = (float)acc[mi][ni][rg] * sc;
        }
      }
    }
  }
}

// ------------- combine: out = sum of 4 planes -------------
__global__ __launch_bounds__(256) void k_combine(
    const float* __restrict__ pbuf, float* __restrict__ out) {
  int i = blockIdx.x * 256 + threadIdx.x;  // float4 index
  float4 s = ((const float4*)pbuf)[i];
#pragma unroll
  for (int z = 1; z < 4; ++z) {
    float4 v = ((const float4*)(pbuf + (size_t)z * TT * DD))[i];
    s.x += v.x; s.y += v.y; s.z += v.z; s.w += v.w;
  }
  ((float4*)out)[i] = s;
}

extern "C" void kernel_launch(void* const* d_in, const int* in_sizes, int n_in,
                              void* d_out, int out_size, void* d_ws, size_t ws_size,
                              hipStream_t stream) {
  const float* x    = (const float*)d_in[0];
  const float* rmsw = (const float*)d_in[1];
  const float* w1s  = (const float*)d_in[2];
  const float* w2s  = (const float*)d_in[3];
  const float* w1r  = (const float*)d_in[4];
  const float* w2r  = (const float*)d_in[5];
  const float* rw   = (const float*)d_in[6];
  float* out = (float*)d_out;

  char* ws = (char*)d_ws;
  // footprint ends at 0x7E80000 ~= 132.6MB (proven safe)
  double* amax_clip      = (double*)(ws + 0x0000000);   // 16KB
  double* part           = (double*)(ws + 0x0004000);   // 20KB (20*128 f64)
  double* wscale         = (double*)(ws + 0x0018000);   // 160B
  float* gates           = (float*)(ws + 0x0019000);    // 64KB
  int2* i01              = (int2*)(ws + 0x0029000);     // 16KB
  int* lists             = (int*)(ws + 0x002D000);      // 64KB
  unsigned char* slots   = (unsigned char*)(ws + 0x003D000); // 16KB
  int* cnt               = (int*)(ws + 0x0041000);      // 32B
  int* meta              = (int*)(ws + 0x0041100);      // 64B
  int* tokidx            = (int*)(ws + 0x0042000);      // 36KB
  int* wrow              = (int*)(ws + 0x004B000);      // 36KB
  float* srow1c          = (float*)(ws + 0x0054000);    // 36KB
  float* sgc             = (float*)(ws + 0x005D000);    // 36KB
  int* rowexp            = (int*)(ws + 0x0066000);      // 288B
  unsigned* rowmaxc      = (unsigned*)(ws + 0x0067000); // 36KB
  signed char* qh        = (signed char*)(ws + 0x0080000);    // 2MB
  __hip_bfloat16* hb     = (__hip_bfloat16*)(ws + 0x0280000); // 4MB
  signed char* q1T       = (signed char*)(ws + 0x0680000);    // 20MB
  signed char* q2T       = (signed char*)(ws + 0x1A80000);    // 20MB
  signed char* qa        = (signed char*)(ws + 0x2E80000);    // <=18.9MB (40MB region)
  float* pbuf            = (float*)(ws + 0x5680000);          // 4 planes = 32MB (40MB region)
  __hip_bfloat16* abuf_c = (__hip_bfloat16*)pbuf;  // alias: bf16 chunk used before g2 writes pbuf

  // fused prologue: wabs (2560) | rms_quant (2048) | rowmax zero (36)
  k_pro<<<4644, 256, 0, stream>>>(w1s, w2s, w1r, w2r, part,
                                  x, rmsw, qh, hb, amax_clip, rowmaxc);
  k_wscale_final<<<20, 64, 0, stream>>>(part, wscale);
  // fused mid: wquant (10240) | router (512 blocks x 4 tokens)
  k_mid<<<10752, 256, 0, stream>>>(w1s, w2s, w1r, w2r, wscale, q1T, q2T,
                                   hb, rw, gates, i01);
  k_lists<<<8, 64, 0, stream>>>(i01, lists, slots, cnt);
  k_meta<<<1, 256, 0, stream>>>(cnt, lists, slots, amax_clip, wscale,
                                meta, rowexp, tokidx, wrow, srow1c);

  dim3 g1(32, CHTILES);
  k_g1<<<g1, 256, 0, stream>>>(qh, q1T, rowexp, tokidx, srow1c, meta, 0,
                               abuf_c, rowmaxc);
  k_aq<<<2048, 256, 0, stream>>>(abuf_c, rowmaxc, meta, 0, qa);
  k_g1<<<g1, 256, 0, stream>>>(qh, q1T, rowexp, tokidx, srow1c, meta, CHTILES,
                               abuf_c, rowmaxc);
  // fused: aq chunk2 (2048) | scg (36)
  k_aqs<<<2048 + 36, 256, 0, stream>>>(abuf_c, rowmaxc, meta, qa,
                                       wscale, gates, tokidx, wrow, rowexp, sgc);
  dim3 g2(16, NTILEMAX);
  k_g2<<<g2, 256, 0, stream>>>(qa, q2T, rowexp, sgc, wrow, meta, pbuf);
  k_combine<<<TT * DD / 4 / 256, 256, 0, stream>>>(pbuf, out);
}

// Round 22
// 220.057 us; speedup vs baseline: 1.4596x; 1.0613x over previous
//
#include <hip/hip_runtime.h>
#include <hip/hip_bf16.h>

#define TT 2048
#define DD 1024
#define FF 2048
#define NEXPI 10     // 2 shared + 8 routed expert instances
#define NRMAX 9216   // max compact rows: 4096 shared + 4096 routed + <=1024 pad
#define NTILEMAX 72  // NRMAX/128

typedef __attribute__((ext_vector_type(4))) int v4i;
typedef __attribute__((ext_vector_type(4))) float f32x4;

__device__ __forceinline__ double wave_sum_d(double v) {
#pragma unroll
  for (int o = 32; o > 0; o >>= 1) v += __shfl_down(v, o);
  return v;
}
__device__ __forceinline__ double wave_max_d(double v) {
#pragma unroll
  for (int o = 32; o > 0; o >>= 1) v = fmax(v, __shfl_down(v, o));
  return v;
}

// async global->LDS, 16B per lane; lds dest is wave-uniform base, lane l lands at +l*16
__device__ __forceinline__ void gll16(const void* g, void* l) {
  __builtin_amdgcn_global_load_lds(
      (const __attribute__((address_space(1))) void*)g,
      (__attribute__((address_space(3))) void*)l, 16, 0, 0);
}

// stage ROWS x 64B tile (i8, row stride K bytes in global) into linear LDS
template<int ROWS>
__device__ __forceinline__ void stage_rows(const signed char* src, int K,
                                           signed char* lds, int tid) {
  int w = tid >> 6, l = tid & 63;
  int sub = l >> 2, seg = (l & 3) * 16;
#pragma unroll
  for (int i = 0; i < ROWS / 64; ++i) {
    int rbase = w * (ROWS / 4) + i * 16;
    gll16(src + (size_t)(rbase + sub) * K + seg, lds + rbase * 64);
  }
}

// ------------- fused prologue: wabs (blocks 0..2559) | rmsnorm+quant (2560..4607)
//               | rowmax zero (4608..4643). All three independent. -------------
__global__ __launch_bounds__(256) void k_pro(
    const float* __restrict__ w1s, const float* __restrict__ w2s,
    const float* __restrict__ w1r, const float* __restrict__ w2r,
    double* __restrict__ part,
    const float* __restrict__ x, const float* __restrict__ rw,
    signed char* __restrict__ qh, __hip_bfloat16* __restrict__ hb,
    double* __restrict__ amax_clip, unsigned* __restrict__ rm) {
  __shared__ double red[12];
  int bid = blockIdx.x, tid = threadIdx.x;
  if (bid < 2560) {
    int m = bid >> 7, blk = bid & 127;
    const float* base;
    if (m < 2)       base = w1s + (size_t)m * (DD * FF);
    else if (m < 4)  base = w2s + (size_t)(m - 2) * (DD * FF);
    else if (m < 12) base = w1r + (size_t)(m - 4) * (DD * FF);
    else             base = w2r + (size_t)(m - 12) * (DD * FF);
    const f32x4* p = (const f32x4*)base + (size_t)blk * 4096;
    double s0 = 0.0, s1 = 0.0, s2 = 0.0, s3 = 0.0;
#pragma unroll
    for (int b = 0; b < 2; ++b) {
      f32x4 v[8];
#pragma unroll
      for (int i = 0; i < 8; ++i)
        v[i] = p[tid + (b * 8 + i) * 256];
#pragma unroll
      for (int i = 0; i < 8; i += 4) {
        s0 += (double)fabsf(v[i+0].x) + (double)fabsf(v[i+0].y) +
              (double)fabsf(v[i+0].z) + (double)fabsf(v[i+0].w);
        s1 += (double)fabsf(v[i+1].x) + (double)fabsf(v[i+1].y) +
              (double)fabsf(v[i+1].z) + (double)fabsf(v[i+1].w);
        s2 += (double)fabsf(v[i+2].x) + (double)fabsf(v[i+2].y) +
              (double)fabsf(v[i+2].z) + (double)fabsf(v[i+2].w);
        s3 += (double)fabsf(v[i+3].x) + (double)fabsf(v[i+3].y) +
              (double)fabsf(v[i+3].z) + (double)fabsf(v[i+3].w);
      }
    }
    double s = (s0 + s1) + (s2 + s3);
    s = wave_sum_d(s);
    int lane = tid & 63, wid = tid >> 6;
    if (lane == 0) red[wid] = s;
    __syncthreads();
    if (tid == 0) part[m * 128 + blk] = red[0] + red[1] + red[2] + red[3];
  } else if (bid < 4608) {
    int t = bid - 2560;
    int lane = tid & 63, wid = tid >> 6;
    float4 xv = ((const float4*)(x + (size_t)t * DD))[tid];
    double x0 = xv.x, x1 = xv.y, x2 = xv.z, x3 = xv.w;
    double ss = x0 * x0 + x1 * x1 + x2 * x2 + x3 * x3;
    ss = wave_sum_d(ss);
    if (lane == 0) red[wid] = ss;
    __syncthreads();
    if (tid == 0) {
      double s = red[0] + red[1] + red[2] + red[3];
      red[8] = 1.0 / sqrt(s * (1.0 / DD) + 1e-6);
    }
    __syncthreads();
    double r = red[8];
    float4 wv = ((const float4*)rw)[tid];
    double h0 = x0 * r * (double)wv.x, h1 = x1 * r * (double)wv.y;
    double h2 = x2 * r * (double)wv.z, h3 = x3 * r * (double)wv.w;
    __hip_bfloat16* hp = hb + (size_t)t * DD + tid * 4;
    hp[0] = __float2bfloat16((float)h0); hp[1] = __float2bfloat16((float)h1);
    hp[2] = __float2bfloat16((float)h2); hp[3] = __float2bfloat16((float)h3);
    double am = fmax(fmax(fabs(h0), fabs(h1)), fmax(fabs(h2), fabs(h3)));
    am = wave_max_d(am);
    if (lane == 0) red[4 + wid] = am;
    __syncthreads();
    if (tid == 0) {
      double a = fmax(fmax(red[4], red[5]), fmax(red[6], red[7]));
      red[9] = fmax(a, 1e-5);
    }
    __syncthreads();
    double clipv = red[9];
    if (tid == 0) amax_clip[t] = clipv;
    double s = 127.0 / clipv;
    int q0 = (int)fmin(127.0, fmax(-128.0, rint(h0 * s)));
    int q1 = (int)fmin(127.0, fmax(-128.0, rint(h1 * s)));
    int q2 = (int)fmin(127.0, fmax(-128.0, rint(h2 * s)));
    int q3 = (int)fmin(127.0, fmax(-128.0, rint(h3 * s)));
    unsigned pw = (unsigned)(q0 & 255) | ((unsigned)(q1 & 255) << 8) |
                  ((unsigned)(q2 & 255) << 16) | ((unsigned)(q3 & 255) << 24);
    *(unsigned*)(qh + (size_t)t * DD + tid * 4) = pw;
  } else {
    int i = (bid - 4608) * 256 + tid;
    if (i < NRMAX) rm[i] = 0u;
  }
}

__global__ __launch_bounds__(64) void k_wscale_final(
    const double* __restrict__ part, double* __restrict__ wscale) {
  int m = blockIdx.x;
  double v = part[m * 128 + threadIdx.x] + part[m * 128 + 64 + threadIdx.x];
  v = wave_sum_d(v);
  if (threadIdx.x == 0) wscale[m] = v * (1.0 / 2097152.0) + 1e-8;
}

// ------------- ternary quant helper (f64 bins) -------------
__device__ __forceinline__ int qtern(float v, double winv) {
  double q = rint((double)v * winv);
  return (int)fmin(1.0, fmax(-1.0, q));
}
__device__ __forceinline__ unsigned pack4(int a, int b, int c, int d) {
  return (unsigned)(a & 255) | ((unsigned)(b & 255) << 8) |
         ((unsigned)(c & 255) << 16) | ((unsigned)(d & 255) << 24);
}

// ------------- fused mid: wquant (blocks 0..10239) | router (10240..10751) ----------
__global__ __launch_bounds__(256) void k_mid(
    const float* __restrict__ w1s, const float* __restrict__ w2s,
    const float* __restrict__ w1r, const float* __restrict__ w2r,
    const double* __restrict__ wscale,
    signed char* __restrict__ q1T, signed char* __restrict__ q2T,
    const __hip_bfloat16* __restrict__ hb, const float* __restrict__ rw,
    float* __restrict__ gates, int2* __restrict__ i01) {
  int bid = blockIdx.x, tidx = threadIdx.x;
  if (bid < 10240) {
    __shared__ signed char tile[64 * 68];
    int m = bid >> 9, t = bid & 511;
    const float* src;
    signed char* dst;
    int ld, ldo, rt, ct;
    if (m < 2) {
      src = w1s + (size_t)m * DD * FF;
      dst = q1T + (size_t)m * FF * DD;
      ld = FF; ldo = DD; rt = t >> 5; ct = t & 31;
    } else if (m < 4) {
      src = w2s + (size_t)(m - 2) * FF * DD;
      dst = q2T + (size_t)(m - 2) * DD * FF;
      ld = DD; ldo = FF; rt = t >> 4; ct = t & 15;
    } else if (m < 12) {
      src = w1r + (size_t)(m - 4) * DD * FF;
      dst = q1T + (size_t)(m - 2) * FF * DD;
      ld = FF; ldo = DD; rt = t >> 5; ct = t & 31;
    } else {
      src = w2r + (size_t)(m - 12) * FF * DD;
      dst = q2T + (size_t)(m - 10) * DD * FF;
      ld = DD; ldo = FF; rt = t >> 4; ct = t & 15;
    }
    double winv = 1.0 / wscale[m];
    int row0 = rt * 64, col0 = ct * 64;
    int r = tidx >> 2, sc_ = (tidx & 3) * 16;
    const float* sp = src + (size_t)(row0 + r) * ld + col0 + sc_;
#pragma unroll
    for (int g = 0; g < 4; ++g) {
      float4 v = *(const float4*)(sp + g * 4);
      unsigned pk = pack4(qtern(v.x, winv), qtern(v.y, winv),
                          qtern(v.z, winv), qtern(v.w, winv));
      *(unsigned*)(tile + r * 68 + sc_ + g * 4) = pk;
    }
    __syncthreads();
    int c = tidx >> 2, sr = (tidx & 3) * 16;
    unsigned o[4];
#pragma unroll
    for (int g = 0; g < 4; ++g) {
      int j = sr + g * 4;
      o[g] = pack4(tile[(j + 0) * 68 + c], tile[(j + 1) * 68 + c],
                   tile[(j + 2) * 68 + c], tile[(j + 3) * 68 + c]);
    }
    int4 ov = make_int4((int)o[0], (int)o[1], (int)o[2], (int)o[3]);
    *(int4*)(dst + (size_t)(col0 + c) * ldo + row0 + sr) = ov;
  } else {
    // router: 4 tokens per block, one 64-lane wave each
    int t = (bid - 10240) * 4 + (tidx >> 6);
    int lane = tidx & 63;
    double acc[8];
#pragma unroll
    for (int e = 0; e < 8; ++e) acc[e] = 0.0;
    const __hip_bfloat16* hp = hb + (size_t)t * DD;
    for (int d = lane; d < DD; d += 64) {
      double hv = (double)__bfloat162float(hp[d]);
#pragma unroll
      for (int e = 0; e < 8; ++e) {
        double wv = (double)__bfloat162float(__float2bfloat16(rw[e * DD + d]));
        acc[e] += hv * wv;
      }
    }
#pragma unroll
    for (int e = 0; e < 8; ++e) acc[e] = wave_sum_d(acc[e]);
    if (lane == 0) {
      double lb[8];
#pragma unroll
      for (int e = 0; e < 8; ++e)
        lb[e] = (double)__bfloat162float(__float2bfloat16((float)acc[e]));
      double mx = lb[0];
#pragma unroll
      for (int e = 1; e < 8; ++e) mx = fmax(mx, lb[e]);
      double p[8];
#pragma unroll
      for (int e = 0; e < 8; ++e) p[e] = exp(lb[e] - mx);
      int i0 = 0;
      for (int e = 1; e < 8; ++e) if (p[e] > p[i0]) i0 = e;
      int i1 = (i0 == 0) ? 1 : 0;
      for (int e = 0; e < 8; ++e) if (e != i0 && p[e] > p[i1]) i1 = e;
      double den = p[i0] + p[i1];
      float o[8] = {0.f, 0.f, 0.f, 0.f, 0.f, 0.f, 0.f, 0.f};
      o[i0] = (float)(p[i0] / den);
      o[i1] = (float)(p[i1] / den);
#pragma unroll
      for (int e = 0; e < 8; ++e) gates[(size_t)t * 8 + e] = o[e];
      i01[t] = make_int2(i0, i1);
    }
  }
}

// ------------- per-expert ordered token lists (ballot prefix compaction) ---------------
__global__ __launch_bounds__(64) void k_lists(
    const int2* __restrict__ i01, int* __restrict__ lists,
    unsigned char* __restrict__ slots, int* __restrict__ cnt) {
  int e = blockIdx.x, lane = threadIdx.x;
  int* le = lists + e * TT;
  unsigned char* se = slots + e * TT;
  int base = 0;
  for (int it = 0; it < TT / 64; ++it) {
    int t = it * 64 + lane;
    int2 r = i01[t];
    bool hit0 = (r.x == e), hit1 = (r.y == e);
    bool hit = hit0 || hit1;
    unsigned long long m = __ballot(hit);
    int pos = base + __popcll(m & ((1ull << lane) - 1ull));
    if (hit) { le[pos] = t; se[pos] = hit0 ? 0 : 1; }
    base += __popcll(m);
  }
  if (lane == 0) cnt[e] = base;
}

// ------------- meta: segment offsets, tile->expert map, per-row gather tables ----------
__global__ __launch_bounds__(256) void k_meta(
    const int* __restrict__ cnt, const int* __restrict__ lists,
    const unsigned char* __restrict__ slots, const double* __restrict__ amax_clip,
    const double* __restrict__ wscale, int* __restrict__ meta,
    int* __restrict__ rowexp, int* __restrict__ tokidx,
    int* __restrict__ wrow, float* __restrict__ srow1c) {
  __shared__ int segs[9];
  __shared__ int scnt[8];
  int tid = threadIdx.x;
  if (tid == 0) {
    int acc = 0;
    for (int e = 0; e < 8; ++e) {
      scnt[e] = cnt[e];
      segs[e] = acc;
      acc += (cnt[e] + 127) & ~127;
    }
    segs[8] = acc;
    meta[0] = 32 + acc / 128;   // total row-tiles
    meta[1] = 4096 + acc;       // total compact rows
  }
  __syncthreads();
  int ntile = 32 + segs[8] / 128;
  for (int j = tid; j < NTILEMAX; j += 256) {
    int ei = -1;
    if (j < 16) ei = 0;
    else if (j < 32) ei = 1;
    else if (j < ntile) {
      int rr = (j - 32) * 128;
      for (int e = 0; e < 8; ++e)
        if (rr >= segs[e] && rr < segs[e + 1]) { ei = 2 + e; break; }
    }
    rowexp[j] = ei;
  }
  for (int r = tid; r < NRMAX; r += 256) {
    int t = 0; float s1 = 0.f; int w = -1;
    if (r < 4096) {
      int e = r >> 11; t = r & (TT - 1);
      double csc = wscale[e] * (1.0 / 127.0);
      s1 = (float)(amax_clip[t] * csc);
      w = e * TT + t;
    } else {
      int rr = r - 4096;
      if (rr < segs[8]) {
        int e = 0;
        for (int q = 0; q < 8; ++q)
          if (rr >= segs[q] && rr < segs[q + 1]) { e = q; break; }
        int k = rr - segs[e];
        if (k < scnt[e]) {
          t = lists[e * TT + k];
          int sl = slots[e * TT + k];
          double csc = wscale[4 + e] * (1.0 / 127.0);
          s1 = (float)(amax_clip[t] * csc);
          w = (2 + sl) * TT + t;
        }
      }
    }
    tokidx[r] = t; srow1c[r] = s1; wrow[r] = w;
  }
}

// ------------- GEMM1 (compact rows, gathered A): 128x64 tiles, BK=128 sub-tiled ------
// SINGLE launch over all row-tiles; abuf covers all compact rows (bf16, 36MB)
// fixed grid (32, NTILEMAX) = 2304 blocks; bijective XCD swizzle (chunks of 288)
__global__ __launch_bounds__(256) void k_g1(
    const signed char* __restrict__ qh, const signed char* __restrict__ q1T,
    const int* __restrict__ rowexp, const int* __restrict__ tokidx,
    const float* __restrict__ srow1c, const int* __restrict__ meta,
    __hip_bfloat16* __restrict__ abuf, unsigned* __restrict__ rowmaxc) {
  __shared__ __align__(16) signed char As[2 * 8192];   // 2 slices x 128 rows x 64B
  __shared__ __align__(16) signed char Bs[2 * 4096];   // 2 slices x 64 rows x 64B
  int lid = blockIdx.x + 32 * blockIdx.y;          // 0..2303
  int nid = (lid & 7) * 288 + (lid >> 3);          // bijective XCD chunks
  int j = nid >> 5;
  if (j >= meta[0]) return;
  int col0 = (nid & 31) * 64;
  int ei = rowexp[j];
  int tid = threadIdx.x, lane = tid & 63, wid = tid >> 6;
  int wr = wid >> 1, wc = wid & 1;
  int rowt0 = j * 128;
  int sub = lane >> 2, seg = (lane & 3) * 16;
  int sr0 = wid * 32 + sub, sr1 = sr0 + 16;
  const signed char* a0 = qh + (size_t)tokidx[rowt0 + sr0] * DD + seg;
  const signed char* a1 = qh + (size_t)tokidx[rowt0 + sr1] * DD + seg;
  const signed char* b_src = q1T + (size_t)ei * FF * DD + (size_t)col0 * DD;
  signed char* lda0 = As + (wid * 32) * 64;
  signed char* lda1 = As + (wid * 32 + 16) * 64;
  int kg = (lane >> 4) * 16, rsel = lane & 15;
  v4i zero = {0, 0, 0, 0};
  v4i acc[4][2];
#pragma unroll
  for (int i = 0; i < 4; ++i)
#pragma unroll
    for (int jj = 0; jj < 2; ++jj) acc[i][jj] = zero;
  for (int k0 = 0; k0 < DD; k0 += 128) {
    __syncthreads();
#pragma unroll
    for (int c = 0; c < 2; ++c) {
      gll16(a0 + k0 + c * 64, lda0 + c * 8192);
      gll16(a1 + k0 + c * 64, lda1 + c * 8192);
      stage_rows<64>(b_src + k0 + c * 64, DD, Bs + c * 4096, tid);
    }
    __syncthreads();
#pragma unroll
    for (int kk = 0; kk < 2; ++kk) {
      v4i af[4], bf[2];
#pragma unroll
      for (int mi = 0; mi < 4; ++mi)
        af[mi] = *(const v4i*)(As + kk * 8192 + (wr * 64 + mi * 16 + rsel) * 64 + kg);
#pragma unroll
      for (int ni = 0; ni < 2; ++ni)
        bf[ni] = *(const v4i*)(Bs + kk * 4096 + (wc * 32 + ni * 16 + rsel) * 64 + kg);
#pragma unroll
      for (int mi = 0; mi < 4; ++mi)
#pragma unroll
        for (int ni = 0; ni < 2; ++ni)
          acc[mi][ni] = __builtin_amdgcn_mfma_i32_16x16x64_i8(af[mi], bf[ni], acc[mi][ni], 0, 0, 0);
    }
  }
#pragma unroll
  for (int mi = 0; mi < 4; ++mi) {
#pragma unroll
    for (int rg = 0; rg < 4; ++rg) {
      int rof = wr * 64 + mi * 16 + ((lane >> 4) << 2) + rg;
      int tr = rowt0 + rof;
      float sA = srow1c[tr];
      float mloc = 0.f;
#pragma unroll
      for (int ni = 0; ni < 2; ++ni) {
        int fc = col0 + wc * 32 + ni * 16 + (lane & 15);
        float a = (float)acc[mi][ni][rg] * sA;
        float v = a / (1.f + expf(-a));
        __hip_bfloat16 vb = __float2bfloat16(v);
        float vq = __bfloat162float(vb);
        abuf[(size_t)tr * FF + fc] = vb;
        mloc = fmaxf(mloc, fabsf(vq));
      }
#pragma unroll
      for (int o = 1; o < 16; o <<= 1) mloc = fmaxf(mloc, __shfl_xor(mloc, o));
      if ((lane & 15) == 0) atomicMax(rowmaxc + tr, __float_as_uint(mloc));
    }
  }
}

// ------------- fused: aquant over ALL compact rows (blocks 0..4095) | scg (4096..4131)
__global__ __launch_bounds__(256) void k_aqs(
    const __hip_bfloat16* __restrict__ abuf, const unsigned* __restrict__ rowmaxc,
    const int* __restrict__ meta, signed char* __restrict__ qa,
    const double* __restrict__ wscale, const float* __restrict__ gates,
    const int* __restrict__ tokidx, const int* __restrict__ wrow,
    const int* __restrict__ rowexp, float* __restrict__ sgc) {
  int bid = blockIdx.x, tid = threadIdx.x;
  if (bid < 4096) {
    int nrows = meta[1];
    if (nrows > NRMAX) nrows = NRMAX;
    int total4 = nrows * (FF / 4);
    int stride = 4096 * 256;
    for (int i = bid * 256 + tid; i < total4; i += stride) {
      int r = i >> 9;
      float clip = fmaxf(__uint_as_float(rowmaxc[r]), 1e-5f);
      float s = 127.f / clip;
      ushort4 raw = ((const ushort4*)abuf)[i];
      float vx = __bfloat162float(*(__hip_bfloat16*)&raw.x);
      float vy = __bfloat162float(*(__hip_bfloat16*)&raw.y);
      float vz = __bfloat162float(*(__hip_bfloat16*)&raw.z);
      float vw = __bfloat162float(*(__hip_bfloat16*)&raw.w);
      int q0 = (int)fminf(127.f, fmaxf(-128.f, rintf(vx * s)));
      int q1 = (int)fminf(127.f, fmaxf(-128.f, rintf(vy * s)));
      int q2 = (int)fminf(127.f, fmaxf(-128.f, rintf(vz * s)));
      int q3 = (int)fminf(127.f, fmaxf(-128.f, rintf(vw * s)));
      ((unsigned*)qa)[(size_t)r * (FF / 4) + (i & 511)] = pack4(q0, q1, q2, q3);
    }
  } else {
    int r = (bid - 4096) * 256 + tid;
    if (r >= NRMAX) return;
    int ei = rowexp[r >> 7];
    int w = wrow[r];
    if (ei < 0 || w < 0) { sgc[r] = 0.f; return; }
    float clip = fmaxf(__uint_as_float(rowmaxc[r]), 1e-5f);
    int t = tokidx[r];
    double csc = wscale[ei < 2 ? ei + 2 : ei + 10] * (1.0 / 127.0);
    float g = (ei < 2) ? 1.f : gates[(size_t)t * 8 + (ei - 2)];
    sgc[r] = (float)((double)clip * csc) * g;
  }
}

// ------------- GEMM2 (compact rows): 128x64 tiles, BK=128 sub-tiled -----------------
__global__ __launch_bounds__(256) void k_g2(
    const signed char* __restrict__ qa, const signed char* __restrict__ q2T,
    const int* __restrict__ rowexp, const float* __restrict__ sgc,
    const int* __restrict__ wrow, const int* __restrict__ meta,
    float* __restrict__ pbuf) {
  __shared__ __align__(16) signed char As[2 * 8192];   // 2 slices x 128 rows x 64B
  __shared__ __align__(16) signed char Bs[2 * 4096];   // 2 slices x 64 rows x 64B
  int lid = blockIdx.x + 16 * blockIdx.y;          // 0..1151
  int nid = (lid & 7) * 144 + (lid >> 3);
  int j = nid >> 4;
  if (j >= meta[0]) return;
  int col0 = (nid & 15) * 64;
  int ei = rowexp[j];
  int tid = threadIdx.x, lane = tid & 63, wid = tid >> 6;
  int wr = wid >> 1, wc = wid & 1;
  const signed char* ap = qa + (size_t)j * 128 * FF;
  const signed char* bp = q2T + (size_t)ei * DD * FF + (size_t)col0 * FF;
  int kg = (lane >> 4) * 16, rsel = lane & 15;
  v4i zero = {0, 0, 0, 0};
  v4i acc[4][2];
#pragma unroll
  for (int i = 0; i < 4; ++i)
#pragma unroll
    for (int jj = 0; jj < 2; ++jj) acc[i][jj] = zero;
  for (int k0 = 0; k0 < FF; k0 += 128) {
    __syncthreads();
#pragma unroll
    for (int c = 0; c < 2; ++c) {
      stage_rows<128>(ap + k0 + c * 64, FF, As + c * 8192, tid);
      stage_rows<64>(bp + k0 + c * 64, FF, Bs + c * 4096, tid);
    }
    __syncthreads();
#pragma unroll
    for (int kk = 0; kk < 2; ++kk) {
      v4i af[4], bf[2];
#pragma unroll
      for (int mi = 0; mi < 4; ++mi)
        af[mi] = *(const v4i*)(As + kk * 8192 + (wr * 64 + mi * 16 + rsel) * 64 + kg);
#pragma unroll
      for (int ni = 0; ni < 2; ++ni)
        bf[ni] = *(const v4i*)(Bs + kk * 4096 + (wc * 32 + ni * 16 + rsel) * 64 + kg);
#pragma unroll
      for (int mi = 0; mi < 4; ++mi)
#pragma unroll
        for (int ni = 0; ni < 2; ++ni)
          acc[mi][ni] = __builtin_amdgcn_mfma_i32_16x16x64_i8(af[mi], bf[ni], acc[mi][ni], 0, 0, 0);
    }
  }
#pragma unroll
  for (int mi = 0; mi < 4; ++mi) {
#pragma unroll
    for (int rg = 0; rg < 4; ++rg) {
      int tr = j * 128 + wr * 64 + mi * 16 + ((lane >> 4) << 2) + rg;
      int w = wrow[tr];
      float sc = sgc[tr];
      if (w >= 0) {
#pragma unroll
        for (int ni = 0; ni < 2; ++ni) {
          int dc = col0 + wc * 32 + ni * 16 + (lane & 15);
          pbuf[(size_t)w * DD + dc] = (float)acc[mi][ni][rg] * sc;
        }
      }
    }
  }
}

// ------------- combine: out = sum of 4 planes -------------
__global__ __launch_bounds__(256) void k_combine(
    const float* __restrict__ pbuf, float* __restrict__ out) {
  int i = blockIdx.x * 256 + threadIdx.x;  // float4 index
  float4 s = ((const float4*)pbuf)[i];
#pragma unroll
  for (int z = 1; z < 4; ++z) {
    float4 v = ((const float4*)(pbuf + (size_t)z * TT * DD))[i];
    s.x += v.x; s.y += v.y; s.z += v.z; s.w += v.w;
  }
  ((float4*)out)[i] = s;
}

extern "C" void kernel_launch(void* const* d_in, const int* in_sizes, int n_in,
                              void* d_out, int out_size, void* d_ws, size_t ws_size,
                              hipStream_t stream) {
  const float* x    = (const float*)d_in[0];
  const float* rmsw = (const float*)d_in[1];
  const float* w1s  = (const float*)d_in[2];
  const float* w2s  = (const float*)d_in[3];
  const float* w1r  = (const float*)d_in[4];
  const float* w2r  = (const float*)d_in[5];
  const float* rw   = (const float*)d_in[6];
  float* out = (float*)d_out;

  char* ws = (char*)d_ws;
  // footprint ends at 0x7E80000 ~= 132.6MB (proven safe)
  double* amax_clip      = (double*)(ws + 0x0000000);   // 16KB
  double* part           = (double*)(ws + 0x0004000);   // 20KB (20*128 f64)
  double* wscale         = (double*)(ws + 0x0018000);   // 160B
  float* gates           = (float*)(ws + 0x0019000);    // 64KB
  int2* i01              = (int2*)(ws + 0x0029000);     // 16KB
  int* lists             = (int*)(ws + 0x002D000);      // 64KB
  unsigned char* slots   = (unsigned char*)(ws + 0x003D000); // 16KB
  int* cnt               = (int*)(ws + 0x0041000);      // 32B
  int* meta              = (int*)(ws + 0x0041100);      // 64B
  int* tokidx            = (int*)(ws + 0x0042000);      // 36KB
  int* wrow              = (int*)(ws + 0x004B000);      // 36KB
  float* srow1c          = (float*)(ws + 0x0054000);    // 36KB
  float* sgc             = (float*)(ws + 0x005D000);    // 36KB
  int* rowexp            = (int*)(ws + 0x0066000);      // 288B
  unsigned* rowmaxc      = (unsigned*)(ws + 0x0067000); // 36KB
  signed char* qh        = (signed char*)(ws + 0x0080000);    // 2MB
  __hip_bfloat16* hb     = (__hip_bfloat16*)(ws + 0x0280000); // 4MB
  signed char* q1T       = (signed char*)(ws + 0x0680000);    // 20MB
  signed char* q2T       = (signed char*)(ws + 0x1A80000);    // 20MB
  signed char* qa        = (signed char*)(ws + 0x2E80000);    // <=18.9MB (40MB region)
  float* pbuf            = (float*)(ws + 0x5680000);          // 4 planes = 32MB (40MB region)
  __hip_bfloat16* abuf   = (__hip_bfloat16*)pbuf;  // alias: full bf16 abuf (36MB) used before g2 writes pbuf

  // fused prologue: wabs (2560) | rms_quant (2048) | rowmax zero (36)
  k_pro<<<4644, 256, 0, stream>>>(w1s, w2s, w1r, w2r, part,
                                  x, rmsw, qh, hb, amax_clip, rowmaxc);
  k_wscale_final<<<20, 64, 0, stream>>>(part, wscale);
  // fused mid: wquant (10240) | router (512 blocks x 4 tokens)
  k_mid<<<10752, 256, 0, stream>>>(w1s, w2s, w1r, w2r, wscale, q1T, q2T,
                                   hb, rw, gates, i01);
  k_lists<<<8, 64, 0, stream>>>(i01, lists, slots, cnt);
  k_meta<<<1, 256, 0, stream>>>(cnt, lists, slots, amax_clip, wscale,
                                meta, rowexp, tokidx, wrow, srow1c);

  // single gemm1 over all compact rows
  dim3 g1(32, NTILEMAX);
  k_g1<<<g1, 256, 0, stream>>>(qh, q1T, rowexp, tokidx, srow1c, meta,
                               abuf, rowmaxc);
  // fused: aquant all rows (4096) | scg (36)
  k_aqs<<<4096 + 36, 256, 0, stream>>>(abuf, rowmaxc, meta, qa,
                                       wscale, gates, tokidx, wrow, rowexp, sgc);
  dim3 g2(16, NTILEMAX);
  k_g2<<<g2, 256, 0, stream>>>(qa, q2T, rowexp, sgc, wrow, meta, pbuf);
  k_combine<<<TT * DD / 4 / 256, 256, 0, stream>>>(pbuf, out);
}

// Round 23
// 214.891 us; speedup vs baseline: 1.4946x; 1.0240x over previous
//
#include <hip/hip_runtime.h>
#include <hip/hip_bf16.h>

#define TT 2048
#define DD 1024
#define FF 2048
#define NEXPI 10     // 2 shared + 8 routed expert instances
#define NRMAX 9216   // max compact rows: 4096 shared + 4096 routed + <=1024 pad
#define NTILEMAX 72  // NRMAX/128

typedef __attribute__((ext_vector_type(4))) int v4i;
typedef __attribute__((ext_vector_type(4))) float f32x4;

__device__ __forceinline__ double wave_sum_d(double v) {
#pragma unroll
  for (int o = 32; o > 0; o >>= 1) v += __shfl_down(v, o);
  return v;
}
__device__ __forceinline__ double wave_max_d(double v) {
#pragma unroll
  for (int o = 32; o > 0; o >>= 1) v = fmax(v, __shfl_down(v, o));
  return v;
}

// async global->LDS, 16B per lane; lds dest is wave-uniform base, lane l lands at +l*16
__device__ __forceinline__ void gll16(const void* g, void* l) {
  __builtin_amdgcn_global_load_lds(
      (const __attribute__((address_space(1))) void*)g,
      (__attribute__((address_space(3))) void*)l, 16, 0, 0);
}

// stage ROWS x 64B tile (i8, row stride K bytes in global) into linear LDS
template<int ROWS>
__device__ __forceinline__ void stage_rows(const signed char* src, int K,
                                           signed char* lds, int tid) {
  int w = tid >> 6, l = tid & 63;
  int sub = l >> 2, seg = (l & 3) * 16;
#pragma unroll
  for (int i = 0; i < ROWS / 64; ++i) {
    int rbase = w * (ROWS / 4) + i * 16;
    gll16(src + (size_t)(rbase + sub) * K + seg, lds + rbase * 64);
  }
}

// ------------- fused prologue: wabs (blocks 0..2559) | rmsnorm+quant (2560..4607)
//               | rowmax zero (4608..4643). All three independent. -------------
__global__ __launch_bounds__(256) void k_pro(
    const float* __restrict__ w1s, const float* __restrict__ w2s,
    const float* __restrict__ w1r, const float* __restrict__ w2r,
    double* __restrict__ part,
    const float* __restrict__ x, const float* __restrict__ rw,
    signed char* __restrict__ qh, __hip_bfloat16* __restrict__ hb,
    double* __restrict__ amax_clip, unsigned* __restrict__ rm) {
  __shared__ double red[12];
  int bid = blockIdx.x, tid = threadIdx.x;
  if (bid < 2560) {
    int m = bid >> 7, blk = bid & 127;
    const float* base;
    if (m < 2)       base = w1s + (size_t)m * (DD * FF);
    else if (m < 4)  base = w2s + (size_t)(m - 2) * (DD * FF);
    else if (m < 12) base = w1r + (size_t)(m - 4) * (DD * FF);
    else             base = w2r + (size_t)(m - 12) * (DD * FF);
    const f32x4* p = (const f32x4*)base + (size_t)blk * 4096;
    double s0 = 0.0, s1 = 0.0, s2 = 0.0, s3 = 0.0;
#pragma unroll
    for (int b = 0; b < 2; ++b) {
      f32x4 v[8];
#pragma unroll
      for (int i = 0; i < 8; ++i)
        v[i] = p[tid + (b * 8 + i) * 256];
#pragma unroll
      for (int i = 0; i < 8; i += 4) {
        s0 += (double)fabsf(v[i+0].x) + (double)fabsf(v[i+0].y) +
              (double)fabsf(v[i+0].z) + (double)fabsf(v[i+0].w);
        s1 += (double)fabsf(v[i+1].x) + (double)fabsf(v[i+1].y) +
              (double)fabsf(v[i+1].z) + (double)fabsf(v[i+1].w);
        s2 += (double)fabsf(v[i+2].x) + (double)fabsf(v[i+2].y) +
              (double)fabsf(v[i+2].z) + (double)fabsf(v[i+2].w);
        s3 += (double)fabsf(v[i+3].x) + (double)fabsf(v[i+3].y) +
              (double)fabsf(v[i+3].z) + (double)fabsf(v[i+3].w);
      }
    }
    double s = (s0 + s1) + (s2 + s3);
    s = wave_sum_d(s);
    int lane = tid & 63, wid = tid >> 6;
    if (lane == 0) red[wid] = s;
    __syncthreads();
    if (tid == 0) part[m * 128 + blk] = red[0] + red[1] + red[2] + red[3];
  } else if (bid < 4608) {
    int t = bid - 2560;
    int lane = tid & 63, wid = tid >> 6;
    float4 xv = ((const float4*)(x + (size_t)t * DD))[tid];
    double x0 = xv.x, x1 = xv.y, x2 = xv.z, x3 = xv.w;
    double ss = x0 * x0 + x1 * x1 + x2 * x2 + x3 * x3;
    ss = wave_sum_d(ss);
    if (lane == 0) red[wid] = ss;
    __syncthreads();
    if (tid == 0) {
      double s = red[0] + red[1] + red[2] + red[3];
      red[8] = 1.0 / sqrt(s * (1.0 / DD) + 1e-6);
    }
    __syncthreads();
    double r = red[8];
    float4 wv = ((const float4*)rw)[tid];
    double h0 = x0 * r * (double)wv.x, h1 = x1 * r * (double)wv.y;
    double h2 = x2 * r * (double)wv.z, h3 = x3 * r * (double)wv.w;
    __hip_bfloat16* hp = hb + (size_t)t * DD + tid * 4;
    hp[0] = __float2bfloat16((float)h0); hp[1] = __float2bfloat16((float)h1);
    hp[2] = __float2bfloat16((float)h2); hp[3] = __float2bfloat16((float)h3);
    double am = fmax(fmax(fabs(h0), fabs(h1)), fmax(fabs(h2), fabs(h3)));
    am = wave_max_d(am);
    if (lane == 0) red[4 + wid] = am;
    __syncthreads();
    if (tid == 0) {
      double a = fmax(fmax(red[4], red[5]), fmax(red[6], red[7]));
      red[9] = fmax(a, 1e-5);
    }
    __syncthreads();
    double clipv = red[9];
    if (tid == 0) amax_clip[t] = clipv;
    double s = 127.0 / clipv;
    int q0 = (int)fmin(127.0, fmax(-128.0, rint(h0 * s)));
    int q1 = (int)fmin(127.0, fmax(-128.0, rint(h1 * s)));
    int q2 = (int)fmin(127.0, fmax(-128.0, rint(h2 * s)));
    int q3 = (int)fmin(127.0, fmax(-128.0, rint(h3 * s)));
    unsigned pw = (unsigned)(q0 & 255) | ((unsigned)(q1 & 255) << 8) |
                  ((unsigned)(q2 & 255) << 16) | ((unsigned)(q3 & 255) << 24);
    *(unsigned*)(qh + (size_t)t * DD + tid * 4) = pw;
  } else {
    int i = (bid - 4608) * 256 + tid;
    if (i < NRMAX) rm[i] = 0u;
  }
}

__global__ __launch_bounds__(64) void k_wscale_final(
    const double* __restrict__ part, double* __restrict__ wscale) {
  int m = blockIdx.x;
  double v = part[m * 128 + threadIdx.x] + part[m * 128 + 64 + threadIdx.x];
  v = wave_sum_d(v);
  if (threadIdx.x == 0) wscale[m] = v * (1.0 / 2097152.0) + 1e-8;
}

// ------------- ternary quant helper (f64 bins) -------------
__device__ __forceinline__ int qtern(float v, double winv) {
  double q = rint((double)v * winv);
  return (int)fmin(1.0, fmax(-1.0, q));
}
__device__ __forceinline__ unsigned pack4(int a, int b, int c, int d) {
  return (unsigned)(a & 255) | ((unsigned)(b & 255) << 8) |
         ((unsigned)(c & 255) << 16) | ((unsigned)(d & 255) << 24);
}

// ------------- fused mid: wquant (blocks 0..10239) | router (10240..10751) ----------
__global__ __launch_bounds__(256) void k_mid(
    const float* __restrict__ w1s, const float* __restrict__ w2s,
    const float* __restrict__ w1r, const float* __restrict__ w2r,
    const double* __restrict__ wscale,
    signed char* __restrict__ q1T, signed char* __restrict__ q2T,
    const __hip_bfloat16* __restrict__ hb, const float* __restrict__ rw,
    float* __restrict__ gates, int2* __restrict__ i01) {
  int bid = blockIdx.x, tidx = threadIdx.x;
  if (bid < 10240) {
    __shared__ signed char tile[64 * 68];
    int m = bid >> 9, t = bid & 511;
    const float* src;
    signed char* dst;
    int ld, ldo, rt, ct;
    if (m < 2) {
      src = w1s + (size_t)m * DD * FF;
      dst = q1T + (size_t)m * FF * DD;
      ld = FF; ldo = DD; rt = t >> 5; ct = t & 31;
    } else if (m < 4) {
      src = w2s + (size_t)(m - 2) * FF * DD;
      dst = q2T + (size_t)(m - 2) * DD * FF;
      ld = DD; ldo = FF; rt = t >> 4; ct = t & 15;
    } else if (m < 12) {
      src = w1r + (size_t)(m - 4) * DD * FF;
      dst = q1T + (size_t)(m - 2) * FF * DD;
      ld = FF; ldo = DD; rt = t >> 5; ct = t & 31;
    } else {
      src = w2r + (size_t)(m - 12) * FF * DD;
      dst = q2T + (size_t)(m - 10) * DD * FF;
      ld = DD; ldo = FF; rt = t >> 4; ct = t & 15;
    }
    double winv = 1.0 / wscale[m];
    int row0 = rt * 64, col0 = ct * 64;
    int r = tidx >> 2, sc_ = (tidx & 3) * 16;
    const float* sp = src + (size_t)(row0 + r) * ld + col0 + sc_;
#pragma unroll
    for (int g = 0; g < 4; ++g) {
      float4 v = *(const float4*)(sp + g * 4);
      unsigned pk = pack4(qtern(v.x, winv), qtern(v.y, winv),
                          qtern(v.z, winv), qtern(v.w, winv));
      *(unsigned*)(tile + r * 68 + sc_ + g * 4) = pk;
    }
    __syncthreads();
    int c = tidx >> 2, sr = (tidx & 3) * 16;
    unsigned o[4];
#pragma unroll
    for (int g = 0; g < 4; ++g) {
      int j = sr + g * 4;
      o[g] = pack4(tile[(j + 0) * 68 + c], tile[(j + 1) * 68 + c],
                   tile[(j + 2) * 68 + c], tile[(j + 3) * 68 + c]);
    }
    int4 ov = make_int4((int)o[0], (int)o[1], (int)o[2], (int)o[3]);
    *(int4*)(dst + (size_t)(col0 + c) * ldo + row0 + sr) = ov;
  } else {
    // router: 4 tokens per block, one 64-lane wave each
    int t = (bid - 10240) * 4 + (tidx >> 6);
    int lane = tidx & 63;
    double acc[8];
#pragma unroll
    for (int e = 0; e < 8; ++e) acc[e] = 0.0;
    const __hip_bfloat16* hp = hb + (size_t)t * DD;
    for (int d = lane; d < DD; d += 64) {
      double hv = (double)__bfloat162float(hp[d]);
#pragma unroll
      for (int e = 0; e < 8; ++e) {
        double wv = (double)__bfloat162float(__float2bfloat16(rw[e * DD + d]));
        acc[e] += hv * wv;
      }
    }
#pragma unroll
    for (int e = 0; e < 8; ++e) acc[e] = wave_sum_d(acc[e]);
    if (lane == 0) {
      double lb[8];
#pragma unroll
      for (int e = 0; e < 8; ++e)
        lb[e] = (double)__bfloat162float(__float2bfloat16((float)acc[e]));
      double mx = lb[0];
#pragma unroll
      for (int e = 1; e < 8; ++e) mx = fmax(mx, lb[e]);
      double p[8];
#pragma unroll
      for (int e = 0; e < 8; ++e) p[e] = exp(lb[e] - mx);
      int i0 = 0;
      for (int e = 1; e < 8; ++e) if (p[e] > p[i0]) i0 = e;
      int i1 = (i0 == 0) ? 1 : 0;
      for (int e = 0; e < 8; ++e) if (e != i0 && p[e] > p[i1]) i1 = e;
      double den = p[i0] + p[i1];
      float o[8] = {0.f, 0.f, 0.f, 0.f, 0.f, 0.f, 0.f, 0.f};
      o[i0] = (float)(p[i0] / den);
      o[i1] = (float)(p[i1] / den);
#pragma unroll
      for (int e = 0; e < 8; ++e) gates[(size_t)t * 8 + e] = o[e];
      i01[t] = make_int2(i0, i1);
    }
  }
}

// ------------- fused lists+meta: single block, 512 threads ---------------------------
// phase 1: 8 waves do per-expert ballot compaction; phase 2: meta/gather tables
__global__ __launch_bounds__(512) void k_lm(
    const int2* __restrict__ i01, const double* __restrict__ amax_clip,
    const double* __restrict__ wscale,
    int* __restrict__ lists, unsigned char* __restrict__ slots,
    int* __restrict__ meta, int* __restrict__ rowexp, int* __restrict__ tokidx,
    int* __restrict__ wrow, float* __restrict__ srow1c) {
  __shared__ int scnt[8];
  __shared__ int segs[9];
  int tid = threadIdx.x;
  int e = tid >> 6, lane = tid & 63;
  // ---- phase 1: per-expert ordered token lists (wave-local ballot prefix) ----
  {
    int* le = lists + e * TT;
    unsigned char* se = slots + e * TT;
    int base = 0;
    for (int it = 0; it < TT / 64; ++it) {
      int t = it * 64 + lane;
      int2 r = i01[t];
      bool hit0 = (r.x == e), hit1 = (r.y == e);
      bool hit = hit0 || hit1;
      unsigned long long m = __ballot(hit);
      int pos = base + __popcll(m & ((1ull << lane) - 1ull));
      if (hit) { le[pos] = t; se[pos] = hit0 ? 0 : 1; }
      base += __popcll(m);
    }
    if (lane == 0) scnt[e] = base;
  }
  __syncthreads();   // orders this block's global writes (lists/slots) too
  // ---- phase 2: segment offsets + tables ----
  if (tid == 0) {
    int acc = 0;
    for (int q = 0; q < 8; ++q) {
      segs[q] = acc;
      acc += (scnt[q] + 127) & ~127;
    }
    segs[8] = acc;
    meta[0] = 32 + acc / 128;   // total row-tiles
    meta[1] = 4096 + acc;       // total compact rows
  }
  __syncthreads();
  int ntile = 32 + segs[8] / 128;
  for (int j = tid; j < NTILEMAX; j += 512) {
    int ei = -1;
    if (j < 16) ei = 0;
    else if (j < 32) ei = 1;
    else if (j < ntile) {
      int rr = (j - 32) * 128;
      for (int q = 0; q < 8; ++q)
        if (rr >= segs[q] && rr < segs[q + 1]) { ei = 2 + q; break; }
    }
    rowexp[j] = ei;
  }
  for (int r = tid; r < NRMAX; r += 512) {
    int t = 0; float s1 = 0.f; int w = -1;
    if (r < 4096) {
      int q = r >> 11; t = r & (TT - 1);
      double csc = wscale[q] * (1.0 / 127.0);
      s1 = (float)(amax_clip[t] * csc);
      w = q * TT + t;
    } else {
      int rr = r - 4096;
      if (rr < segs[8]) {
        int q = 0;
        for (int z = 0; z < 8; ++z)
          if (rr >= segs[z] && rr < segs[z + 1]) { q = z; break; }
        int k = rr - segs[q];
        if (k < scnt[q]) {
          t = lists[q * TT + k];
          int sl = slots[q * TT + k];
          double csc = wscale[4 + q] * (1.0 / 127.0);
          s1 = (float)(amax_clip[t] * csc);
          w = (2 + sl) * TT + t;
        }
      }
    }
    tokidx[r] = t; srow1c[r] = s1; wrow[r] = w;
  }
}

// ------------- GEMM1 (compact rows, gathered A): 128x64 tiles, BK=64 -----------------
// SINGLE launch over all row-tiles; 12.3KB LDS -> 13 blocks/CU capacity (all resident)
// fixed grid (32, NTILEMAX) = 2304 blocks; bijective XCD swizzle (chunks of 288)
__global__ __launch_bounds__(256) void k_g1(
    const signed char* __restrict__ qh, const signed char* __restrict__ q1T,
    const int* __restrict__ rowexp, const int* __restrict__ tokidx,
    const float* __restrict__ srow1c, const int* __restrict__ meta,
    __hip_bfloat16* __restrict__ abuf, unsigned* __restrict__ rowmaxc) {
  __shared__ __align__(16) signed char As[8192];   // 128 rows x 64 B
  __shared__ __align__(16) signed char Bs[4096];   // 64 rows x 64 B
  int lid = blockIdx.x + 32 * blockIdx.y;          // 0..2303
  int nid = (lid & 7) * 288 + (lid >> 3);          // bijective XCD chunks
  int j = nid >> 5;
  if (j >= meta[0]) return;
  int col0 = (nid & 31) * 64;
  int ei = rowexp[j];
  int tid = threadIdx.x, lane = tid & 63, wid = tid >> 6;
  int wr = wid >> 1, wc = wid & 1;
  int rowt0 = j * 128;
  int sub = lane >> 2, seg = (lane & 3) * 16;
  int sr0 = wid * 32 + sub, sr1 = sr0 + 16;
  const signed char* a0 = qh + (size_t)tokidx[rowt0 + sr0] * DD + seg;
  const signed char* a1 = qh + (size_t)tokidx[rowt0 + sr1] * DD + seg;
  const signed char* b_src = q1T + (size_t)ei * FF * DD + (size_t)col0 * DD;
  signed char* lda0 = As + (wid * 32) * 64;
  signed char* lda1 = As + (wid * 32 + 16) * 64;
  int kg = (lane >> 4) * 16, rsel = lane & 15;
  v4i zero = {0, 0, 0, 0};
  v4i acc[4][2];
#pragma unroll
  for (int i = 0; i < 4; ++i)
#pragma unroll
    for (int jj = 0; jj < 2; ++jj) acc[i][jj] = zero;
  for (int k0 = 0; k0 < DD; k0 += 64) {
    __syncthreads();
    gll16(a0 + k0, lda0);
    gll16(a1 + k0, lda1);
    stage_rows<64>(b_src + k0, DD, Bs, tid);
    __syncthreads();
    v4i af[4], bf[2];
#pragma unroll
    for (int mi = 0; mi < 4; ++mi)
      af[mi] = *(const v4i*)(As + (wr * 64 + mi * 16 + rsel) * 64 + kg);
#pragma unroll
    for (int ni = 0; ni < 2; ++ni)
      bf[ni] = *(const v4i*)(Bs + (wc * 32 + ni * 16 + rsel) * 64 + kg);
#pragma unroll
    for (int mi = 0; mi < 4; ++mi)
#pragma unroll
      for (int ni = 0; ni < 2; ++ni)
        acc[mi][ni] = __builtin_amdgcn_mfma_i32_16x16x64_i8(af[mi], bf[ni], acc[mi][ni], 0, 0, 0);
  }
#pragma unroll
  for (int mi = 0; mi < 4; ++mi) {
#pragma unroll
    for (int rg = 0; rg < 4; ++rg) {
      int rof = wr * 64 + mi * 16 + ((lane >> 4) << 2) + rg;
      int tr = rowt0 + rof;
      float sA = srow1c[tr];
      float mloc = 0.f;
#pragma unroll
      for (int ni = 0; ni < 2; ++ni) {
        int fc = col0 + wc * 32 + ni * 16 + (lane & 15);
        float a = (float)acc[mi][ni][rg] * sA;
        float v = a / (1.f + expf(-a));
        __hip_bfloat16 vb = __float2bfloat16(v);
        float vq = __bfloat162float(vb);
        abuf[(size_t)tr * FF + fc] = vb;
        mloc = fmaxf(mloc, fabsf(vq));
      }
#pragma unroll
      for (int o = 1; o < 16; o <<= 1) mloc = fmaxf(mloc, __shfl_xor(mloc, o));
      if ((lane & 15) == 0) atomicMax(rowmaxc + tr, __float_as_uint(mloc));
    }
  }
}

// ------------- fused: aquant over ALL compact rows (blocks 0..4095) | scg (4096..4131)
__global__ __launch_bounds__(256) void k_aqs(
    const __hip_bfloat16* __restrict__ abuf, const unsigned* __restrict__ rowmaxc,
    const int* __restrict__ meta, signed char* __restrict__ qa,
    const double* __restrict__ wscale, const float* __restrict__ gates,
    const int* __restrict__ tokidx, const int* __restrict__ wrow,
    const int* __restrict__ rowexp, float* __restrict__ sgc) {
  int bid = blockIdx.x, tid = threadIdx.x;
  if (bid < 4096) {
    int nrows = meta[1];
    if (nrows > NRMAX) nrows = NRMAX;
    int total4 = nrows * (FF / 4);
    int stride = 4096 * 256;
    for (int i = bid * 256 + tid; i < total4; i += stride) {
      int r = i >> 9;
      float clip = fmaxf(__uint_as_float(rowmaxc[r]), 1e-5f);
      float s = 127.f / clip;
      ushort4 raw = ((const ushort4*)abuf)[i];
      float vx = __bfloat162float(*(__hip_bfloat16*)&raw.x);
      float vy = __bfloat162float(*(__hip_bfloat16*)&raw.y);
      float vz = __bfloat162float(*(__hip_bfloat16*)&raw.z);
      float vw = __bfloat162float(*(__hip_bfloat16*)&raw.w);
      int q0 = (int)fminf(127.f, fmaxf(-128.f, rintf(vx * s)));
      int q1 = (int)fminf(127.f, fmaxf(-128.f, rintf(vy * s)));
      int q2 = (int)fminf(127.f, fmaxf(-128.f, rintf(vz * s)));
      int q3 = (int)fminf(127.f, fmaxf(-128.f, rintf(vw * s)));
      ((unsigned*)qa)[(size_t)r * (FF / 4) + (i & 511)] = pack4(q0, q1, q2, q3);
    }
  } else {
    int r = (bid - 4096) * 256 + tid;
    if (r >= NRMAX) return;
    int ei = rowexp[r >> 7];
    int w = wrow[r];
    if (ei < 0 || w < 0) { sgc[r] = 0.f; return; }
    float clip = fmaxf(__uint_as_float(rowmaxc[r]), 1e-5f);
    int t = tokidx[r];
    double csc = wscale[ei < 2 ? ei + 2 : ei + 10] * (1.0 / 127.0);
    float g = (ei < 2) ? 1.f : gates[(size_t)t * 8 + (ei - 2)];
    sgc[r] = (float)((double)clip * csc) * g;
  }
}

// ------------- GEMM2 (compact rows): 128x64 tiles, BK=128 sub-tiled -----------------
__global__ __launch_bounds__(256) void k_g2(
    const signed char* __restrict__ qa, const signed char* __restrict__ q2T,
    const int* __restrict__ rowexp, const float* __restrict__ sgc,
    const int* __restrict__ wrow, const int* __restrict__ meta,
    float* __restrict__ pbuf) {
  __shared__ __align__(16) signed char As[2 * 8192];   // 2 slices x 128 rows x 64B
  __shared__ __align__(16) signed char Bs[2 * 4096];   // 2 slices x 64 rows x 64B
  int lid = blockIdx.x + 16 * blockIdx.y;          // 0..1151
  int nid = (lid & 7) * 144 + (lid >> 3);
  int j = nid >> 4;
  if (j >= meta[0]) return;
  int col0 = (nid & 15) * 64;
  int ei = rowexp[j];
  int tid = threadIdx.x, lane = tid & 63, wid = tid >> 6;
  int wr = wid >> 1, wc = wid & 1;
  const signed char* ap = qa + (size_t)j * 128 * FF;
  const signed char* bp = q2T + (size_t)ei * DD * FF + (size_t)col0 * FF;
  int kg = (lane >> 4) * 16, rsel = lane & 15;
  v4i zero = {0, 0, 0, 0};
  v4i acc[4][2];
#pragma unroll
  for (int i = 0; i < 4; ++i)
#pragma unroll
    for (int jj = 0; jj < 2; ++jj) acc[i][jj] = zero;
  for (int k0 = 0; k0 < FF; k0 += 128) {
    __syncthreads();
#pragma unroll
    for (int c = 0; c < 2; ++c) {
      stage_rows<128>(ap + k0 + c * 64, FF, As + c * 8192, tid);
      stage_rows<64>(bp + k0 + c * 64, FF, Bs + c * 4096, tid);
    }
    __syncthreads();
#pragma unroll
    for (int kk = 0; kk < 2; ++kk) {
      v4i af[4], bf[2];
#pragma unroll
      for (int mi = 0; mi < 4; ++mi)
        af[mi] = *(const v4i*)(As + kk * 8192 + (wr * 64 + mi * 16 + rsel) * 64 + kg);
#pragma unroll
      for (int ni = 0; ni < 2; ++ni)
        bf[ni] = *(const v4i*)(Bs + kk * 4096 + (wc * 32 + ni * 16 + rsel) * 64 + kg);
#pragma unroll
      for (int mi = 0; mi < 4; ++mi)
#pragma unroll
        for (int ni = 0; ni < 2; ++ni)
          acc[mi][ni] = __builtin_amdgcn_mfma_i32_16x16x64_i8(af[mi], bf[ni], acc[mi][ni], 0, 0, 0);
    }
  }
#pragma unroll
  for (int mi = 0; mi < 4; ++mi) {
#pragma unroll
    for (int rg = 0; rg < 4; ++rg) {
      int tr = j * 128 + wr * 64 + mi * 16 + ((lane >> 4) << 2) + rg;
      int w = wrow[tr];
      float sc = sgc[tr];
      if (w >= 0) {
#pragma unroll
        for (int ni = 0; ni < 2; ++ni) {
          int dc = col0 + wc * 32 + ni * 16 + (lane & 15);
          pbuf[(size_t)w * DD + dc] = (float)acc[mi][ni][rg] * sc;
        }
      }
    }
  }
}

// ------------- combine: out = sum of 4 planes -------------
__global__ __launch_bounds__(256) void k_combine(
    const float* __restrict__ pbuf, float* __restrict__ out) {
  int i = blockIdx.x * 256 + threadIdx.x;  // float4 index
  float4 s = ((const float4*)pbuf)[i];
#pragma unroll
  for (int z = 1; z < 4; ++z) {
    float4 v = ((const float4*)(pbuf + (size_t)z * TT * DD))[i];
    s.x += v.x; s.y += v.y; s.z += v.z; s.w += v.w;
  }
  ((float4*)out)[i] = s;
}

extern "C" void kernel_launch(void* const* d_in, const int* in_sizes, int n_in,
                              void* d_out, int out_size, void* d_ws, size_t ws_size,
                              hipStream_t stream) {
  const float* x    = (const float*)d_in[0];
  const float* rmsw = (const float*)d_in[1];
  const float* w1s  = (const float*)d_in[2];
  const float* w2s  = (const float*)d_in[3];
  const float* w1r  = (const float*)d_in[4];
  const float* w2r  = (const float*)d_in[5];
  const float* rw   = (const float*)d_in[6];
  float* out = (float*)d_out;

  char* ws = (char*)d_ws;
  // footprint ends at 0x7E80000 ~= 132.6MB (proven safe)
  double* amax_clip      = (double*)(ws + 0x0000000);   // 16KB
  double* part           = (double*)(ws + 0x0004000);   // 20KB (20*128 f64)
  double* wscale         = (double*)(ws + 0x0018000);   // 160B
  float* gates           = (float*)(ws + 0x0019000);    // 64KB
  int2* i01              = (int2*)(ws + 0x0029000);     // 16KB
  int* lists             = (int*)(ws + 0x002D000);      // 64KB
  unsigned char* slots   = (unsigned char*)(ws + 0x003D000); // 16KB
  int* meta              = (int*)(ws + 0x0041100);      // 64B
  int* tokidx            = (int*)(ws + 0x0042000);      // 36KB
  int* wrow              = (int*)(ws + 0x004B000);      // 36KB
  float* srow1c          = (float*)(ws + 0x0054000);    // 36KB
  float* sgc             = (float*)(ws + 0x005D000);    // 36KB
  int* rowexp            = (int*)(ws + 0x0066000);      // 288B
  unsigned* rowmaxc      = (unsigned*)(ws + 0x0067000); // 36KB
  signed char* qh        = (signed char*)(ws + 0x0080000);    // 2MB
  __hip_bfloat16* hb     = (__hip_bfloat16*)(ws + 0x0280000); // 4MB
  signed char* q1T       = (signed char*)(ws + 0x0680000);    // 20MB
  signed char* q2T       = (signed char*)(ws + 0x1A80000);    // 20MB
  signed char* qa        = (signed char*)(ws + 0x2E80000);    // <=18.9MB (40MB region)
  float* pbuf            = (float*)(ws + 0x5680000);          // 4 planes = 32MB (40MB region)
  __hip_bfloat16* abuf   = (__hip_bfloat16*)pbuf;  // alias: full bf16 abuf (36MB) used before g2 writes pbuf

  // fused prologue: wabs (2560) | rms_quant (2048) | rowmax zero (36)
  k_pro<<<4644, 256, 0, stream>>>(w1s, w2s, w1r, w2r, part,
                                  x, rmsw, qh, hb, amax_clip, rowmaxc);
  k_wscale_final<<<20, 64, 0, stream>>>(part, wscale);
  // fused mid: wquant (10240) | router (512 blocks x 4 tokens)
  k_mid<<<10752, 256, 0, stream>>>(w1s, w2s, w1r, w2r, wscale, q1T, q2T,
                                   hb, rw, gates, i01);
  // fused lists + meta (single block)
  k_lm<<<1, 512, 0, stream>>>(i01, amax_clip, wscale, lists, slots,
                              meta, rowexp, tokidx, wrow, srow1c);

  // single gemm1 over all compact rows (BK=64, fully resident)
  dim3 g1(32, NTILEMAX);
  k_g1<<<g1, 256, 0, stream>>>(qh, q1T, rowexp, tokidx, srow1c, meta,
                               abuf, rowmaxc);
  // fused: aquant all rows (4096) | scg (36)
  k_aqs<<<4096 + 36, 256, 0, stream>>>(abuf, rowmaxc, meta, qa,
                                       wscale, gates, tokidx, wrow, rowexp, sgc);
  dim3 g2(16, NTILEMAX);
  k_g2<<<g2, 256, 0, stream>>>(qa, q2T, rowexp, sgc, wrow, meta, pbuf);
  k_combine<<<TT * DD / 4 / 256, 256, 0, stream>>>(pbuf, out);
}

// Round 24
// 211.468 us; speedup vs baseline: 1.5188x; 1.0162x over previous
//
#include <hip/hip_runtime.h>
#include <hip/hip_bf16.h>

#define TT 2048
#define DD 1024
#define FF 2048
#define NEXPI 10     // 2 shared + 8 routed expert instances
#define NRMAX 9216   // max compact rows: 4096 shared + 4096 routed + <=1024 pad
#define NTILEMAX 72  // NRMAX/128

typedef __attribute__((ext_vector_type(4))) int v4i;
typedef __attribute__((ext_vector_type(4))) float f32x4;

__device__ __forceinline__ double wave_sum_d(double v) {
#pragma unroll
  for (int o = 32; o > 0; o >>= 1) v += __shfl_down(v, o);
  return v;
}
__device__ __forceinline__ double wave_max_d(double v) {
#pragma unroll
  for (int o = 32; o > 0; o >>= 1) v = fmax(v, __shfl_down(v, o));
  return v;
}

// async global->LDS, 16B per lane; lds dest is wave-uniform base, lane l lands at +l*16
__device__ __forceinline__ void gll16(const void* g, void* l) {
  __builtin_amdgcn_global_load_lds(
      (const __attribute__((address_space(1))) void*)g,
      (__attribute__((address_space(3))) void*)l, 16, 0, 0);
}

// stage ROWS x 64B tile (i8, row stride K bytes in global) into linear LDS
template<int ROWS>
__device__ __forceinline__ void stage_rows(const signed char* src, int K,
                                           signed char* lds, int tid) {
  int w = tid >> 6, l = tid & 63;
  int sub = l >> 2, seg = (l & 3) * 16;
#pragma unroll
  for (int i = 0; i < ROWS / 64; ++i) {
    int rbase = w * (ROWS / 4) + i * 16;
    gll16(src + (size_t)(rbase + sub) * K + seg, lds + rbase * 64);
  }
}

// ------------- fused prologue: wabs (blocks 0..2559) | rmsnorm+quant (2560..4607)
//               | rowmax zero (4608..4643). All three independent. -------------
__global__ __launch_bounds__(256) void k_pro(
    const float* __restrict__ w1s, const float* __restrict__ w2s,
    const float* __restrict__ w1r, const float* __restrict__ w2r,
    double* __restrict__ part,
    const float* __restrict__ x, const float* __restrict__ rw,
    signed char* __restrict__ qh, __hip_bfloat16* __restrict__ hb,
    double* __restrict__ amax_clip, unsigned* __restrict__ rm) {
  __shared__ double red[12];
  int bid = blockIdx.x, tid = threadIdx.x;
  if (bid < 2560) {
    int m = bid >> 7, blk = bid & 127;
    const float* base;
    if (m < 2)       base = w1s + (size_t)m * (DD * FF);
    else if (m < 4)  base = w2s + (size_t)(m - 2) * (DD * FF);
    else if (m < 12) base = w1r + (size_t)(m - 4) * (DD * FF);
    else             base = w2r + (size_t)(m - 12) * (DD * FF);
    const f32x4* p = (const f32x4*)base + (size_t)blk * 4096;
    double s0 = 0.0, s1 = 0.0, s2 = 0.0, s3 = 0.0;
#pragma unroll
    for (int b = 0; b < 2; ++b) {
      f32x4 v[8];
#pragma unroll
      for (int i = 0; i < 8; ++i)
        v[i] = p[tid + (b * 8 + i) * 256];
#pragma unroll
      for (int i = 0; i < 8; i += 4) {
        s0 += (double)fabsf(v[i+0].x) + (double)fabsf(v[i+0].y) +
              (double)fabsf(v[i+0].z) + (double)fabsf(v[i+0].w);
        s1 += (double)fabsf(v[i+1].x) + (double)fabsf(v[i+1].y) +
              (double)fabsf(v[i+1].z) + (double)fabsf(v[i+1].w);
        s2 += (double)fabsf(v[i+2].x) + (double)fabsf(v[i+2].y) +
              (double)fabsf(v[i+2].z) + (double)fabsf(v[i+2].w);
        s3 += (double)fabsf(v[i+3].x) + (double)fabsf(v[i+3].y) +
              (double)fabsf(v[i+3].z) + (double)fabsf(v[i+3].w);
      }
    }
    double s = (s0 + s1) + (s2 + s3);
    s = wave_sum_d(s);
    int lane = tid & 63, wid = tid >> 6;
    if (lane == 0) red[wid] = s;
    __syncthreads();
    if (tid == 0) part[m * 128 + blk] = red[0] + red[1] + red[2] + red[3];
  } else if (bid < 4608) {
    int t = bid - 2560;
    int lane = tid & 63, wid = tid >> 6;
    float4 xv = ((const float4*)(x + (size_t)t * DD))[tid];
    double x0 = xv.x, x1 = xv.y, x2 = xv.z, x3 = xv.w;
    double ss = x0 * x0 + x1 * x1 + x2 * x2 + x3 * x3;
    ss = wave_sum_d(ss);
    if (lane == 0) red[wid] = ss;
    __syncthreads();
    if (tid == 0) {
      double s = red[0] + red[1] + red[2] + red[3];
      red[8] = 1.0 / sqrt(s * (1.0 / DD) + 1e-6);
    }
    __syncthreads();
    double r = red[8];
    float4 wv = ((const float4*)rw)[tid];
    double h0 = x0 * r * (double)wv.x, h1 = x1 * r * (double)wv.y;
    double h2 = x2 * r * (double)wv.z, h3 = x3 * r * (double)wv.w;
    __hip_bfloat16* hp = hb + (size_t)t * DD + tid * 4;
    hp[0] = __float2bfloat16((float)h0); hp[1] = __float2bfloat16((float)h1);
    hp[2] = __float2bfloat16((float)h2); hp[3] = __float2bfloat16((float)h3);
    double am = fmax(fmax(fabs(h0), fabs(h1)), fmax(fabs(h2), fabs(h3)));
    am = wave_max_d(am);
    if (lane == 0) red[4 + wid] = am;
    __syncthreads();
    if (tid == 0) {
      double a = fmax(fmax(red[4], red[5]), fmax(red[6], red[7]));
      red[9] = fmax(a, 1e-5);
    }
    __syncthreads();
    double clipv = red[9];
    if (tid == 0) amax_clip[t] = clipv;
    double s = 127.0 / clipv;
    int q0 = (int)fmin(127.0, fmax(-128.0, rint(h0 * s)));
    int q1 = (int)fmin(127.0, fmax(-128.0, rint(h1 * s)));
    int q2 = (int)fmin(127.0, fmax(-128.0, rint(h2 * s)));
    int q3 = (int)fmin(127.0, fmax(-128.0, rint(h3 * s)));
    unsigned pw = (unsigned)(q0 & 255) | ((unsigned)(q1 & 255) << 8) |
                  ((unsigned)(q2 & 255) << 16) | ((unsigned)(q3 & 255) << 24);
    *(unsigned*)(qh + (size_t)t * DD + tid * 4) = pw;
  } else {
    int i = (bid - 4608) * 256 + tid;
    if (i < NRMAX) rm[i] = 0u;
  }
}

__global__ __launch_bounds__(64) void k_wscale_final(
    const double* __restrict__ part, double* __restrict__ wscale) {
  int m = blockIdx.x;
  double v = part[m * 128 + threadIdx.x] + part[m * 128 + 64 + threadIdx.x];
  v = wave_sum_d(v);
  if (threadIdx.x == 0) wscale[m] = v * (1.0 / 2097152.0) + 1e-8;
}

// ------------- ternary quant helper (f64 bins) -------------
__device__ __forceinline__ int qtern(float v, double winv) {
  double q = rint((double)v * winv);
  return (int)fmin(1.0, fmax(-1.0, q));
}
__device__ __forceinline__ unsigned pack4(int a, int b, int c, int d) {
  return (unsigned)(a & 255) | ((unsigned)(b & 255) << 8) |
         ((unsigned)(c & 255) << 16) | ((unsigned)(d & 255) << 24);
}

// ------------- fused mid: wquant (blocks 0..10239) | router (10240..10751) ----------
__global__ __launch_bounds__(256) void k_mid(
    const float* __restrict__ w1s, const float* __restrict__ w2s,
    const float* __restrict__ w1r, const float* __restrict__ w2r,
    const double* __restrict__ wscale,
    signed char* __restrict__ q1T, signed char* __restrict__ q2T,
    const __hip_bfloat16* __restrict__ hb, const float* __restrict__ rw,
    float* __restrict__ gates, int2* __restrict__ i01) {
  int bid = blockIdx.x, tidx = threadIdx.x;
  if (bid < 10240) {
    __shared__ signed char tile[64 * 68];
    int m = bid >> 9, t = bid & 511;
    const float* src;
    signed char* dst;
    int ld, ldo, rt, ct;
    if (m < 2) {
      src = w1s + (size_t)m * DD * FF;
      dst = q1T + (size_t)m * FF * DD;
      ld = FF; ldo = DD; rt = t >> 5; ct = t & 31;
    } else if (m < 4) {
      src = w2s + (size_t)(m - 2) * FF * DD;
      dst = q2T + (size_t)(m - 2) * DD * FF;
      ld = DD; ldo = FF; rt = t >> 4; ct = t & 15;
    } else if (m < 12) {
      src = w1r + (size_t)(m - 4) * DD * FF;
      dst = q1T + (size_t)(m - 2) * FF * DD;
      ld = FF; ldo = DD; rt = t >> 5; ct = t & 31;
    } else {
      src = w2r + (size_t)(m - 12) * FF * DD;
      dst = q2T + (size_t)(m - 10) * DD * FF;
      ld = DD; ldo = FF; rt = t >> 4; ct = t & 15;
    }
    double winv = 1.0 / wscale[m];
    int row0 = rt * 64, col0 = ct * 64;
    int r = tidx >> 2, sc_ = (tidx & 3) * 16;
    const float* sp = src + (size_t)(row0 + r) * ld + col0 + sc_;
#pragma unroll
    for (int g = 0; g < 4; ++g) {
      float4 v = *(const float4*)(sp + g * 4);
      unsigned pk = pack4(qtern(v.x, winv), qtern(v.y, winv),
                          qtern(v.z, winv), qtern(v.w, winv));
      *(unsigned*)(tile + r * 68 + sc_ + g * 4) = pk;
    }
    __syncthreads();
    int c = tidx >> 2, sr = (tidx & 3) * 16;
    unsigned o[4];
#pragma unroll
    for (int g = 0; g < 4; ++g) {
      int j = sr + g * 4;
      o[g] = pack4(tile[(j + 0) * 68 + c], tile[(j + 1) * 68 + c],
                   tile[(j + 2) * 68 + c], tile[(j + 3) * 68 + c]);
    }
    int4 ov = make_int4((int)o[0], (int)o[1], (int)o[2], (int)o[3]);
    *(int4*)(dst + (size_t)(col0 + c) * ldo + row0 + sr) = ov;
  } else {
    // router: 4 tokens per block, one 64-lane wave each
    int t = (bid - 10240) * 4 + (tidx >> 6);
    int lane = tidx & 63;
    double acc[8];
#pragma unroll
    for (int e = 0; e < 8; ++e) acc[e] = 0.0;
    const __hip_bfloat16* hp = hb + (size_t)t * DD;
    for (int d = lane; d < DD; d += 64) {
      double hv = (double)__bfloat162float(hp[d]);
#pragma unroll
      for (int e = 0; e < 8; ++e) {
        double wv = (double)__bfloat162float(__float2bfloat16(rw[e * DD + d]));
        acc[e] += hv * wv;
      }
    }
#pragma unroll
    for (int e = 0; e < 8; ++e) acc[e] = wave_sum_d(acc[e]);
    if (lane == 0) {
      double lb[8];
#pragma unroll
      for (int e = 0; e < 8; ++e)
        lb[e] = (double)__bfloat162float(__float2bfloat16((float)acc[e]));
      double mx = lb[0];
#pragma unroll
      for (int e = 1; e < 8; ++e) mx = fmax(mx, lb[e]);
      double p[8];
#pragma unroll
      for (int e = 0; e < 8; ++e) p[e] = exp(lb[e] - mx);
      int i0 = 0;
      for (int e = 1; e < 8; ++e) if (p[e] > p[i0]) i0 = e;
      int i1 = (i0 == 0) ? 1 : 0;
      for (int e = 0; e < 8; ++e) if (e != i0 && p[e] > p[i1]) i1 = e;
      double den = p[i0] + p[i1];
      float o[8] = {0.f, 0.f, 0.f, 0.f, 0.f, 0.f, 0.f, 0.f};
      o[i0] = (float)(p[i0] / den);
      o[i1] = (float)(p[i1] / den);
#pragma unroll
      for (int e = 0; e < 8; ++e) gates[(size_t)t * 8 + e] = o[e];
      i01[t] = make_int2(i0, i1);
    }
  }
}

// ------------- fused lists+meta: single block, 512 threads ---------------------------
__global__ __launch_bounds__(512) void k_lm(
    const int2* __restrict__ i01, const double* __restrict__ amax_clip,
    const double* __restrict__ wscale,
    int* __restrict__ lists, unsigned char* __restrict__ slots,
    int* __restrict__ meta, int* __restrict__ rowexp, int* __restrict__ tokidx,
    int* __restrict__ wrow, float* __restrict__ srow1c) {
  __shared__ int scnt[8];
  __shared__ int segs[9];
  int tid = threadIdx.x;
  int e = tid >> 6, lane = tid & 63;
  {
    int* le = lists + e * TT;
    unsigned char* se = slots + e * TT;
    int base = 0;
    for (int it = 0; it < TT / 64; ++it) {
      int t = it * 64 + lane;
      int2 r = i01[t];
      bool hit0 = (r.x == e), hit1 = (r.y == e);
      bool hit = hit0 || hit1;
      unsigned long long m = __ballot(hit);
      int pos = base + __popcll(m & ((1ull << lane) - 1ull));
      if (hit) { le[pos] = t; se[pos] = hit0 ? 0 : 1; }
      base += __popcll(m);
    }
    if (lane == 0) scnt[e] = base;
  }
  __syncthreads();
  if (tid == 0) {
    int acc = 0;
    for (int q = 0; q < 8; ++q) {
      segs[q] = acc;
      acc += (scnt[q] + 127) & ~127;
    }
    segs[8] = acc;
    meta[0] = 32 + acc / 128;   // total row-tiles
    meta[1] = 4096 + acc;       // total compact rows
  }
  __syncthreads();
  int ntile = 32 + segs[8] / 128;
  for (int j = tid; j < NTILEMAX; j += 512) {
    int ei = -1;
    if (j < 16) ei = 0;
    else if (j < 32) ei = 1;
    else if (j < ntile) {
      int rr = (j - 32) * 128;
      for (int q = 0; q < 8; ++q)
        if (rr >= segs[q] && rr < segs[q + 1]) { ei = 2 + q; break; }
    }
    rowexp[j] = ei;
  }
  for (int r = tid; r < NRMAX; r += 512) {
    int t = 0; float s1 = 0.f; int w = -1;
    if (r < 4096) {
      int q = r >> 11; t = r & (TT - 1);
      double csc = wscale[q] * (1.0 / 127.0);
      s1 = (float)(amax_clip[t] * csc);
      w = q * TT + t;
    } else {
      int rr = r - 4096;
      if (rr < segs[8]) {
        int q = 0;
        for (int z = 0; z < 8; ++z)
          if (rr >= segs[z] && rr < segs[z + 1]) { q = z; break; }
        int k = rr - segs[q];
        if (k < scnt[q]) {
          t = lists[q * TT + k];
          int sl = slots[q * TT + k];
          double csc = wscale[4 + q] * (1.0 / 127.0);
          s1 = (float)(amax_clip[t] * csc);
          w = (2 + sl) * TT + t;
        }
      }
    }
    tokidx[r] = t; srow1c[r] = s1; wrow[r] = w;
  }
}

// ------------- GEMM1 (compact rows, gathered A): 128x64 tiles, BK=128 sub-tiled ------
// SINGLE launch over all row-tiles; conflict-free [slice][rows][64B] LDS layout
// fixed grid (32, NTILEMAX) = 2304 blocks; bijective XCD swizzle (chunks of 288)
__global__ __launch_bounds__(256) void k_g1(
    const signed char* __restrict__ qh, const signed char* __restrict__ q1T,
    const int* __restrict__ rowexp, const int* __restrict__ tokidx,
    const float* __restrict__ srow1c, const int* __restrict__ meta,
    __hip_bfloat16* __restrict__ abuf, unsigned* __restrict__ rowmaxc) {
  __shared__ __align__(16) signed char As[2 * 8192];   // 2 slices x 128 rows x 64B
  __shared__ __align__(16) signed char Bs[2 * 4096];   // 2 slices x 64 rows x 64B
  int lid = blockIdx.x + 32 * blockIdx.y;          // 0..2303
  int nid = (lid & 7) * 288 + (lid >> 3);          // bijective XCD chunks
  int j = nid >> 5;
  if (j >= meta[0]) return;
  int col0 = (nid & 31) * 64;
  int ei = rowexp[j];
  int tid = threadIdx.x, lane = tid & 63, wid = tid >> 6;
  int wr = wid >> 1, wc = wid & 1;
  int rowt0 = j * 128;
  int sub = lane >> 2, seg = (lane & 3) * 16;
  int sr0 = wid * 32 + sub, sr1 = sr0 + 16;
  const signed char* a0 = qh + (size_t)tokidx[rowt0 + sr0] * DD + seg;
  const signed char* a1 = qh + (size_t)tokidx[rowt0 + sr1] * DD + seg;
  const signed char* b_src = q1T + (size_t)ei * FF * DD + (size_t)col0 * DD;
  signed char* lda0 = As + (wid * 32) * 64;
  signed char* lda1 = As + (wid * 32 + 16) * 64;
  int kg = (lane >> 4) * 16, rsel = lane & 15;
  v4i zero = {0, 0, 0, 0};
  v4i acc[4][2];
#pragma unroll
  for (int i = 0; i < 4; ++i)
#pragma unroll
    for (int jj = 0; jj < 2; ++jj) acc[i][jj] = zero;
  for (int k0 = 0; k0 < DD; k0 += 128) {
    __syncthreads();
#pragma unroll
    for (int c = 0; c < 2; ++c) {
      gll16(a0 + k0 + c * 64, lda0 + c * 8192);
      gll16(a1 + k0 + c * 64, lda1 + c * 8192);
      stage_rows<64>(b_src + k0 + c * 64, DD, Bs + c * 4096, tid);
    }
    __syncthreads();
#pragma unroll
    for (int kk = 0; kk < 2; ++kk) {
      v4i af[4], bf[2];
#pragma unroll
      for (int mi = 0; mi < 4; ++mi)
        af[mi] = *(const v4i*)(As + kk * 8192 + (wr * 64 + mi * 16 + rsel) * 64 + kg);
#pragma unroll
      for (int ni = 0; ni < 2; ++ni)
        bf[ni] = *(const v4i*)(Bs + kk * 4096 + (wc * 32 + ni * 16 + rsel) * 64 + kg);
#pragma unroll
      for (int mi = 0; mi < 4; ++mi)
#pragma unroll
        for (int ni = 0; ni < 2; ++ni)
          acc[mi][ni] = __builtin_amdgcn_mfma_i32_16x16x64_i8(af[mi], bf[ni], acc[mi][ni], 0, 0, 0);
    }
  }
#pragma unroll
  for (int mi = 0; mi < 4; ++mi) {
#pragma unroll
    for (int rg = 0; rg < 4; ++rg) {
      int rof = wr * 64 + mi * 16 + ((lane >> 4) << 2) + rg;
      int tr = rowt0 + rof;
      float sA = srow1c[tr];
      float mloc = 0.f;
#pragma unroll
      for (int ni = 0; ni < 2; ++ni) {
        int fc = col0 + wc * 32 + ni * 16 + (lane & 15);
        float a = (float)acc[mi][ni][rg] * sA;
        float v = a / (1.f + expf(-a));
        __hip_bfloat16 vb = __float2bfloat16(v);
        float vq = __bfloat162float(vb);
        abuf[(size_t)tr * FF + fc] = vb;
        mloc = fmaxf(mloc, fabsf(vq));
      }
#pragma unroll
      for (int o = 1; o < 16; o <<= 1) mloc = fmaxf(mloc, __shfl_xor(mloc, o));
      if ((lane & 15) == 0) atomicMax(rowmaxc + tr, __float_as_uint(mloc));
    }
  }
}

// ------------- fused: aquant over ALL compact rows (blocks 0..4095) | scg (4096..4131)
__global__ __launch_bounds__(256) void k_aqs(
    const __hip_bfloat16* __restrict__ abuf, const unsigned* __restrict__ rowmaxc,
    const int* __restrict__ meta, signed char* __restrict__ qa,
    const double* __restrict__ wscale, const float* __restrict__ gates,
    const int* __restrict__ tokidx, const int* __restrict__ wrow,
    const int* __restrict__ rowexp, float* __restrict__ sgc) {
  int bid = blockIdx.x, tid = threadIdx.x;
  if (bid < 4096) {
    int nrows = meta[1];
    if (nrows > NRMAX) nrows = NRMAX;
    int total4 = nrows * (FF / 4);
    int stride = 4096 * 256;
    for (int i = bid * 256 + tid; i < total4; i += stride) {
      int r = i >> 9;
      float clip = fmaxf(__uint_as_float(rowmaxc[r]), 1e-5f);
      float s = 127.f / clip;
      ushort4 raw = ((const ushort4*)abuf)[i];
      float vx = __bfloat162float(*(__hip_bfloat16*)&raw.x);
      float vy = __bfloat162float(*(__hip_bfloat16*)&raw.y);
      float vz = __bfloat162float(*(__hip_bfloat16*)&raw.z);
      float vw = __bfloat162float(*(__hip_bfloat16*)&raw.w);
      int q0 = (int)fminf(127.f, fmaxf(-128.f, rintf(vx * s)));
      int q1 = (int)fminf(127.f, fmaxf(-128.f, rintf(vy * s)));
      int q2 = (int)fminf(127.f, fmaxf(-128.f, rintf(vz * s)));
      int q3 = (int)fminf(127.f, fmaxf(-128.f, rintf(vw * s)));
      ((unsigned*)qa)[(size_t)r * (FF / 4) + (i & 511)] = pack4(q0, q1, q2, q3);
    }
  } else {
    int r = (bid - 4096) * 256 + tid;
    if (r >= NRMAX) return;
    int ei = rowexp[r >> 7];
    int w = wrow[r];
    if (ei < 0 || w < 0) { sgc[r] = 0.f; return; }
    float clip = fmaxf(__uint_as_float(rowmaxc[r]), 1e-5f);
    int t = tokidx[r];
    double csc = wscale[ei < 2 ? ei + 2 : ei + 10] * (1.0 / 127.0);
    float g = (ei < 2) ? 1.f : gates[(size_t)t * 8 + (ei - 2)];
    sgc[r] = (float)((double)clip * csc) * g;
  }
}

// ------------- GEMM2 (compact rows): 128x64 tiles, BK=128 sub-tiled -----------------
__global__ __launch_bounds__(256) void k_g2(
    const signed char* __restrict__ qa, const signed char* __restrict__ q2T,
    const int* __restrict__ rowexp, const float* __restrict__ sgc,
    const int* __restrict__ wrow, const int* __restrict__ meta,
    float* __restrict__ pbuf) {
  __shared__ __align__(16) signed char As[2 * 8192];   // 2 slices x 128 rows x 64B
  __shared__ __align__(16) signed char Bs[2 * 4096];   // 2 slices x 64 rows x 64B
  int lid = blockIdx.x + 16 * blockIdx.y;          // 0..1151
  int nid = (lid & 7) * 144 + (lid >> 3);
  int j = nid >> 4;
  if (j >= meta[0]) return;
  int col0 = (nid & 15) * 64;
  int ei = rowexp[j];
  int tid = threadIdx.x, lane = tid & 63, wid = tid >> 6;
  int wr = wid >> 1, wc = wid & 1;
  const signed char* ap = qa + (size_t)j * 128 * FF;
  const signed char* bp = q2T + (size_t)ei * DD * FF + (size_t)col0 * FF;
  int kg = (lane >> 4) * 16, rsel = lane & 15;
  v4i zero = {0, 0, 0, 0};
  v4i acc[4][2];
#pragma unroll
  for (int i = 0; i < 4; ++i)
#pragma unroll
    for (int jj = 0; jj < 2; ++jj) acc[i][jj] = zero;
  for (int k0 = 0; k0 < FF; k0 += 128) {
    __syncthreads();
#pragma unroll
    for (int c = 0; c < 2; ++c) {
      stage_rows<128>(ap + k0 + c * 64, FF, As + c * 8192, tid);
      stage_rows<64>(bp + k0 + c * 64, FF, Bs + c * 4096, tid);
    }
    __syncthreads();
#pragma unroll
    for (int kk = 0; kk < 2; ++kk) {
      v4i af[4], bf[2];
#pragma unroll
      for (int mi = 0; mi < 4; ++mi)
        af[mi] = *(const v4i*)(As + kk * 8192 + (wr * 64 + mi * 16 + rsel) * 64 + kg);
#pragma unroll
      for (int ni = 0; ni < 2; ++ni)
        bf[ni] = *(const v4i*)(Bs + kk * 4096 + (wc * 32 + ni * 16 + rsel) * 64 + kg);
#pragma unroll
      for (int mi = 0; mi < 4; ++mi)
#pragma unroll
        for (int ni = 0; ni < 2; ++ni)
          acc[mi][ni] = __builtin_amdgcn_mfma_i32_16x16x64_i8(af[mi], bf[ni], acc[mi][ni], 0, 0, 0);
    }
  }
#pragma unroll
  for (int mi = 0; mi < 4; ++mi) {
#pragma unroll
    for (int rg = 0; rg < 4; ++rg) {
      int tr = j * 128 + wr * 64 + mi * 16 + ((lane >> 4) << 2) + rg;
      int w = wrow[tr];
      float sc = sgc[tr];
      if (w >= 0) {
#pragma unroll
        for (int ni = 0; ni < 2; ++ni) {
          int dc = col0 + wc * 32 + ni * 16 + (lane & 15);
          pbuf[(size_t)w * DD + dc] = (float)acc[mi][ni][rg] * sc;
        }
      }
    }
  }
}

// ------------- combine: out = sum of 4 planes -------------
__global__ __launch_bounds__(256) void k_combine(
    const float* __restrict__ pbuf, float* __restrict__ out) {
  int i = blockIdx.x * 256 + threadIdx.x;  // float4 index
  float4 s = ((const float4*)pbuf)[i];
#pragma unroll
  for (int z = 1; z < 4; ++z) {
    float4 v = ((const float4*)(pbuf + (size_t)z * TT * DD))[i];
    s.x += v.x; s.y += v.y; s.z += v.z; s.w += v.w;
  }
  ((float4*)out)[i] = s;
}

extern "C" void kernel_launch(void* const* d_in, const int* in_sizes, int n_in,
                              void* d_out, int out_size, void* d_ws, size_t ws_size,
                              hipStream_t stream) {
  const float* x    = (const float*)d_in[0];
  const float* rmsw = (const float*)d_in[1];
  const float* w1s  = (const float*)d_in[2];
  const float* w2s  = (const float*)d_in[3];
  const float* w1r  = (const float*)d_in[4];
  const float* w2r  = (const float*)d_in[5];
  const float* rw   = (const float*)d_in[6];
  float* out = (float*)d_out;

  char* ws = (char*)d_ws;
  // footprint ends at 0x7E80000 ~= 132.6MB (proven safe)
  double* amax_clip      = (double*)(ws + 0x0000000);   // 16KB
  double* part           = (double*)(ws + 0x0004000);   // 20KB (20*128 f64)
  double* wscale         = (double*)(ws + 0x0018000);   // 160B
  float* gates           = (float*)(ws + 0x0019000);    // 64KB
  int2* i01              = (int2*)(ws + 0x0029000);     // 16KB
  int* lists             = (int*)(ws + 0x002D000);      // 64KB
  unsigned char* slots   = (unsigned char*)(ws + 0x003D000); // 16KB
  int* meta              = (int*)(ws + 0x0041100);      // 64B
  int* tokidx            = (int*)(ws + 0x0042000);      // 36KB
  int* wrow              = (int*)(ws + 0x004B000);      // 36KB
  float* srow1c          = (float*)(ws + 0x0054000);    // 36KB
  float* sgc             = (float*)(ws + 0x005D000);    // 36KB
  int* rowexp            = (int*)(ws + 0x0066000);      // 288B
  unsigned* rowmaxc      = (unsigned*)(ws + 0x0067000); // 36KB
  signed char* qh        = (signed char*)(ws + 0x0080000);    // 2MB
  __hip_bfloat16* hb     = (__hip_bfloat16*)(ws + 0x0280000); // 4MB
  signed char* q1T       = (signed char*)(ws + 0x0680000);    // 20MB
  signed char* q2T       = (signed char*)(ws + 0x1A80000);    // 20MB
  signed char* qa        = (signed char*)(ws + 0x2E80000);    // <=18.9MB (40MB region)
  float* pbuf            = (float*)(ws + 0x5680000);          // 4 planes = 32MB (40MB region)
  __hip_bfloat16* abuf   = (__hip_bfloat16*)pbuf;  // alias: full bf16 abuf (36MB) used before g2 writes pbuf

  // fused prologue: wabs (2560) | rms_quant (2048) | rowmax zero (36)
  k_pro<<<4644, 256, 0, stream>>>(w1s, w2s, w1r, w2r, part,
                                  x, rmsw, qh, hb, amax_clip, rowmaxc);
  k_wscale_final<<<20, 64, 0, stream>>>(part, wscale);
  // fused mid: wquant (10240) | router (512 blocks x 4 tokens)
  k_mid<<<10752, 256, 0, stream>>>(w1s, w2s, w1r, w2r, wscale, q1T, q2T,
                                   hb, rw, gates, i01);
  // fused lists + meta (single block)
  k_lm<<<1, 512, 0, stream>>>(i01, amax_clip, wscale, lists, slots,
                              meta, rowexp, tokidx, wrow, srow1c);

  // single gemm1 over all compact rows (BK=128 sub-tiled)
  dim3 g1(32, NTILEMAX);
  k_g1<<<g1, 256, 0, stream>>>(qh, q1T, rowexp, tokidx, srow1c, meta,
                               abuf, rowmaxc);
  // fused: aquant all rows (4096) | scg (36)
  k_aqs<<<4096 + 36, 256, 0, stream>>>(abuf, rowmaxc, meta, qa,
                                       wscale, gates, tokidx, wrow, rowexp, sgc);
  dim3 g2(16, NTILEMAX);
  k_g2<<<g2, 256, 0, stream>>>(qa, q2T, rowexp, sgc, wrow, meta, pbuf);
  k_combine<<<TT * DD / 4 / 256, 256, 0, stream>>>(pbuf, out);
}